// Round 14
// baseline (788.656 us; speedup 1.0000x reference)
//
#include <hip/hip_runtime.h>
#include <hip/hip_fp16.h>

#define HD 64
#define SEQ 2304

typedef unsigned short u16;
typedef unsigned int u32;
using f32x4 = __attribute__((ext_vector_type(4))) float;
using s16x8 = __attribute__((ext_vector_type(8))) short;

static __device__ __forceinline__ float bf2f(u16 h) {
  union { float f; u32 u; } a; a.u = ((u32)h) << 16; return a.f;
}
// truncation split: x ~= hi + lo, |err| ~ 2^-16 |x|
static __device__ __forceinline__ void split2(float x, u16& h, u16& l) {
  u32 u = __float_as_uint(x);
  h = (u16)(u >> 16);
  float r = x - __uint_as_float(u & 0xffff0000u);
  l = (u16)(__float_as_uint(r) >> 16);
}
// round-to-nearest-even bf16 (unbiased: used for V which is consumed hi-only)
static __device__ __forceinline__ u16 rne_bf16(float x) {
  u32 u = __float_as_uint(x);
  return (u16)((u + 0x7fffu + ((u >> 16) & 1u)) >> 16);
}

// ---------------- split fp32 -> bf16 hi/lo, 8 elems/thread
__global__ __launch_bounds__(256) void conv_split_k(
    const float* __restrict__ src, u16* __restrict__ dhi, u16* __restrict__ dlo)
{
  const size_t i = ((size_t)blockIdx.x * 256 + threadIdx.x) * 8;
  f32x4 a = *(const f32x4*)(src + i);
  f32x4 b = *(const f32x4*)(src + i + 4);
  u16 h[8], l[8];
#pragma unroll
  for (int j = 0; j < 8; j++) {
    float x = j < 4 ? a[j] : b[j - 4];
    split2(x, h[j], l[j]);
  }
  *(uint4*)(dhi + i) = *(uint4*)&h[0];
  *(uint4*)(dlo + i) = *(uint4*)&l[0];
}

// ---------------- convert + transpose weights: w[K][N] f32 -> wT[N][K] bf16 hi/lo
__global__ __launch_bounds__(256) void conv_wT_k(
    const float* __restrict__ src, u16* __restrict__ dhi, u16* __restrict__ dlo,
    int K, int N)
{
  __shared__ u32 t[64][65];
  const int tid = threadIdx.x;
  const int n0 = blockIdx.x * 64, k0 = blockIdx.y * 64;
  const int r = tid >> 2, c0 = (tid & 3) * 16;
  const float* sp = src + (size_t)(k0 + r) * N + n0 + c0;
#pragma unroll
  for (int j = 0; j < 16; j += 4) {
    f32x4 v = *(const f32x4*)(sp + j);
#pragma unroll
    for (int e = 0; e < 4; e++) {
      u16 h, l;
      split2(v[e], h, l);
      t[r][c0 + j + e] = (u32)h | ((u32)l << 16);
    }
  }
  __syncthreads();
  u16 hb[16], lb[16];
#pragma unroll
  for (int j = 0; j < 16; j++) {
    u32 p = t[c0 + j][r];
    hb[j] = (u16)(p & 0xffffu);
    lb[j] = (u16)(p >> 16);
  }
  size_t off = (size_t)(n0 + r) * K + k0 + c0;
  *(uint4*)(dhi + off)     = *(uint4*)&hb[0];
  *(uint4*)(dhi + off + 8) = *(uint4*)&hb[8];
  *(uint4*)(dlo + off)     = *(uint4*)&lb[0];
  *(uint4*)(dlo + off + 8) = *(uint4*)&lb[8];
}

// ---- direct-fragment helpers (qkv): 16 global b128 loads / 48 MFMAs per K-step
static __device__ __forceinline__ void load16(
    const u16* pAh, const u16* pAl, const u16* pBh, const u16* pBl, int kk,
    s16x8 ah[4], s16x8 al[4], s16x8 bh[4], s16x8 bl[4])
{
#pragma unroll
  for (int mt = 0; mt < 4; mt++) {
    size_t o = (size_t)mt * 12288 + (size_t)kk * 32;   // mt*16 rows, kk*32 cols
    ah[mt] = *(const s16x8*)(pAh + o);
    al[mt] = *(const s16x8*)(pAl + o);
    bh[mt] = *(const s16x8*)(pBh + o);
    bl[mt] = *(const s16x8*)(pBl + o);
  }
}
static __device__ __forceinline__ void mfma48(
    const s16x8 ah[4], const s16x8 al[4], const s16x8 bh[4], const s16x8 bl[4],
    f32x4 acc[4][4])
{
#pragma unroll
  for (int mt = 0; mt < 4; mt++)
#pragma unroll
    for (int nt = 0; nt < 4; nt++) {
      acc[mt][nt] = __builtin_amdgcn_mfma_f32_16x16x32_bf16(ah[mt], bh[nt], acc[mt][nt], 0, 0, 0);
      acc[mt][nt] = __builtin_amdgcn_mfma_f32_16x16x32_bf16(ah[mt], bl[nt], acc[mt][nt], 0, 0, 0);
      acc[mt][nt] = __builtin_amdgcn_mfma_f32_16x16x32_bf16(al[mt], bh[nt], acc[mt][nt], 0, 0, 0);
    }
}

// ---------------- QKV GEMM, barrier-free direct-fragment: -> q fp32 + K (hi/lo) +
// V (single RNE bf16) images
__global__ __launch_bounds__(256, 2) void qkv_mfma_k(
    const u16* __restrict__ xhi, const u16* __restrict__ xlo,
    const u16* __restrict__ bthi, const u16* __restrict__ btlo,
    const float* __restrict__ bias,
    float* __restrict__ qbuf, u16* __restrict__ khi, u16* __restrict__ klo,
    u16* __restrict__ vhi)
{
  __shared__ __align__(16) u16 img[4][4096];   // epilogue only (wave-private)
  const int tid = threadIdx.x;
  const int lane = tid & 63, wid = tid >> 6;
  const int g = lane >> 4, ql = lane & 15;
  const int wr = wid >> 1, wc = wid & 1;
  const int c0 = blockIdx.x * 128, r0 = blockIdx.y * 128;

  const u16* pAh = xhi  + (size_t)(r0 + wr * 64 + ql) * 768 + g * 8;
  const u16* pAl = xlo  + (size_t)(r0 + wr * 64 + ql) * 768 + g * 8;
  const u16* pBh = bthi + (size_t)(c0 + wc * 64 + ql) * 768 + g * 8;
  const u16* pBl = btlo + (size_t)(c0 + wc * 64 + ql) * 768 + g * 8;

  s16x8 Xah[4], Xal[4], Xbh[4], Xbl[4];
  s16x8 Yah[4], Yal[4], Ybh[4], Ybl[4];
  f32x4 acc[4][4] = {};

  load16(pAh, pAl, pBh, pBl, 0, Xah, Xal, Xbh, Xbl);
  for (int ks = 0; ks < 24; ks += 2) {
    load16(pAh, pAl, pBh, pBl, ks + 1, Yah, Yal, Ybh, Ybl);
    mfma48(Xah, Xal, Xbh, Xbl, acc);
    if (ks + 2 < 24)
      load16(pAh, pAl, pBh, pBl, ks + 2, Xah, Xal, Xbh, Xbl);
    mfma48(Yah, Yal, Ybh, Ybl, acc);
  }

  // ---- epilogue: q fp32 scatter / K,V permuted tile-images via LDS (wave-private)
  const int col0 = c0 + wc * 64;
  const int row0 = r0 + wr * 64;
  const int hb36 = col0 >> 6;
  const int which = hb36 / 12, head = hb36 - (hb36 / 12) * 12;
  const int b = row0 / 2304;
  const int sb = row0 - b * 2304;
  const int bh = b * 12 + head;
  float bb[4];
#pragma unroll
  for (int nt = 0; nt < 4; nt++) bb[nt] = bias[col0 + nt * 16 + ql];
#pragma unroll
  for (int mt = 0; mt < 4; mt++)
#pragma unroll
    for (int nt = 0; nt < 4; nt++)
#pragma unroll
      for (int r = 0; r < 4; r++)
        acc[mt][nt][r] += bb[nt];

  if (which == 0) {
#pragma unroll
    for (int mt = 0; mt < 4; mt++)
#pragma unroll
      for (int nt = 0; nt < 4; nt++)
#pragma unroll
        for (int r = 0; r < 4; r++) {
          int s = sb + mt * 16 + g * 4 + r;
          qbuf[((size_t)bh * SEQ + s) * 64 + nt * 16 + ql] = acc[mt][nt][r];
        }
  } else if (which == 1) {
    const int kt = sb >> 6;
    const size_t tile = ((size_t)bh * 36 + kt) * 4096;
    u16* const reg = img[wid];
    // pass 1: HI
#pragma unroll
    for (int mt = 0; mt < 4; mt++)
#pragma unroll
      for (int nt = 0; nt < 4; nt++) {
        int pcK = (nt >> 1) * 32 + (ql >> 2) * 8 + (nt & 1) * 4 + (ql & 3);
#pragma unroll
        for (int r = 0; r < 4; r++) {
          u16 h, l;
          split2(acc[mt][nt][r], h, l);
          reg[(mt * 16 + g * 4 + r) * 64 + pcK] = h;
        }
      }
    {
      const u16* src = reg + lane * 64;
      u16* dst = khi + tile + lane * 64;
#pragma unroll
      for (int j = 0; j < 8; j++)
        *(uint4*)(dst + j * 8) = *(const uint4*)(src + j * 8);
    }
    // pass 2: LO
#pragma unroll
    for (int mt = 0; mt < 4; mt++)
#pragma unroll
      for (int nt = 0; nt < 4; nt++) {
        int pcK = (nt >> 1) * 32 + (ql >> 2) * 8 + (nt & 1) * 4 + (ql & 3);
#pragma unroll
        for (int r = 0; r < 4; r++) {
          u16 h, l;
          split2(acc[mt][nt][r], h, l);
          reg[(mt * 16 + g * 4 + r) * 64 + pcK] = l;
        }
      }
    {
      const u16* src = reg + lane * 64;
      u16* dst = klo + tile + lane * 64;
#pragma unroll
      for (int j = 0; j < 8; j++)
        *(uint4*)(dst + j * 8) = *(const uint4*)(src + j * 8);
    }
  } else {
    // V image: single pass, RNE bf16 (consumed hi-only; RNE kills truncation bias)
    const int kt = sb >> 6;
    const size_t tile = ((size_t)bh * 36 + kt) * 4096;
    u16* const reg = img[wid];
#pragma unroll
    for (int mt = 0; mt < 4; mt++)
#pragma unroll
      for (int nt = 0; nt < 4; nt++)
#pragma unroll
        for (int r = 0; r < 4; r++) {
          int off = (nt * 16 + ql) * 64 + (mt >> 1) * 32 + g * 8 + (mt & 1) * 4 + r;
          reg[off] = rne_bf16(acc[mt][nt][r]);
        }
    {
      const u16* src = reg + lane * 64;
      u16* dst = vhi + tile + lane * 64;
#pragma unroll
      for (int j = 0; j < 8; j++)
        *(uint4*)(dst + j * 8) = *(const uint4*)(src + j * 8);
    }
  }
}

// ---------------- Fused attention: 64 q-rows/block, 864 blocks. LDS stages only
// K-hi + V (8 b128 reads + 2 writes per wave/tile, -33% LDS-pipe traffic); K-lo
// fragments read DIRECT from L2-pinned global image at their MFMA. l-reduction
// deferred to epilogue (corr is g-uniform, per-lane partial l is exact).
// LDS 31.6KB + VGPR<=64 (launch_bounds 8/EU) -> 4 blocks/CU, 32 waves.
// grid(bh=24, qt=36): 24%8==0 -> XCD = bh%8 for all qt (K/V images L2-pinned).
#define BH_OFF  18432                     // Bh: 49 x 65 u16
#define BW_OFFA (BH_OFF + 6372)           // 24804 (49*65*2=6370, +2 align)
#define MS_OFF  (BW_OFFA + 48*65*2)       // 31044
#define LS_OFF  (MS_OFF + 256)            // 31300
__global__ __launch_bounds__(512, 8) void attn_k(
    const float* __restrict__ qb,
    const u16* __restrict__ khi, const u16* __restrict__ klo,
    const u16* __restrict__ vhi,
    const float* __restrict__ rph, const float* __restrict__ rpw,
    u32* __restrict__ aop)
{
  __shared__ __align__(16) char pool[LS_OFF + 256];   // 31556 B
  u16* KhiL = (u16*)pool;              // [64 key][72]
  u16* VhL  = (u16*)(pool + 9216);     // [64 d][72]
  __half* Bh = (__half*)(pool + BH_OFF);   // [49 kh][65 pad]
  __half* Bw = (__half*)(pool + BW_OFFA);  // [48 kw][65 pad]
  float* m_s = (float*)(pool + MS_OFF);    // [64]
  float* l_s = (float*)(pool + LS_OFF);    // [64]
  float* qlds = (float*)pool;              // prologue alias [64][68] f32 (17408B)
  float* o_s  = (float*)pool;              // epilogue alias [64][68] f32

  const int tid  = threadIdx.x;
  const int lane = tid & 63;
  const int wid  = tid >> 6;
  const int g    = lane >> 4;
  const int ql   = lane & 15;
  const int wq   = wid & 3;     // q-group: rows [16*wq, 16*wq+16)
  const int hh   = wid >> 2;    // key-half stream
  const int bh   = blockIdx.x;  // 24
  const int qt   = blockIdx.y;  // 36
  const int s0   = qt * 64;

  // ---- stage Q tile fp32 -> LDS
  {
    int row = tid >> 3, c0 = (tid & 7) * 8;
    const float* src = qb + ((size_t)bh * SEQ + s0 + row) * HD + c0;
    f32x4 v0 = *(const f32x4*)src;
    f32x4 v1 = *(const f32x4*)(src + 4);
    *(f32x4*)&qlds[row * 68 + c0]     = v0;
    *(f32x4*)&qlds[row * 68 + c0 + 4] = v1;
  }
  __syncthreads();

  // ---- Q fragments hi/lo (lane's q = 16*wq + ql)
  s16x8 qfh[2], qfl[2];
  {
    int qrow = wq * 16 + ql;
#pragma unroll
    for (int ds = 0; ds < 2; ds++) {
#pragma unroll
      for (int h2 = 0; h2 < 2; h2++) {
        f32x4 qv = *(const f32x4*)&qlds[qrow * 68 + g * 4 + h2 * 16 + ds * 32];
#pragma unroll
        for (int j = 0; j < 4; j++) {
          u16 hi, lo;
          split2(qv[j], hi, lo);
          qfh[ds][h2 * 4 + j] = (short)hi;
          qfl[ds][h2 * 4 + j] = (short)lo;
        }
      }
    }
  }

  // ---- prefetch tile 0 (K-hi + V only; K-lo is read direct from global)
  const size_t tbK = (size_t)bh * 36 * 4096;
  const int srow = tid >> 3;
  const int sch  = ((tid & 7) - (srow & 7)) & 7;
  const size_t soff = (size_t)srow * 64 + sch * 8;
  uint4 rkh = *(const uint4*)(khi + tbK + soff);
  uint4 rvh = *(const uint4*)(vhi + tbK + soff);

  // ---- decomposed rel-pos bias tables (fp16, stride 65)
  for (int i = tid; i < 64 * 96; i += 512) {
    int q = i / 96, j = i - (i / 96) * 96;
    int s = s0 + q;
    int qhg = s / 48, qw = s - qhg * 48;
    const float* tab;
    int ridx, col;
    if (j < 48) { col = j;      ridx = qhg - j + 47;        tab = rph; }
    else        { col = j - 48; ridx = qw - (j - 48) + 47;  tab = rpw; }
    const float* rp = tab + (size_t)ridx * HD;
    const float* qp = &qlds[q * 68];
    float s1 = 0.f;
#pragma unroll 4
    for (int d = 0; d < 64; d += 4) {
      f32x4 a = *(const f32x4*)(qp + d);
      f32x4 bv = *(const f32x4*)(rp + d);
      s1 += a[0]*bv[0] + a[1]*bv[1] + a[2]*bv[2] + a[3]*bv[3];
    }
    if (j < 48) Bh[col * 65 + q] = __float2half_rn(s1);
    else        Bw[col * 65 + q] = __float2half_rn(s1);
  }

  float m_r = -3.0e38f, l_r = 0.f;   // l_r is PER-LANE partial (reduced in epilogue)
  f32x4 oacc[4] = {};   // O[q = 4g+r][d = ql + 16*dt]
  const int q64b = wq * 16 + ql;

  for (int kt = 0; kt < 36; kt++) {
    __syncthreads();
    *(uint4*)(KhiL + srow * 72 + sch * 8) = rkh;
    *(uint4*)(VhL  + srow * 72 + sch * 8) = rvh;
    __syncthreads();
    if (kt < 35) {     // T14: issue next-tile loads; land under MFMA phase
      size_t tb2 = tbK + (size_t)(kt + 1) * 4096;
      rkh = *(const uint4*)(khi + tb2 + soff);
      rvh = *(const uint4*)(vhi + tb2 + soff);
    }
    const size_t tb = tbK + (size_t)kt * 4096;

    // ---- QK^T (swapped): S^T[key][q]; K-hi frag from LDS, K-lo frag from global
    f32x4 sacc[2] = {};
    __builtin_amdgcn_s_setprio(1);
#pragma unroll
    for (int ds = 0; ds < 2; ds++) {
#pragma unroll
      for (int t2 = 0; t2 < 2; t2++) {
        int row = (hh * 2 + t2) * 16 + ql;
        s16x8 al = *(const s16x8*)(klo + tb + (size_t)row * 64 + ds * 32 + g * 8);
        s16x8 af = *(const s16x8*)(KhiL + row * 72 + ds * 32 + g * 8);
        sacc[t2] = __builtin_amdgcn_mfma_f32_16x16x32_bf16(af, qfh[ds], sacc[t2], 0, 0, 0);
        sacc[t2] = __builtin_amdgcn_mfma_f32_16x16x32_bf16(af, qfl[ds], sacc[t2], 0, 0, 0);
        sacc[t2] = __builtin_amdgcn_mfma_f32_16x16x32_bf16(al, qfh[ds], sacc[t2], 0, 0, 0);
      }
    }
    __builtin_amdgcn_s_setprio(0);

    // ---- bias gather: kh in {kh0,kh0+1} within a half-tile
    u32 kg0 = (u32)(kt * 64 + hh * 32);
    u32 kh0 = kg0 / 48u;
    int kw0 = (int)(kg0 - kh0 * 48u);
    float bh0 = __half2float(Bh[kh0 * 65 + q64b]);
    float bh1 = __half2float(Bh[(kh0 + 1) * 65 + q64b]);
    float lg[8];
    float tmax = -3.0e38f;
#pragma unroll
    for (int t2 = 0; t2 < 2; t2++)
#pragma unroll
      for (int r = 0; r < 4; r++) {
        int j = t2 * 4 + r;
        int w = kw0 + t2 * 16 + g * 4 + r;
        bool wrap = w >= 48;
        float bw = __half2float(Bw[(wrap ? w - 48 : w) * 65 + q64b]);
        float x = sacc[t2][r] * 0.125f + (wrap ? bh1 : bh0) + bw;
        lg[j] = x;
        tmax = fmaxf(tmax, x);
      }
    tmax = fmaxf(tmax, __shfl_xor(tmax, 16));
    tmax = fmaxf(tmax, __shfl_xor(tmax, 32));
    if (__any(tmax > m_r + 6.0f)) {   // T13 defer-max
      float mnew = fmaxf(m_r, tmax);
      float corr = __expf(m_r - mnew);
      l_r *= corr;                    // corr identical across g-lanes: per-lane ok
      m_r = mnew;
      float cq[4];
#pragma unroll
      for (int r = 0; r < 4; r++) cq[r] = __shfl(corr, g * 4 + r);
#pragma unroll
      for (int dt = 0; dt < 4; dt++)
#pragma unroll
        for (int r = 0; r < 4; r++) oacc[dt][r] *= cq[r];
    }
    float psum = 0.f;
    s16x8 pfh;
#pragma unroll
    for (int j = 0; j < 8; j++) {
      float p = __expf(lg[j] - m_r);
      psum += p;
      pfh[j] = (short)(u16)(__float_as_uint(p) >> 16);
    }
    l_r += psum;   // per-lane partial; cross-g reduction deferred to epilogue

    // ---- PV: single MFMA per dt
    __builtin_amdgcn_s_setprio(1);
#pragma unroll
    for (int dt = 0; dt < 4; dt++) {
      int row = ql + 16 * dt;
      s16x8 bhf = *(const s16x8*)(VhL + row * 72 + hh * 32 + g * 8);
      oacc[dt] = __builtin_amdgcn_mfma_f32_16x16x32_bf16(pfh, bhf, oacc[dt], 0, 0, 0);
    }
    __builtin_amdgcn_s_setprio(0);
  }

  // ---- reduce per-lane l across the 4 g-lanes (deferred from the main loop)
  l_r += __shfl_xor(l_r, 16);
  l_r += __shfl_xor(l_r, 32);

  // ---- merge the two key-streams per q-group, write out (packed u32 hi|lo)
  __syncthreads();
  if (hh == 1) {
    if (g == 0) { m_s[q64b] = m_r; l_s[q64b] = l_r; }
#pragma unroll
    for (int dt = 0; dt < 4; dt++)
#pragma unroll
      for (int r = 0; r < 4; r++)
        o_s[(wq * 16 + g * 4 + r) * 68 + ql + 16 * dt] = oacc[dt][r];
  }
  __syncthreads();
  if (hh == 0) {
    float m2 = m_s[q64b];
    float l2 = l_s[q64b];
    float mf = fmaxf(m_r, m2);
    float c1 = __expf(m_r - mf);
    float c2 = __expf(m2 - mf);
    float lf = l_r * c1 + l2 * c2;
    float c1q[4], c2q[4], lfq[4];
#pragma unroll
    for (int r = 0; r < 4; r++) {
      c1q[r] = __shfl(c1, g * 4 + r);
      c2q[r] = __shfl(c2, g * 4 + r);
      lfq[r] = __shfl(lf, g * 4 + r);
    }
    const int b = bh / 12, head = bh - (bh / 12) * 12;
#pragma unroll
    for (int dt = 0; dt < 4; dt++)
#pragma unroll
      for (int r = 0; r < 4; r++) {
        float oo = oacc[dt][r] * c1q[r]
                 + o_s[(wq * 16 + g * 4 + r) * 68 + ql + 16 * dt] * c2q[r];
        float on = oo / lfq[r];
        int s = s0 + wq * 16 + g * 4 + r;
        size_t idx = ((size_t)b * SEQ + s) * 768 + head * 64 + ql + 16 * dt;
        u16 h, l;
        split2(on, h, l);
        aop[idx] = (u32)h | ((u32)l << 16);
      }
  }
}

// ---------------- proj GEMM via split-bf16 MFMA (A = packed u32 hi|lo): -> out
__global__ __launch_bounds__(256) void proj_mfma_k(
    const u32* __restrict__ aop,
    const u16* __restrict__ bthi, const u16* __restrict__ btlo,
    const float* __restrict__ bias, float* __restrict__ out)
{
  __shared__ __align__(16) u16 Ah[128*40], Al[128*40], Bh2[128*40], Bl2[128*40];
  const int tid = threadIdx.x;
  const int lane = tid & 63, wid = tid >> 6;
  const int g = lane >> 4, ql = lane & 15;
  const int wr = wid >> 1, wc = wid & 1;
  const int c0 = blockIdx.x * 128, r0 = blockIdx.y * 128;
  const int srow = tid >> 1, half = tid & 1;

  const u32* ag = aop + (size_t)(r0 + srow) * 768 + half * 16;
  const u16* bgh = bthi + (size_t)(c0 + srow) * 768 + half * 16;
  const u16* bgl = btlo + (size_t)(c0 + srow) * 768 + half * 16;

  uint4 paw[4]; uint4 pbh[2], pbl[2];
#pragma unroll
  for (int j = 0; j < 4; j++) paw[j] = *(const uint4*)(ag + j * 4);
  pbh[0] = *(const uint4*)bgh; pbh[1] = *(const uint4*)(bgh + 8);
  pbl[0] = *(const uint4*)bgl; pbl[1] = *(const uint4*)(bgl + 8);

  f32x4 acc[4][4] = {};

  for (int ks = 0; ks < 24; ks++) {
    __syncthreads();
    {
      u16 hb[16], lb[16];
      const u32* pw = (const u32*)&paw[0];
#pragma unroll
      for (int j = 0; j < 16; j++) {
        hb[j] = (u16)(pw[j] & 0xffffu);
        lb[j] = (u16)(pw[j] >> 16);
      }
      u16* d1 = Ah + srow * 40 + half * 16;
      u16* d2 = Al + srow * 40 + half * 16;
      u16* d3 = Bh2 + srow * 40 + half * 16;
      u16* d4 = Bl2 + srow * 40 + half * 16;
      *(uint4*)d1 = *(uint4*)&hb[0]; *(uint4*)(d1 + 8) = *(uint4*)&hb[8];
      *(uint4*)d2 = *(uint4*)&lb[0]; *(uint4*)(d2 + 8) = *(uint4*)&lb[8];
      *(uint4*)d3 = pbh[0]; *(uint4*)(d3 + 8) = pbh[1];
      *(uint4*)d4 = pbl[0]; *(uint4*)(d4 + 8) = pbl[1];
    }
    __syncthreads();
    if (ks < 23) {
      const int o = (ks + 1) * 32;
#pragma unroll
      for (int j = 0; j < 4; j++) paw[j] = *(const uint4*)(ag + o + j * 4);
      pbh[0] = *(const uint4*)(bgh + o); pbh[1] = *(const uint4*)(bgh + o + 8);
      pbl[0] = *(const uint4*)(bgl + o); pbl[1] = *(const uint4*)(bgl + o + 8);
    }
    s16x8 bfh[4], bfl[4];
#pragma unroll
    for (int nt = 0; nt < 4; nt++) {
      bfh[nt] = *(const s16x8*)(Bh2 + (wc * 64 + nt * 16 + ql) * 40 + g * 8);
      bfl[nt] = *(const s16x8*)(Bl2 + (wc * 64 + nt * 16 + ql) * 40 + g * 8);
    }
#pragma unroll
    for (int mt = 0; mt < 4; mt++) {
      s16x8 ah = *(const s16x8*)(Ah + (wr * 64 + mt * 16 + ql) * 40 + g * 8);
      s16x8 al = *(const s16x8*)(Al + (wr * 64 + mt * 16 + ql) * 40 + g * 8);
#pragma unroll
      for (int nt = 0; nt < 4; nt++) {
        acc[mt][nt] = __builtin_amdgcn_mfma_f32_16x16x32_bf16(ah, bfh[nt], acc[mt][nt], 0, 0, 0);
        acc[mt][nt] = __builtin_amdgcn_mfma_f32_16x16x32_bf16(ah, bfl[nt], acc[mt][nt], 0, 0, 0);
        acc[mt][nt] = __builtin_amdgcn_mfma_f32_16x16x32_bf16(al, bfh[nt], acc[mt][nt], 0, 0, 0);
      }
    }
  }
  const int col0 = c0 + wc * 64;
  const int row0 = r0 + wr * 64;
  float bb[4];
#pragma unroll
  for (int nt = 0; nt < 4; nt++) bb[nt] = bias[col0 + nt * 16 + ql];
#pragma unroll
  for (int mt = 0; mt < 4; mt++)
#pragma unroll
    for (int nt = 0; nt < 4; nt++)
#pragma unroll
      for (int r = 0; r < 4; r++)
        out[(size_t)(row0 + mt * 16 + g * 4 + r) * 768 + col0 + nt * 16 + ql] =
            acc[mt][nt][r] + bb[nt];
}

extern "C" void kernel_launch(void* const* d_in, const int* in_sizes, int n_in,
                              void* d_out, int out_size, void* d_ws, size_t ws_size,
                              hipStream_t stream) {
  const float* x      = (const float*)d_in[0];
  const float* qkv_w  = (const float*)d_in[1];
  const float* qkv_b  = (const float*)d_in[2];
  const float* proj_w = (const float*)d_in[3];
  const float* proj_b = (const float*)d_in[4];
  const float* rph    = (const float*)d_in[5];
  const float* rpw    = (const float*)d_in[6];
  float* out = (float*)d_out;
  float* ws  = (float*)d_ws;

  const size_t SZ = (size_t)24 * SEQ * HD;   // 3,538,944 elems (== 4608*768)
  float* qbuf = ws;                          // SZ f32
  u16* khi = (u16*)(ws + SZ);                // khi, klo, vhi (+dead slot)
  u16* klo = khi + SZ;
  u16* vhi = klo + SZ;
  u16* xhi = (u16*)(ws + 3 * SZ);            // 2 x SZ u16
  u16* xlo = xhi + SZ;
  u32* aop = (u32*)(ws + 4 * SZ);            // SZ u32 (packed hi|lo)
  u16* wqThi = (u16*)(ws + 5 * SZ);          // 768*2304 x2
  u16* wqTlo = wqThi + 768 * 2304;
  u16* wpThi = wqTlo + 768 * 2304;           // 768*768 x2
  u16* wpTlo = wpThi + 768 * 768;

  conv_split_k<<<1728, 256, 0, stream>>>(x, xhi, xlo);
  conv_wT_k <<<dim3(36, 12), 256, 0, stream>>>(qkv_w, wqThi, wqTlo, 768, 2304);
  conv_wT_k <<<dim3(12, 12), 256, 0, stream>>>(proj_w, wpThi, wpTlo, 768, 768);
  qkv_mfma_k<<<dim3(18, 36), 256, 0, stream>>>(xhi, xlo, wqThi, wqTlo, qkv_b,
                                               qbuf, khi, klo, vhi);
  attn_k    <<<dim3(24, 36), 512, 0, stream>>>(qbuf, khi, klo, vhi, rph, rpw, aop);
  proj_mfma_k<<<dim3(6, 36), 256, 0, stream>>>(aop, wpThi, wpTlo, proj_b, out);
}

// Round 15
// 536.923 us; speedup vs baseline: 1.4688x; 1.4688x over previous
//
#include <hip/hip_runtime.h>
#include <hip/hip_fp16.h>

#define HD 64
#define SEQ 2304

typedef unsigned short u16;
typedef unsigned int u32;
using f32x4 = __attribute__((ext_vector_type(4))) float;
using s16x8 = __attribute__((ext_vector_type(8))) short;

static __device__ __forceinline__ float bf2f(u16 h) {
  union { float f; u32 u; } a; a.u = ((u32)h) << 16; return a.f;
}
// truncation split: x ~= hi + lo, |err| ~ 2^-16 |x|
static __device__ __forceinline__ void split2(float x, u16& h, u16& l) {
  u32 u = __float_as_uint(x);
  h = (u16)(u >> 16);
  float r = x - __uint_as_float(u & 0xffff0000u);
  l = (u16)(__float_as_uint(r) >> 16);
}
// round-to-nearest-even bf16 (unbiased: used for V which is consumed hi-only)
static __device__ __forceinline__ u16 rne_bf16(float x) {
  u32 u = __float_as_uint(x);
  return (u16)((u + 0x7fffu + ((u >> 16) & 1u)) >> 16);
}

// ---------------- split fp32 -> bf16 hi/lo, 8 elems/thread
__global__ __launch_bounds__(256) void conv_split_k(
    const float* __restrict__ src, u16* __restrict__ dhi, u16* __restrict__ dlo)
{
  const size_t i = ((size_t)blockIdx.x * 256 + threadIdx.x) * 8;
  f32x4 a = *(const f32x4*)(src + i);
  f32x4 b = *(const f32x4*)(src + i + 4);
  u16 h[8], l[8];
#pragma unroll
  for (int j = 0; j < 8; j++) {
    float x = j < 4 ? a[j] : b[j - 4];
    split2(x, h[j], l[j]);
  }
  *(uint4*)(dhi + i) = *(uint4*)&h[0];
  *(uint4*)(dlo + i) = *(uint4*)&l[0];
}

// ---------------- convert + transpose weights: w[K][N] f32 -> wT[N][K] bf16 hi/lo
__global__ __launch_bounds__(256) void conv_wT_k(
    const float* __restrict__ src, u16* __restrict__ dhi, u16* __restrict__ dlo,
    int K, int N)
{
  __shared__ u32 t[64][65];
  const int tid = threadIdx.x;
  const int n0 = blockIdx.x * 64, k0 = blockIdx.y * 64;
  const int r = tid >> 2, c0 = (tid & 3) * 16;
  const float* sp = src + (size_t)(k0 + r) * N + n0 + c0;
#pragma unroll
  for (int j = 0; j < 16; j += 4) {
    f32x4 v = *(const f32x4*)(sp + j);
#pragma unroll
    for (int e = 0; e < 4; e++) {
      u16 h, l;
      split2(v[e], h, l);
      t[r][c0 + j + e] = (u32)h | ((u32)l << 16);
    }
  }
  __syncthreads();
  u16 hb[16], lb[16];
#pragma unroll
  for (int j = 0; j < 16; j++) {
    u32 p = t[c0 + j][r];
    hb[j] = (u16)(p & 0xffffu);
    lb[j] = (u16)(p >> 16);
  }
  size_t off = (size_t)(n0 + r) * K + k0 + c0;
  *(uint4*)(dhi + off)     = *(uint4*)&hb[0];
  *(uint4*)(dhi + off + 8) = *(uint4*)&hb[8];
  *(uint4*)(dlo + off)     = *(uint4*)&lb[0];
  *(uint4*)(dlo + off + 8) = *(uint4*)&lb[8];
}

// ---- direct-fragment helpers (qkv): 16 global b128 loads / 48 MFMAs per K-step
static __device__ __forceinline__ void load16(
    const u16* pAh, const u16* pAl, const u16* pBh, const u16* pBl, int kk,
    s16x8 ah[4], s16x8 al[4], s16x8 bh[4], s16x8 bl[4])
{
#pragma unroll
  for (int mt = 0; mt < 4; mt++) {
    size_t o = (size_t)mt * 12288 + (size_t)kk * 32;   // mt*16 rows, kk*32 cols
    ah[mt] = *(const s16x8*)(pAh + o);
    al[mt] = *(const s16x8*)(pAl + o);
    bh[mt] = *(const s16x8*)(pBh + o);
    bl[mt] = *(const s16x8*)(pBl + o);
  }
}
static __device__ __forceinline__ void mfma48(
    const s16x8 ah[4], const s16x8 al[4], const s16x8 bh[4], const s16x8 bl[4],
    f32x4 acc[4][4])
{
#pragma unroll
  for (int mt = 0; mt < 4; mt++)
#pragma unroll
    for (int nt = 0; nt < 4; nt++) {
      acc[mt][nt] = __builtin_amdgcn_mfma_f32_16x16x32_bf16(ah[mt], bh[nt], acc[mt][nt], 0, 0, 0);
      acc[mt][nt] = __builtin_amdgcn_mfma_f32_16x16x32_bf16(ah[mt], bl[nt], acc[mt][nt], 0, 0, 0);
      acc[mt][nt] = __builtin_amdgcn_mfma_f32_16x16x32_bf16(al[mt], bh[nt], acc[mt][nt], 0, 0, 0);
    }
}

// ---------------- QKV GEMM, barrier-free direct-fragment: -> q fp32 + K (hi/lo) +
// V (single RNE bf16) images
__global__ __launch_bounds__(256, 2) void qkv_mfma_k(
    const u16* __restrict__ xhi, const u16* __restrict__ xlo,
    const u16* __restrict__ bthi, const u16* __restrict__ btlo,
    const float* __restrict__ bias,
    float* __restrict__ qbuf, u16* __restrict__ khi, u16* __restrict__ klo,
    u16* __restrict__ vhi)
{
  __shared__ __align__(16) u16 img[4][4096];   // epilogue only (wave-private)
  const int tid = threadIdx.x;
  const int lane = tid & 63, wid = tid >> 6;
  const int g = lane >> 4, ql = lane & 15;
  const int wr = wid >> 1, wc = wid & 1;
  const int c0 = blockIdx.x * 128, r0 = blockIdx.y * 128;

  const u16* pAh = xhi  + (size_t)(r0 + wr * 64 + ql) * 768 + g * 8;
  const u16* pAl = xlo  + (size_t)(r0 + wr * 64 + ql) * 768 + g * 8;
  const u16* pBh = bthi + (size_t)(c0 + wc * 64 + ql) * 768 + g * 8;
  const u16* pBl = btlo + (size_t)(c0 + wc * 64 + ql) * 768 + g * 8;

  s16x8 Xah[4], Xal[4], Xbh[4], Xbl[4];
  s16x8 Yah[4], Yal[4], Ybh[4], Ybl[4];
  f32x4 acc[4][4] = {};

  load16(pAh, pAl, pBh, pBl, 0, Xah, Xal, Xbh, Xbl);
  for (int ks = 0; ks < 24; ks += 2) {
    load16(pAh, pAl, pBh, pBl, ks + 1, Yah, Yal, Ybh, Ybl);
    mfma48(Xah, Xal, Xbh, Xbl, acc);
    if (ks + 2 < 24)
      load16(pAh, pAl, pBh, pBl, ks + 2, Xah, Xal, Xbh, Xbl);
    mfma48(Yah, Yal, Ybh, Ybl, acc);
  }

  // ---- epilogue: q fp32 scatter / K,V permuted tile-images via LDS (wave-private)
  const int col0 = c0 + wc * 64;
  const int row0 = r0 + wr * 64;
  const int hb36 = col0 >> 6;
  const int which = hb36 / 12, head = hb36 - (hb36 / 12) * 12;
  const int b = row0 / 2304;
  const int sb = row0 - b * 2304;
  const int bh = b * 12 + head;
  float bb[4];
#pragma unroll
  for (int nt = 0; nt < 4; nt++) bb[nt] = bias[col0 + nt * 16 + ql];
#pragma unroll
  for (int mt = 0; mt < 4; mt++)
#pragma unroll
    for (int nt = 0; nt < 4; nt++)
#pragma unroll
      for (int r = 0; r < 4; r++)
        acc[mt][nt][r] += bb[nt];

  if (which == 0) {
#pragma unroll
    for (int mt = 0; mt < 4; mt++)
#pragma unroll
      for (int nt = 0; nt < 4; nt++)
#pragma unroll
        for (int r = 0; r < 4; r++) {
          int s = sb + mt * 16 + g * 4 + r;
          qbuf[((size_t)bh * SEQ + s) * 64 + nt * 16 + ql] = acc[mt][nt][r];
        }
  } else if (which == 1) {
    const int kt = sb >> 6;
    const size_t tile = ((size_t)bh * 36 + kt) * 4096;
    u16* const reg = img[wid];
    // pass 1: HI
#pragma unroll
    for (int mt = 0; mt < 4; mt++)
#pragma unroll
      for (int nt = 0; nt < 4; nt++) {
        int pcK = (nt >> 1) * 32 + (ql >> 2) * 8 + (nt & 1) * 4 + (ql & 3);
#pragma unroll
        for (int r = 0; r < 4; r++) {
          u16 h, l;
          split2(acc[mt][nt][r], h, l);
          reg[(mt * 16 + g * 4 + r) * 64 + pcK] = h;
        }
      }
    {
      const u16* src = reg + lane * 64;
      u16* dst = khi + tile + lane * 64;
#pragma unroll
      for (int j = 0; j < 8; j++)
        *(uint4*)(dst + j * 8) = *(const uint4*)(src + j * 8);
    }
    // pass 2: LO
#pragma unroll
    for (int mt = 0; mt < 4; mt++)
#pragma unroll
      for (int nt = 0; nt < 4; nt++) {
        int pcK = (nt >> 1) * 32 + (ql >> 2) * 8 + (nt & 1) * 4 + (ql & 3);
#pragma unroll
        for (int r = 0; r < 4; r++) {
          u16 h, l;
          split2(acc[mt][nt][r], h, l);
          reg[(mt * 16 + g * 4 + r) * 64 + pcK] = l;
        }
      }
    {
      const u16* src = reg + lane * 64;
      u16* dst = klo + tile + lane * 64;
#pragma unroll
      for (int j = 0; j < 8; j++)
        *(uint4*)(dst + j * 8) = *(const uint4*)(src + j * 8);
    }
  } else {
    // V image: single pass, RNE bf16 (consumed hi-only; RNE kills truncation bias)
    const int kt = sb >> 6;
    const size_t tile = ((size_t)bh * 36 + kt) * 4096;
    u16* const reg = img[wid];
#pragma unroll
    for (int mt = 0; mt < 4; mt++)
#pragma unroll
      for (int nt = 0; nt < 4; nt++)
#pragma unroll
        for (int r = 0; r < 4; r++) {
          int off = (nt * 16 + ql) * 64 + (mt >> 1) * 32 + g * 8 + (mt & 1) * 4 + r;
          reg[off] = rne_bf16(acc[mt][nt][r]);
        }
    {
      const u16* src = reg + lane * 64;
      u16* dst = vhi + tile + lane * 64;
#pragma unroll
      for (int j = 0; j < 8; j++)
        *(uint4*)(dst + j * 8) = *(const uint4*)(src + j * 8);
    }
  }
}

// ---------------- Fused attention: 64 q-rows/block, 864 blocks. LDS stages only
// K-hi + V; K-lo fragments read DIRECT from L2-pinned global image at their MFMA.
// l-reduction deferred to epilogue. NO forced min-occupancy (r14's (512,8) caused
// a 32-VGPR spill catastrophe) — compiler picks ~56-64 VGPR naturally.
// grid(bh=24, qt=36): 24%8==0 -> XCD = bh%8 for all qt (K/V images L2-pinned).
#define BH_OFF  18432                     // Bh: 49 x 65 u16
#define BW_OFFA (BH_OFF + 6372)           // 24804 (49*65*2=6370, +2 align)
#define MS_OFF  (BW_OFFA + 48*65*2)       // 31044
#define LS_OFF  (MS_OFF + 256)            // 31300
__global__ __launch_bounds__(512) void attn_k(
    const float* __restrict__ qb,
    const u16* __restrict__ khi, const u16* __restrict__ klo,
    const u16* __restrict__ vhi,
    const float* __restrict__ rph, const float* __restrict__ rpw,
    u32* __restrict__ aop)
{
  __shared__ __align__(16) char pool[LS_OFF + 256];   // 31556 B
  u16* KhiL = (u16*)pool;              // [64 key][72]
  u16* VhL  = (u16*)(pool + 9216);     // [64 d][72]
  __half* Bh = (__half*)(pool + BH_OFF);   // [49 kh][65 pad]
  __half* Bw = (__half*)(pool + BW_OFFA);  // [48 kw][65 pad]
  float* m_s = (float*)(pool + MS_OFF);    // [64]
  float* l_s = (float*)(pool + LS_OFF);    // [64]
  float* qlds = (float*)pool;              // prologue alias [64][68] f32 (17408B)
  float* o_s  = (float*)pool;              // epilogue alias [64][68] f32

  const int tid  = threadIdx.x;
  const int lane = tid & 63;
  const int wid  = tid >> 6;
  const int g    = lane >> 4;
  const int ql   = lane & 15;
  const int wq   = wid & 3;     // q-group: rows [16*wq, 16*wq+16)
  const int hh   = wid >> 2;    // key-half stream
  const int bh   = blockIdx.x;  // 24
  const int qt   = blockIdx.y;  // 36
  const int s0   = qt * 64;

  // ---- stage Q tile fp32 -> LDS
  {
    int row = tid >> 3, c0 = (tid & 7) * 8;
    const float* src = qb + ((size_t)bh * SEQ + s0 + row) * HD + c0;
    f32x4 v0 = *(const f32x4*)src;
    f32x4 v1 = *(const f32x4*)(src + 4);
    *(f32x4*)&qlds[row * 68 + c0]     = v0;
    *(f32x4*)&qlds[row * 68 + c0 + 4] = v1;
  }
  __syncthreads();

  // ---- Q fragments hi/lo (lane's q = 16*wq + ql)
  s16x8 qfh[2], qfl[2];
  {
    int qrow = wq * 16 + ql;
#pragma unroll
    for (int ds = 0; ds < 2; ds++) {
#pragma unroll
      for (int h2 = 0; h2 < 2; h2++) {
        f32x4 qv = *(const f32x4*)&qlds[qrow * 68 + g * 4 + h2 * 16 + ds * 32];
#pragma unroll
        for (int j = 0; j < 4; j++) {
          u16 hi, lo;
          split2(qv[j], hi, lo);
          qfh[ds][h2 * 4 + j] = (short)hi;
          qfl[ds][h2 * 4 + j] = (short)lo;
        }
      }
    }
  }

  // ---- prefetch tile 0 (K-hi + V only; K-lo is read direct from global)
  const size_t tbK = (size_t)bh * 36 * 4096;
  const int srow = tid >> 3;
  const int sch  = ((tid & 7) - (srow & 7)) & 7;
  const size_t soff = (size_t)srow * 64 + sch * 8;
  uint4 rkh = *(const uint4*)(khi + tbK + soff);
  uint4 rvh = *(const uint4*)(vhi + tbK + soff);

  // ---- decomposed rel-pos bias tables (fp16, stride 65)
  for (int i = tid; i < 64 * 96; i += 512) {
    int q = i / 96, j = i - (i / 96) * 96;
    int s = s0 + q;
    int qhg = s / 48, qw = s - qhg * 48;
    const float* tab;
    int ridx, col;
    if (j < 48) { col = j;      ridx = qhg - j + 47;        tab = rph; }
    else        { col = j - 48; ridx = qw - (j - 48) + 47;  tab = rpw; }
    const float* rp = tab + (size_t)ridx * HD;
    const float* qp = &qlds[q * 68];
    float s1 = 0.f;
#pragma unroll 4
    for (int d = 0; d < 64; d += 4) {
      f32x4 a = *(const f32x4*)(qp + d);
      f32x4 bv = *(const f32x4*)(rp + d);
      s1 += a[0]*bv[0] + a[1]*bv[1] + a[2]*bv[2] + a[3]*bv[3];
    }
    if (j < 48) Bh[col * 65 + q] = __float2half_rn(s1);
    else        Bw[col * 65 + q] = __float2half_rn(s1);
  }

  float m_r = -3.0e38f, l_r = 0.f;   // l_r is PER-LANE partial (reduced in epilogue)
  f32x4 oacc[4] = {};   // O[q = 4g+r][d = ql + 16*dt]
  const int q64b = wq * 16 + ql;

  for (int kt = 0; kt < 36; kt++) {
    __syncthreads();
    *(uint4*)(KhiL + srow * 72 + sch * 8) = rkh;
    *(uint4*)(VhL  + srow * 72 + sch * 8) = rvh;
    __syncthreads();
    if (kt < 35) {     // T14: issue next-tile loads; land under MFMA phase
      size_t tb2 = tbK + (size_t)(kt + 1) * 4096;
      rkh = *(const uint4*)(khi + tb2 + soff);
      rvh = *(const uint4*)(vhi + tb2 + soff);
    }
    const size_t tb = tbK + (size_t)kt * 4096;

    // ---- QK^T (swapped): S^T[key][q]; K-hi frag from LDS, K-lo frag from global
    f32x4 sacc[2] = {};
    __builtin_amdgcn_s_setprio(1);
#pragma unroll
    for (int ds = 0; ds < 2; ds++) {
#pragma unroll
      for (int t2 = 0; t2 < 2; t2++) {
        int row = (hh * 2 + t2) * 16 + ql;
        s16x8 al = *(const s16x8*)(klo + tb + (size_t)row * 64 + ds * 32 + g * 8);
        s16x8 af = *(const s16x8*)(KhiL + row * 72 + ds * 32 + g * 8);
        sacc[t2] = __builtin_amdgcn_mfma_f32_16x16x32_bf16(af, qfh[ds], sacc[t2], 0, 0, 0);
        sacc[t2] = __builtin_amdgcn_mfma_f32_16x16x32_bf16(af, qfl[ds], sacc[t2], 0, 0, 0);
        sacc[t2] = __builtin_amdgcn_mfma_f32_16x16x32_bf16(al, qfh[ds], sacc[t2], 0, 0, 0);
      }
    }
    __builtin_amdgcn_s_setprio(0);

    // ---- bias gather: kh in {kh0,kh0+1} within a half-tile
    u32 kg0 = (u32)(kt * 64 + hh * 32);
    u32 kh0 = kg0 / 48u;
    int kw0 = (int)(kg0 - kh0 * 48u);
    float bh0 = __half2float(Bh[kh0 * 65 + q64b]);
    float bh1 = __half2float(Bh[(kh0 + 1) * 65 + q64b]);
    float lg[8];
    float tmax = -3.0e38f;
#pragma unroll
    for (int t2 = 0; t2 < 2; t2++)
#pragma unroll
      for (int r = 0; r < 4; r++) {
        int j = t2 * 4 + r;
        int w = kw0 + t2 * 16 + g * 4 + r;
        bool wrap = w >= 48;
        float bw = __half2float(Bw[(wrap ? w - 48 : w) * 65 + q64b]);
        float x = sacc[t2][r] * 0.125f + (wrap ? bh1 : bh0) + bw;
        lg[j] = x;
        tmax = fmaxf(tmax, x);
      }
    tmax = fmaxf(tmax, __shfl_xor(tmax, 16));
    tmax = fmaxf(tmax, __shfl_xor(tmax, 32));
    if (__any(tmax > m_r + 6.0f)) {   // T13 defer-max
      float mnew = fmaxf(m_r, tmax);
      float corr = __expf(m_r - mnew);
      l_r *= corr;                    // corr identical across g-lanes: per-lane ok
      m_r = mnew;
      float cq[4];
#pragma unroll
      for (int r = 0; r < 4; r++) cq[r] = __shfl(corr, g * 4 + r);
#pragma unroll
      for (int dt = 0; dt < 4; dt++)
#pragma unroll
        for (int r = 0; r < 4; r++) oacc[dt][r] *= cq[r];
    }
    float psum = 0.f;
    s16x8 pfh;
#pragma unroll
    for (int j = 0; j < 8; j++) {
      float p = __expf(lg[j] - m_r);
      psum += p;
      pfh[j] = (short)(u16)(__float_as_uint(p) >> 16);
    }
    l_r += psum;   // per-lane partial; cross-g reduction deferred to epilogue

    // ---- PV: single MFMA per dt
    __builtin_amdgcn_s_setprio(1);
#pragma unroll
    for (int dt = 0; dt < 4; dt++) {
      int row = ql + 16 * dt;
      s16x8 bhf = *(const s16x8*)(VhL + row * 72 + hh * 32 + g * 8);
      oacc[dt] = __builtin_amdgcn_mfma_f32_16x16x32_bf16(pfh, bhf, oacc[dt], 0, 0, 0);
    }
    __builtin_amdgcn_s_setprio(0);
  }

  // ---- reduce per-lane l across the 4 g-lanes (deferred from the main loop)
  l_r += __shfl_xor(l_r, 16);
  l_r += __shfl_xor(l_r, 32);

  // ---- merge the two key-streams per q-group, write out (packed u32 hi|lo)
  __syncthreads();
  if (hh == 1) {
    if (g == 0) { m_s[q64b] = m_r; l_s[q64b] = l_r; }
#pragma unroll
    for (int dt = 0; dt < 4; dt++)
#pragma unroll
      for (int r = 0; r < 4; r++)
        o_s[(wq * 16 + g * 4 + r) * 68 + ql + 16 * dt] = oacc[dt][r];
  }
  __syncthreads();
  if (hh == 0) {
    float m2 = m_s[q64b];
    float l2 = l_s[q64b];
    float mf = fmaxf(m_r, m2);
    float c1 = __expf(m_r - mf);
    float c2 = __expf(m2 - mf);
    float lf = l_r * c1 + l2 * c2;
    float c1q[4], c2q[4], lfq[4];
#pragma unroll
    for (int r = 0; r < 4; r++) {
      c1q[r] = __shfl(c1, g * 4 + r);
      c2q[r] = __shfl(c2, g * 4 + r);
      lfq[r] = __shfl(lf, g * 4 + r);
    }
    const int b = bh / 12, head = bh - (bh / 12) * 12;
#pragma unroll
    for (int dt = 0; dt < 4; dt++)
#pragma unroll
      for (int r = 0; r < 4; r++) {
        float oo = oacc[dt][r] * c1q[r]
                 + o_s[(wq * 16 + g * 4 + r) * 68 + ql + 16 * dt] * c2q[r];
        float on = oo / lfq[r];
        int s = s0 + wq * 16 + g * 4 + r;
        size_t idx = ((size_t)b * SEQ + s) * 768 + head * 64 + ql + 16 * dt;
        u16 h, l;
        split2(on, h, l);
        aop[idx] = (u32)h | ((u32)l << 16);
      }
  }
}

// ---------------- proj GEMM via split-bf16 MFMA (A = packed u32 hi|lo): -> out
__global__ __launch_bounds__(256) void proj_mfma_k(
    const u32* __restrict__ aop,
    const u16* __restrict__ bthi, const u16* __restrict__ btlo,
    const float* __restrict__ bias, float* __restrict__ out)
{
  __shared__ __align__(16) u16 Ah[128*40], Al[128*40], Bh2[128*40], Bl2[128*40];
  const int tid = threadIdx.x;
  const int lane = tid & 63, wid = tid >> 6;
  const int g = lane >> 4, ql = lane & 15;
  const int wr = wid >> 1, wc = wid & 1;
  const int c0 = blockIdx.x * 128, r0 = blockIdx.y * 128;
  const int srow = tid >> 1, half = tid & 1;

  const u32* ag = aop + (size_t)(r0 + srow) * 768 + half * 16;
  const u16* bgh = bthi + (size_t)(c0 + srow) * 768 + half * 16;
  const u16* bgl = btlo + (size_t)(c0 + srow) * 768 + half * 16;

  uint4 paw[4]; uint4 pbh[2], pbl[2];
#pragma unroll
  for (int j = 0; j < 4; j++) paw[j] = *(const uint4*)(ag + j * 4);
  pbh[0] = *(const uint4*)bgh; pbh[1] = *(const uint4*)(bgh + 8);
  pbl[0] = *(const uint4*)bgl; pbl[1] = *(const uint4*)(bgl + 8);

  f32x4 acc[4][4] = {};

  for (int ks = 0; ks < 24; ks++) {
    __syncthreads();
    {
      u16 hb[16], lb[16];
      const u32* pw = (const u32*)&paw[0];
#pragma unroll
      for (int j = 0; j < 16; j++) {
        hb[j] = (u16)(pw[j] & 0xffffu);
        lb[j] = (u16)(pw[j] >> 16);
      }
      u16* d1 = Ah + srow * 40 + half * 16;
      u16* d2 = Al + srow * 40 + half * 16;
      u16* d3 = Bh2 + srow * 40 + half * 16;
      u16* d4 = Bl2 + srow * 40 + half * 16;
      *(uint4*)d1 = *(uint4*)&hb[0]; *(uint4*)(d1 + 8) = *(uint4*)&hb[8];
      *(uint4*)d2 = *(uint4*)&lb[0]; *(uint4*)(d2 + 8) = *(uint4*)&lb[8];
      *(uint4*)d3 = pbh[0]; *(uint4*)(d3 + 8) = pbh[1];
      *(uint4*)d4 = pbl[0]; *(uint4*)(d4 + 8) = pbl[1];
    }
    __syncthreads();
    if (ks < 23) {
      const int o = (ks + 1) * 32;
#pragma unroll
      for (int j = 0; j < 4; j++) paw[j] = *(const uint4*)(ag + o + j * 4);
      pbh[0] = *(const uint4*)(bgh + o); pbh[1] = *(const uint4*)(bgh + o + 8);
      pbl[0] = *(const uint4*)(bgl + o); pbl[1] = *(const uint4*)(bgl + o + 8);
    }
    s16x8 bfh[4], bfl[4];
#pragma unroll
    for (int nt = 0; nt < 4; nt++) {
      bfh[nt] = *(const s16x8*)(Bh2 + (wc * 64 + nt * 16 + ql) * 40 + g * 8);
      bfl[nt] = *(const s16x8*)(Bl2 + (wc * 64 + nt * 16 + ql) * 40 + g * 8);
    }
#pragma unroll
    for (int mt = 0; mt < 4; mt++) {
      s16x8 ah = *(const s16x8*)(Ah + (wr * 64 + mt * 16 + ql) * 40 + g * 8);
      s16x8 al = *(const s16x8*)(Al + (wr * 64 + mt * 16 + ql) * 40 + g * 8);
#pragma unroll
      for (int nt = 0; nt < 4; nt++) {
        acc[mt][nt] = __builtin_amdgcn_mfma_f32_16x16x32_bf16(ah, bfh[nt], acc[mt][nt], 0, 0, 0);
        acc[mt][nt] = __builtin_amdgcn_mfma_f32_16x16x32_bf16(ah, bfl[nt], acc[mt][nt], 0, 0, 0);
        acc[mt][nt] = __builtin_amdgcn_mfma_f32_16x16x32_bf16(al, bfh[nt], acc[mt][nt], 0, 0, 0);
      }
    }
  }
  const int col0 = c0 + wc * 64;
  const int row0 = r0 + wr * 64;
  float bb[4];
#pragma unroll
  for (int nt = 0; nt < 4; nt++) bb[nt] = bias[col0 + nt * 16 + ql];
#pragma unroll
  for (int mt = 0; mt < 4; mt++)
#pragma unroll
    for (int nt = 0; nt < 4; nt++)
#pragma unroll
      for (int r = 0; r < 4; r++)
        out[(size_t)(row0 + mt * 16 + g * 4 + r) * 768 + col0 + nt * 16 + ql] =
            acc[mt][nt][r] + bb[nt];
}

extern "C" void kernel_launch(void* const* d_in, const int* in_sizes, int n_in,
                              void* d_out, int out_size, void* d_ws, size_t ws_size,
                              hipStream_t stream) {
  const float* x      = (const float*)d_in[0];
  const float* qkv_w  = (const float*)d_in[1];
  const float* qkv_b  = (const float*)d_in[2];
  const float* proj_w = (const float*)d_in[3];
  const float* proj_b = (const float*)d_in[4];
  const float* rph    = (const float*)d_in[5];
  const float* rpw    = (const float*)d_in[6];
  float* out = (float*)d_out;
  float* ws  = (float*)d_ws;

  const size_t SZ = (size_t)24 * SEQ * HD;   // 3,538,944 elems (== 4608*768)
  float* qbuf = ws;                          // SZ f32
  u16* khi = (u16*)(ws + SZ);                // khi, klo, vhi (+dead slot)
  u16* klo = khi + SZ;
  u16* vhi = klo + SZ;
  u16* xhi = (u16*)(ws + 3 * SZ);            // 2 x SZ u16
  u16* xlo = xhi + SZ;
  u32* aop = (u32*)(ws + 4 * SZ);            // SZ u32 (packed hi|lo)
  u16* wqThi = (u16*)(ws + 5 * SZ);          // 768*2304 x2
  u16* wqTlo = wqThi + 768 * 2304;
  u16* wpThi = wqTlo + 768 * 2304;           // 768*768 x2
  u16* wpTlo = wpThi + 768 * 768;

  conv_split_k<<<1728, 256, 0, stream>>>(x, xhi, xlo);
  conv_wT_k <<<dim3(36, 12), 256, 0, stream>>>(qkv_w, wqThi, wqTlo, 768, 2304);
  conv_wT_k <<<dim3(12, 12), 256, 0, stream>>>(proj_w, wpThi, wpTlo, 768, 768);
  qkv_mfma_k<<<dim3(18, 36), 256, 0, stream>>>(xhi, xlo, wqThi, wqTlo, qkv_b,
                                               qbuf, khi, klo, vhi);
  attn_k    <<<dim3(24, 36), 512, 0, stream>>>(qbuf, khi, klo, vhi, rph, rpw, aop);
  proj_mfma_k<<<dim3(6, 36), 256, 0, stream>>>(aop, wpThi, wpTlo, proj_b, out);
}

// Round 16
// 520.646 us; speedup vs baseline: 1.5148x; 1.0313x over previous
//
#include <hip/hip_runtime.h>
#include <hip/hip_fp16.h>

#define HD 64
#define SEQ 2304

typedef unsigned short u16;
typedef unsigned int u32;
using f32x4 = __attribute__((ext_vector_type(4))) float;
using s16x8 = __attribute__((ext_vector_type(8))) short;

static __device__ __forceinline__ float bf2f(u16 h) {
  union { float f; u32 u; } a; a.u = ((u32)h) << 16; return a.f;
}
// truncation split: x ~= hi + lo, |err| ~ 2^-16 |x|
static __device__ __forceinline__ void split2(float x, u16& h, u16& l) {
  u32 u = __float_as_uint(x);
  h = (u16)(u >> 16);
  float r = x - __uint_as_float(u & 0xffff0000u);
  l = (u16)(__float_as_uint(r) >> 16);
}
// round-to-nearest-even bf16 (unbiased: used for V which is consumed hi-only)
static __device__ __forceinline__ u16 rne_bf16(float x) {
  u32 u = __float_as_uint(x);
  return (u16)((u + 0x7fffu + ((u >> 16) & 1u)) >> 16);
}

// ---------------- split fp32 -> bf16 hi/lo, 8 elems/thread
__global__ __launch_bounds__(256) void conv_split_k(
    const float* __restrict__ src, u16* __restrict__ dhi, u16* __restrict__ dlo)
{
  const size_t i = ((size_t)blockIdx.x * 256 + threadIdx.x) * 8;
  f32x4 a = *(const f32x4*)(src + i);
  f32x4 b = *(const f32x4*)(src + i + 4);
  u16 h[8], l[8];
#pragma unroll
  for (int j = 0; j < 8; j++) {
    float x = j < 4 ? a[j] : b[j - 4];
    split2(x, h[j], l[j]);
  }
  *(uint4*)(dhi + i) = *(uint4*)&h[0];
  *(uint4*)(dlo + i) = *(uint4*)&l[0];
}

// ---------------- convert + transpose weights: w[K][N] f32 -> wT[N][K] bf16 hi/lo
__global__ __launch_bounds__(256) void conv_wT_k(
    const float* __restrict__ src, u16* __restrict__ dhi, u16* __restrict__ dlo,
    int K, int N)
{
  __shared__ u32 t[64][65];
  const int tid = threadIdx.x;
  const int n0 = blockIdx.x * 64, k0 = blockIdx.y * 64;
  const int r = tid >> 2, c0 = (tid & 3) * 16;
  const float* sp = src + (size_t)(k0 + r) * N + n0 + c0;
#pragma unroll
  for (int j = 0; j < 16; j += 4) {
    f32x4 v = *(const f32x4*)(sp + j);
#pragma unroll
    for (int e = 0; e < 4; e++) {
      u16 h, l;
      split2(v[e], h, l);
      t[r][c0 + j + e] = (u32)h | ((u32)l << 16);
    }
  }
  __syncthreads();
  u16 hb[16], lb[16];
#pragma unroll
  for (int j = 0; j < 16; j++) {
    u32 p = t[c0 + j][r];
    hb[j] = (u16)(p & 0xffffu);
    lb[j] = (u16)(p >> 16);
  }
  size_t off = (size_t)(n0 + r) * K + k0 + c0;
  *(uint4*)(dhi + off)     = *(uint4*)&hb[0];
  *(uint4*)(dhi + off + 8) = *(uint4*)&hb[8];
  *(uint4*)(dlo + off)     = *(uint4*)&lb[0];
  *(uint4*)(dlo + off + 8) = *(uint4*)&lb[8];
}

// ---- direct-fragment helpers (qkv): 16 global b128 loads / 48 MFMAs per K-step
static __device__ __forceinline__ void load16(
    const u16* pAh, const u16* pAl, const u16* pBh, const u16* pBl, int kk,
    s16x8 ah[4], s16x8 al[4], s16x8 bh[4], s16x8 bl[4])
{
#pragma unroll
  for (int mt = 0; mt < 4; mt++) {
    size_t o = (size_t)mt * 12288 + (size_t)kk * 32;   // mt*16 rows, kk*32 cols
    ah[mt] = *(const s16x8*)(pAh + o);
    al[mt] = *(const s16x8*)(pAl + o);
    bh[mt] = *(const s16x8*)(pBh + o);
    bl[mt] = *(const s16x8*)(pBl + o);
  }
}
static __device__ __forceinline__ void mfma48(
    const s16x8 ah[4], const s16x8 al[4], const s16x8 bh[4], const s16x8 bl[4],
    f32x4 acc[4][4])
{
#pragma unroll
  for (int mt = 0; mt < 4; mt++)
#pragma unroll
    for (int nt = 0; nt < 4; nt++) {
      acc[mt][nt] = __builtin_amdgcn_mfma_f32_16x16x32_bf16(ah[mt], bh[nt], acc[mt][nt], 0, 0, 0);
      acc[mt][nt] = __builtin_amdgcn_mfma_f32_16x16x32_bf16(ah[mt], bl[nt], acc[mt][nt], 0, 0, 0);
      acc[mt][nt] = __builtin_amdgcn_mfma_f32_16x16x32_bf16(al[mt], bh[nt], acc[mt][nt], 0, 0, 0);
    }
}

// ---------------- QKV GEMM, barrier-free direct-fragment: -> q fp32 + K (hi/lo) +
// V (single RNE bf16) images
__global__ __launch_bounds__(256, 2) void qkv_mfma_k(
    const u16* __restrict__ xhi, const u16* __restrict__ xlo,
    const u16* __restrict__ bthi, const u16* __restrict__ btlo,
    const float* __restrict__ bias,
    float* __restrict__ qbuf, u16* __restrict__ khi, u16* __restrict__ klo,
    u16* __restrict__ vhi)
{
  __shared__ __align__(16) u16 img[4][4096];   // epilogue only (wave-private)
  const int tid = threadIdx.x;
  const int lane = tid & 63, wid = tid >> 6;
  const int g = lane >> 4, ql = lane & 15;
  const int wr = wid >> 1, wc = wid & 1;
  const int c0 = blockIdx.x * 128, r0 = blockIdx.y * 128;

  const u16* pAh = xhi  + (size_t)(r0 + wr * 64 + ql) * 768 + g * 8;
  const u16* pAl = xlo  + (size_t)(r0 + wr * 64 + ql) * 768 + g * 8;
  const u16* pBh = bthi + (size_t)(c0 + wc * 64 + ql) * 768 + g * 8;
  const u16* pBl = btlo + (size_t)(c0 + wc * 64 + ql) * 768 + g * 8;

  s16x8 Xah[4], Xal[4], Xbh[4], Xbl[4];
  s16x8 Yah[4], Yal[4], Ybh[4], Ybl[4];
  f32x4 acc[4][4] = {};

  load16(pAh, pAl, pBh, pBl, 0, Xah, Xal, Xbh, Xbl);
  for (int ks = 0; ks < 24; ks += 2) {
    load16(pAh, pAl, pBh, pBl, ks + 1, Yah, Yal, Ybh, Ybl);
    mfma48(Xah, Xal, Xbh, Xbl, acc);
    if (ks + 2 < 24)
      load16(pAh, pAl, pBh, pBl, ks + 2, Xah, Xal, Xbh, Xbl);
    mfma48(Yah, Yal, Ybh, Ybl, acc);
  }

  // ---- epilogue: q fp32 scatter / K,V permuted tile-images via LDS (wave-private)
  const int col0 = c0 + wc * 64;
  const int row0 = r0 + wr * 64;
  const int hb36 = col0 >> 6;
  const int which = hb36 / 12, head = hb36 - (hb36 / 12) * 12;
  const int b = row0 / 2304;
  const int sb = row0 - b * 2304;
  const int bh = b * 12 + head;
  float bb[4];
#pragma unroll
  for (int nt = 0; nt < 4; nt++) bb[nt] = bias[col0 + nt * 16 + ql];
#pragma unroll
  for (int mt = 0; mt < 4; mt++)
#pragma unroll
    for (int nt = 0; nt < 4; nt++)
#pragma unroll
      for (int r = 0; r < 4; r++)
        acc[mt][nt][r] += bb[nt];

  if (which == 0) {
#pragma unroll
    for (int mt = 0; mt < 4; mt++)
#pragma unroll
      for (int nt = 0; nt < 4; nt++)
#pragma unroll
        for (int r = 0; r < 4; r++) {
          int s = sb + mt * 16 + g * 4 + r;
          qbuf[((size_t)bh * SEQ + s) * 64 + nt * 16 + ql] = acc[mt][nt][r];
        }
  } else if (which == 1) {
    const int kt = sb >> 6;
    const size_t tile = ((size_t)bh * 36 + kt) * 4096;
    u16* const reg = img[wid];
    // pass 1: HI
#pragma unroll
    for (int mt = 0; mt < 4; mt++)
#pragma unroll
      for (int nt = 0; nt < 4; nt++) {
        int pcK = (nt >> 1) * 32 + (ql >> 2) * 8 + (nt & 1) * 4 + (ql & 3);
#pragma unroll
        for (int r = 0; r < 4; r++) {
          u16 h, l;
          split2(acc[mt][nt][r], h, l);
          reg[(mt * 16 + g * 4 + r) * 64 + pcK] = h;
        }
      }
    {
      const u16* src = reg + lane * 64;
      u16* dst = khi + tile + lane * 64;
#pragma unroll
      for (int j = 0; j < 8; j++)
        *(uint4*)(dst + j * 8) = *(const uint4*)(src + j * 8);
    }
    // pass 2: LO
#pragma unroll
    for (int mt = 0; mt < 4; mt++)
#pragma unroll
      for (int nt = 0; nt < 4; nt++) {
        int pcK = (nt >> 1) * 32 + (ql >> 2) * 8 + (nt & 1) * 4 + (ql & 3);
#pragma unroll
        for (int r = 0; r < 4; r++) {
          u16 h, l;
          split2(acc[mt][nt][r], h, l);
          reg[(mt * 16 + g * 4 + r) * 64 + pcK] = l;
        }
      }
    {
      const u16* src = reg + lane * 64;
      u16* dst = klo + tile + lane * 64;
#pragma unroll
      for (int j = 0; j < 8; j++)
        *(uint4*)(dst + j * 8) = *(const uint4*)(src + j * 8);
    }
  } else {
    // V image: single pass, RNE bf16 (consumed hi-only; RNE kills truncation bias)
    const int kt = sb >> 6;
    const size_t tile = ((size_t)bh * 36 + kt) * 4096;
    u16* const reg = img[wid];
#pragma unroll
    for (int mt = 0; mt < 4; mt++)
#pragma unroll
      for (int nt = 0; nt < 4; nt++)
#pragma unroll
        for (int r = 0; r < 4; r++) {
          int off = (nt * 16 + ql) * 64 + (mt >> 1) * 32 + g * 8 + (mt & 1) * 4 + r;
          reg[off] = rne_bf16(acc[mt][nt][r]);
        }
    {
      const u16* src = reg + lane * 64;
      u16* dst = vhi + tile + lane * 64;
#pragma unroll
      for (int j = 0; j < 8; j++)
        *(uint4*)(dst + j * 8) = *(const uint4*)(src + j * 8);
    }
  }
}

// ---------------- Fused attention: 64 q-rows/block, 864 blocks. LDS stages K-hi + V;
// K-lo FRAGMENTS prefetched into registers ONE TILE AHEAD (T14 on the fragment:
// r15's in-loop global load put ~200cyc L2 latency on the QK chain — issuing at
// kt for kt+1 gives a full tile of slack). l-reduction deferred to epilogue.
// grid(bh=24, qt=36): 24%8==0 -> XCD = bh%8 for all qt (K/V images L2-pinned).
#define BH_OFF  18432                     // Bh: 49 x 65 u16
#define BW_OFFA (BH_OFF + 6372)           // 24804 (49*65*2=6370, +2 align)
#define MS_OFF  (BW_OFFA + 48*65*2)       // 31044
#define LS_OFF  (MS_OFF + 256)            // 31300
__global__ __launch_bounds__(512) void attn_k(
    const float* __restrict__ qb,
    const u16* __restrict__ khi, const u16* __restrict__ klo,
    const u16* __restrict__ vhi,
    const float* __restrict__ rph, const float* __restrict__ rpw,
    u32* __restrict__ aop)
{
  __shared__ __align__(16) char pool[LS_OFF + 256];   // 31556 B
  u16* KhiL = (u16*)pool;              // [64 key][72]
  u16* VhL  = (u16*)(pool + 9216);     // [64 d][72]
  __half* Bh = (__half*)(pool + BH_OFF);   // [49 kh][65 pad]
  __half* Bw = (__half*)(pool + BW_OFFA);  // [48 kw][65 pad]
  float* m_s = (float*)(pool + MS_OFF);    // [64]
  float* l_s = (float*)(pool + LS_OFF);    // [64]
  float* qlds = (float*)pool;              // prologue alias [64][68] f32 (17408B)
  float* o_s  = (float*)pool;              // epilogue alias [64][68] f32

  const int tid  = threadIdx.x;
  const int lane = tid & 63;
  const int wid  = tid >> 6;
  const int g    = lane >> 4;
  const int ql   = lane & 15;
  const int wq   = wid & 3;     // q-group: rows [16*wq, 16*wq+16)
  const int hh   = wid >> 2;    // key-half stream
  const int bh   = blockIdx.x;  // 24
  const int qt   = blockIdx.y;  // 36
  const int s0   = qt * 64;

  // ---- stage Q tile fp32 -> LDS
  {
    int row = tid >> 3, c0 = (tid & 7) * 8;
    const float* src = qb + ((size_t)bh * SEQ + s0 + row) * HD + c0;
    f32x4 v0 = *(const f32x4*)src;
    f32x4 v1 = *(const f32x4*)(src + 4);
    *(f32x4*)&qlds[row * 68 + c0]     = v0;
    *(f32x4*)&qlds[row * 68 + c0 + 4] = v1;
  }
  __syncthreads();

  // ---- Q fragments hi/lo (lane's q = 16*wq + ql)
  s16x8 qfh[2], qfl[2];
  {
    int qrow = wq * 16 + ql;
#pragma unroll
    for (int ds = 0; ds < 2; ds++) {
#pragma unroll
      for (int h2 = 0; h2 < 2; h2++) {
        f32x4 qv = *(const f32x4*)&qlds[qrow * 68 + g * 4 + h2 * 16 + ds * 32];
#pragma unroll
        for (int j = 0; j < 4; j++) {
          u16 hi, lo;
          split2(qv[j], hi, lo);
          qfh[ds][h2 * 4 + j] = (short)hi;
          qfl[ds][h2 * 4 + j] = (short)lo;
        }
      }
    }
  }

  // ---- prefetch tile 0: K-hi + V staging regs, and K-lo FRAGMENTS (per-lane)
  const size_t tbK = (size_t)bh * 36 * 4096;
  const int srow = tid >> 3;
  const int sch  = ((tid & 7) - (srow & 7)) & 7;
  const size_t soff = (size_t)srow * 64 + sch * 8;
  uint4 rkh = *(const uint4*)(khi + tbK + soff);
  uint4 rvh = *(const uint4*)(vhi + tbK + soff);

  // per-lane K-lo fragment offsets (ds-major x t2): row = (hh*2+t2)*16+ql
  size_t loff[2][2];
#pragma unroll
  for (int ds = 0; ds < 2; ds++)
#pragma unroll
    for (int t2 = 0; t2 < 2; t2++)
      loff[ds][t2] = (size_t)((hh * 2 + t2) * 16 + ql) * 64 + ds * 32 + g * 8;
  s16x8 ral[2][2];
#pragma unroll
  for (int ds = 0; ds < 2; ds++)
#pragma unroll
    for (int t2 = 0; t2 < 2; t2++)
      ral[ds][t2] = *(const s16x8*)(klo + tbK + loff[ds][t2]);

  // ---- decomposed rel-pos bias tables (fp16, stride 65)
  for (int i = tid; i < 64 * 96; i += 512) {
    int q = i / 96, j = i - (i / 96) * 96;
    int s = s0 + q;
    int qhg = s / 48, qw = s - qhg * 48;
    const float* tab;
    int ridx, col;
    if (j < 48) { col = j;      ridx = qhg - j + 47;        tab = rph; }
    else        { col = j - 48; ridx = qw - (j - 48) + 47;  tab = rpw; }
    const float* rp = tab + (size_t)ridx * HD;
    const float* qp = &qlds[q * 68];
    float s1 = 0.f;
#pragma unroll 4
    for (int d = 0; d < 64; d += 4) {
      f32x4 a = *(const f32x4*)(qp + d);
      f32x4 bv = *(const f32x4*)(rp + d);
      s1 += a[0]*bv[0] + a[1]*bv[1] + a[2]*bv[2] + a[3]*bv[3];
    }
    if (j < 48) Bh[col * 65 + q] = __float2half_rn(s1);
    else        Bw[col * 65 + q] = __float2half_rn(s1);
  }

  float m_r = -3.0e38f, l_r = 0.f;   // l_r is PER-LANE partial (reduced in epilogue)
  f32x4 oacc[4] = {};   // O[q = 4g+r][d = ql + 16*dt]
  const int q64b = wq * 16 + ql;

  for (int kt = 0; kt < 36; kt++) {
    __syncthreads();
    *(uint4*)(KhiL + srow * 72 + sch * 8) = rkh;
    *(uint4*)(VhL  + srow * 72 + sch * 8) = rvh;
    __syncthreads();
    if (kt < 35) {     // T14: issue next-tile staging loads; land under MFMA phase
      size_t tb2 = tbK + (size_t)(kt + 1) * 4096;
      rkh = *(const uint4*)(khi + tb2 + soff);
      rvh = *(const uint4*)(vhi + tb2 + soff);
    }

    // ---- QK^T (swapped): S^T[key][q]; K-hi frag from LDS, K-lo frag from regs
    f32x4 sacc[2] = {};
    __builtin_amdgcn_s_setprio(1);
#pragma unroll
    for (int ds = 0; ds < 2; ds++) {
#pragma unroll
      for (int t2 = 0; t2 < 2; t2++) {
        int row = (hh * 2 + t2) * 16 + ql;
        s16x8 af = *(const s16x8*)(KhiL + row * 72 + ds * 32 + g * 8);
        sacc[t2] = __builtin_amdgcn_mfma_f32_16x16x32_bf16(af, qfh[ds], sacc[t2], 0, 0, 0);
        sacc[t2] = __builtin_amdgcn_mfma_f32_16x16x32_bf16(af, qfl[ds], sacc[t2], 0, 0, 0);
        sacc[t2] = __builtin_amdgcn_mfma_f32_16x16x32_bf16(ral[ds][t2], qfh[ds], sacc[t2], 0, 0, 0);
      }
    }
    __builtin_amdgcn_s_setprio(0);

    // ---- reload K-lo fragments for kt+1 (consumed next tile: full tile of slack)
    if (kt < 35) {
      const size_t tbn = tbK + (size_t)(kt + 1) * 4096;
#pragma unroll
      for (int ds = 0; ds < 2; ds++)
#pragma unroll
        for (int t2 = 0; t2 < 2; t2++)
          ral[ds][t2] = *(const s16x8*)(klo + tbn + loff[ds][t2]);
    }

    // ---- bias gather: kh in {kh0,kh0+1} within a half-tile
    u32 kg0 = (u32)(kt * 64 + hh * 32);
    u32 kh0 = kg0 / 48u;
    int kw0 = (int)(kg0 - kh0 * 48u);
    float bh0 = __half2float(Bh[kh0 * 65 + q64b]);
    float bh1 = __half2float(Bh[(kh0 + 1) * 65 + q64b]);
    float lg[8];
    float tmax = -3.0e38f;
#pragma unroll
    for (int t2 = 0; t2 < 2; t2++)
#pragma unroll
      for (int r = 0; r < 4; r++) {
        int j = t2 * 4 + r;
        int w = kw0 + t2 * 16 + g * 4 + r;
        bool wrap = w >= 48;
        float bw = __half2float(Bw[(wrap ? w - 48 : w) * 65 + q64b]);
        float x = sacc[t2][r] * 0.125f + (wrap ? bh1 : bh0) + bw;
        lg[j] = x;
        tmax = fmaxf(tmax, x);
      }
    tmax = fmaxf(tmax, __shfl_xor(tmax, 16));
    tmax = fmaxf(tmax, __shfl_xor(tmax, 32));
    if (__any(tmax > m_r + 6.0f)) {   // T13 defer-max
      float mnew = fmaxf(m_r, tmax);
      float corr = __expf(m_r - mnew);
      l_r *= corr;                    // corr identical across g-lanes: per-lane ok
      m_r = mnew;
      float cq[4];
#pragma unroll
      for (int r = 0; r < 4; r++) cq[r] = __shfl(corr, g * 4 + r);
#pragma unroll
      for (int dt = 0; dt < 4; dt++)
#pragma unroll
        for (int r = 0; r < 4; r++) oacc[dt][r] *= cq[r];
    }
    float psum = 0.f;
    s16x8 pfh;
#pragma unroll
    for (int j = 0; j < 8; j++) {
      float p = __expf(lg[j] - m_r);
      psum += p;
      pfh[j] = (short)(u16)(__float_as_uint(p) >> 16);
    }
    l_r += psum;   // per-lane partial; cross-g reduction deferred to epilogue

    // ---- PV: single MFMA per dt
    __builtin_amdgcn_s_setprio(1);
#pragma unroll
    for (int dt = 0; dt < 4; dt++) {
      int row = ql + 16 * dt;
      s16x8 bhf = *(const s16x8*)(VhL + row * 72 + hh * 32 + g * 8);
      oacc[dt] = __builtin_amdgcn_mfma_f32_16x16x32_bf16(pfh, bhf, oacc[dt], 0, 0, 0);
    }
    __builtin_amdgcn_s_setprio(0);
  }

  // ---- reduce per-lane l across the 4 g-lanes (deferred from the main loop)
  l_r += __shfl_xor(l_r, 16);
  l_r += __shfl_xor(l_r, 32);

  // ---- merge the two key-streams per q-group, write out (packed u32 hi|lo)
  __syncthreads();
  if (hh == 1) {
    if (g == 0) { m_s[q64b] = m_r; l_s[q64b] = l_r; }
#pragma unroll
    for (int dt = 0; dt < 4; dt++)
#pragma unroll
      for (int r = 0; r < 4; r++)
        o_s[(wq * 16 + g * 4 + r) * 68 + ql + 16 * dt] = oacc[dt][r];
  }
  __syncthreads();
  if (hh == 0) {
    float m2 = m_s[q64b];
    float l2 = l_s[q64b];
    float mf = fmaxf(m_r, m2);
    float c1 = __expf(m_r - mf);
    float c2 = __expf(m2 - mf);
    float lf = l_r * c1 + l2 * c2;
    float c1q[4], c2q[4], lfq[4];
#pragma unroll
    for (int r = 0; r < 4; r++) {
      c1q[r] = __shfl(c1, g * 4 + r);
      c2q[r] = __shfl(c2, g * 4 + r);
      lfq[r] = __shfl(lf, g * 4 + r);
    }
    const int b = bh / 12, head = bh - (bh / 12) * 12;
#pragma unroll
    for (int dt = 0; dt < 4; dt++)
#pragma unroll
      for (int r = 0; r < 4; r++) {
        float oo = oacc[dt][r] * c1q[r]
                 + o_s[(wq * 16 + g * 4 + r) * 68 + ql + 16 * dt] * c2q[r];
        float on = oo / lfq[r];
        int s = s0 + wq * 16 + g * 4 + r;
        size_t idx = ((size_t)b * SEQ + s) * 768 + head * 64 + ql + 16 * dt;
        u16 h, l;
        split2(on, h, l);
        aop[idx] = (u32)h | ((u32)l << 16);
      }
  }
}

// ---------------- proj GEMM via split-bf16 MFMA (A = packed u32 hi|lo): -> out
__global__ __launch_bounds__(256) void proj_mfma_k(
    const u32* __restrict__ aop,
    const u16* __restrict__ bthi, const u16* __restrict__ btlo,
    const float* __restrict__ bias, float* __restrict__ out)
{
  __shared__ __align__(16) u16 Ah[128*40], Al[128*40], Bh2[128*40], Bl2[128*40];
  const int tid = threadIdx.x;
  const int lane = tid & 63, wid = tid >> 6;
  const int g = lane >> 4, ql = lane & 15;
  const int wr = wid >> 1, wc = wid & 1;
  const int c0 = blockIdx.x * 128, r0 = blockIdx.y * 128;
  const int srow = tid >> 1, half = tid & 1;

  const u32* ag = aop + (size_t)(r0 + srow) * 768 + half * 16;
  const u16* bgh = bthi + (size_t)(c0 + srow) * 768 + half * 16;
  const u16* bgl = btlo + (size_t)(c0 + srow) * 768 + half * 16;

  uint4 paw[4]; uint4 pbh[2], pbl[2];
#pragma unroll
  for (int j = 0; j < 4; j++) paw[j] = *(const uint4*)(ag + j * 4);
  pbh[0] = *(const uint4*)bgh; pbh[1] = *(const uint4*)(bgh + 8);
  pbl[0] = *(const uint4*)bgl; pbl[1] = *(const uint4*)(bgl + 8);

  f32x4 acc[4][4] = {};

  for (int ks = 0; ks < 24; ks++) {
    __syncthreads();
    {
      u16 hb[16], lb[16];
      const u32* pw = (const u32*)&paw[0];
#pragma unroll
      for (int j = 0; j < 16; j++) {
        hb[j] = (u16)(pw[j] & 0xffffu);
        lb[j] = (u16)(pw[j] >> 16);
      }
      u16* d1 = Ah + srow * 40 + half * 16;
      u16* d2 = Al + srow * 40 + half * 16;
      u16* d3 = Bh2 + srow * 40 + half * 16;
      u16* d4 = Bl2 + srow * 40 + half * 16;
      *(uint4*)d1 = *(uint4*)&hb[0]; *(uint4*)(d1 + 8) = *(uint4*)&hb[8];
      *(uint4*)d2 = *(uint4*)&lb[0]; *(uint4*)(d2 + 8) = *(uint4*)&lb[8];
      *(uint4*)d3 = pbh[0]; *(uint4*)(d3 + 8) = pbh[1];
      *(uint4*)d4 = pbl[0]; *(uint4*)(d4 + 8) = pbl[1];
    }
    __syncthreads();
    if (ks < 23) {
      const int o = (ks + 1) * 32;
#pragma unroll
      for (int j = 0; j < 4; j++) paw[j] = *(const uint4*)(ag + o + j * 4);
      pbh[0] = *(const uint4*)(bgh + o); pbh[1] = *(const uint4*)(bgh + o + 8);
      pbl[0] = *(const uint4*)(bgl + o); pbl[1] = *(const uint4*)(bgl + o + 8);
    }
    s16x8 bfh[4], bfl[4];
#pragma unroll
    for (int nt = 0; nt < 4; nt++) {
      bfh[nt] = *(const s16x8*)(Bh2 + (wc * 64 + nt * 16 + ql) * 40 + g * 8);
      bfl[nt] = *(const s16x8*)(Bl2 + (wc * 64 + nt * 16 + ql) * 40 + g * 8);
    }
#pragma unroll
    for (int mt = 0; mt < 4; mt++) {
      s16x8 ah = *(const s16x8*)(Ah + (wr * 64 + mt * 16 + ql) * 40 + g * 8);
      s16x8 al = *(const s16x8*)(Al + (wr * 64 + mt * 16 + ql) * 40 + g * 8);
#pragma unroll
      for (int nt = 0; nt < 4; nt++) {
        acc[mt][nt] = __builtin_amdgcn_mfma_f32_16x16x32_bf16(ah, bfh[nt], acc[mt][nt], 0, 0, 0);
        acc[mt][nt] = __builtin_amdgcn_mfma_f32_16x16x32_bf16(ah, bfl[nt], acc[mt][nt], 0, 0, 0);
        acc[mt][nt] = __builtin_amdgcn_mfma_f32_16x16x32_bf16(al, bfh[nt], acc[mt][nt], 0, 0, 0);
      }
    }
  }
  const int col0 = c0 + wc * 64;
  const int row0 = r0 + wr * 64;
  float bb[4];
#pragma unroll
  for (int nt = 0; nt < 4; nt++) bb[nt] = bias[col0 + nt * 16 + ql];
#pragma unroll
  for (int mt = 0; mt < 4; mt++)
#pragma unroll
    for (int nt = 0; nt < 4; nt++)
#pragma unroll
      for (int r = 0; r < 4; r++)
        out[(size_t)(row0 + mt * 16 + g * 4 + r) * 768 + col0 + nt * 16 + ql] =
            acc[mt][nt][r] + bb[nt];
}

extern "C" void kernel_launch(void* const* d_in, const int* in_sizes, int n_in,
                              void* d_out, int out_size, void* d_ws, size_t ws_size,
                              hipStream_t stream) {
  const float* x      = (const float*)d_in[0];
  const float* qkv_w  = (const float*)d_in[1];
  const float* qkv_b  = (const float*)d_in[2];
  const float* proj_w = (const float*)d_in[3];
  const float* proj_b = (const float*)d_in[4];
  const float* rph    = (const float*)d_in[5];
  const float* rpw    = (const float*)d_in[6];
  float* out = (float*)d_out;
  float* ws  = (float*)d_ws;

  const size_t SZ = (size_t)24 * SEQ * HD;   // 3,538,944 elems (== 4608*768)
  float* qbuf = ws;                          // SZ f32
  u16* khi = (u16*)(ws + SZ);                // khi, klo, vhi (+dead slot)
  u16* klo = khi + SZ;
  u16* vhi = klo + SZ;
  u16* xhi = (u16*)(ws + 3 * SZ);            // 2 x SZ u16
  u16* xlo = xhi + SZ;
  u32* aop = (u32*)(ws + 4 * SZ);            // SZ u32 (packed hi|lo)
  u16* wqThi = (u16*)(ws + 5 * SZ);          // 768*2304 x2
  u16* wqTlo = wqThi + 768 * 2304;
  u16* wpThi = wqTlo + 768 * 2304;           // 768*768 x2
  u16* wpTlo = wpThi + 768 * 768;

  conv_split_k<<<1728, 256, 0, stream>>>(x, xhi, xlo);
  conv_wT_k <<<dim3(36, 12), 256, 0, stream>>>(qkv_w, wqThi, wqTlo, 768, 2304);
  conv_wT_k <<<dim3(12, 12), 256, 0, stream>>>(proj_w, wpThi, wpTlo, 768, 768);
  qkv_mfma_k<<<dim3(18, 36), 256, 0, stream>>>(xhi, xlo, wqThi, wqTlo, qkv_b,
                                               qbuf, khi, klo, vhi);
  attn_k    <<<dim3(24, 36), 512, 0, stream>>>(qbuf, khi, klo, vhi, rph, rpw, aop);
  proj_mfma_k<<<dim3(6, 36), 256, 0, stream>>>(aop, wpThi, wpTlo, proj_b, out);
}

// Round 17
// 469.381 us; speedup vs baseline: 1.6802x; 1.1092x over previous
//
#include <hip/hip_runtime.h>
#include <hip/hip_fp16.h>

#define HD 64
#define SEQ 2304

typedef unsigned short u16;
typedef unsigned int u32;
using f32x4 = __attribute__((ext_vector_type(4))) float;
using s16x8 = __attribute__((ext_vector_type(8))) short;

static __device__ __forceinline__ float bf2f(u16 h) {
  union { float f; u32 u; } a; a.u = ((u32)h) << 16; return a.f;
}
// truncation split: x ~= hi + lo, |err| ~ 2^-16 |x|
static __device__ __forceinline__ void split2(float x, u16& h, u16& l) {
  u32 u = __float_as_uint(x);
  h = (u16)(u >> 16);
  float r = x - __uint_as_float(u & 0xffff0000u);
  l = (u16)(__float_as_uint(r) >> 16);
}
// round-to-nearest-even bf16 (unbiased: used for V which is consumed hi-only)
static __device__ __forceinline__ u16 rne_bf16(float x) {
  u32 u = __float_as_uint(x);
  return (u16)((u + 0x7fffu + ((u >> 16) & 1u)) >> 16);
}

// ---------------- split fp32 -> bf16 hi/lo, 8 elems/thread
__global__ __launch_bounds__(256) void conv_split_k(
    const float* __restrict__ src, u16* __restrict__ dhi, u16* __restrict__ dlo)
{
  const size_t i = ((size_t)blockIdx.x * 256 + threadIdx.x) * 8;
  f32x4 a = *(const f32x4*)(src + i);
  f32x4 b = *(const f32x4*)(src + i + 4);
  u16 h[8], l[8];
#pragma unroll
  for (int j = 0; j < 8; j++) {
    float x = j < 4 ? a[j] : b[j - 4];
    split2(x, h[j], l[j]);
  }
  *(uint4*)(dhi + i) = *(uint4*)&h[0];
  *(uint4*)(dlo + i) = *(uint4*)&l[0];
}

// ---------------- convert + transpose weights: w[K][N] f32 -> wT[N][K] bf16 hi/lo
__global__ __launch_bounds__(256) void conv_wT_k(
    const float* __restrict__ src, u16* __restrict__ dhi, u16* __restrict__ dlo,
    int K, int N)
{
  __shared__ u32 t[64][65];
  const int tid = threadIdx.x;
  const int n0 = blockIdx.x * 64, k0 = blockIdx.y * 64;
  const int r = tid >> 2, c0 = (tid & 3) * 16;
  const float* sp = src + (size_t)(k0 + r) * N + n0 + c0;
#pragma unroll
  for (int j = 0; j < 16; j += 4) {
    f32x4 v = *(const f32x4*)(sp + j);
#pragma unroll
    for (int e = 0; e < 4; e++) {
      u16 h, l;
      split2(v[e], h, l);
      t[r][c0 + j + e] = (u32)h | ((u32)l << 16);
    }
  }
  __syncthreads();
  u16 hb[16], lb[16];
#pragma unroll
  for (int j = 0; j < 16; j++) {
    u32 p = t[c0 + j][r];
    hb[j] = (u16)(p & 0xffffu);
    lb[j] = (u16)(p >> 16);
  }
  size_t off = (size_t)(n0 + r) * K + k0 + c0;
  *(uint4*)(dhi + off)     = *(uint4*)&hb[0];
  *(uint4*)(dhi + off + 8) = *(uint4*)&hb[8];
  *(uint4*)(dlo + off)     = *(uint4*)&lb[0];
  *(uint4*)(dlo + off + 8) = *(uint4*)&lb[8];
}

// ---- direct-fragment helpers (qkv): 16 global b128 loads / 48 MFMAs per K-step
static __device__ __forceinline__ void load16(
    const u16* pAh, const u16* pAl, const u16* pBh, const u16* pBl, int kk,
    s16x8 ah[4], s16x8 al[4], s16x8 bh[4], s16x8 bl[4])
{
#pragma unroll
  for (int mt = 0; mt < 4; mt++) {
    size_t o = (size_t)mt * 12288 + (size_t)kk * 32;   // mt*16 rows, kk*32 cols
    ah[mt] = *(const s16x8*)(pAh + o);
    al[mt] = *(const s16x8*)(pAl + o);
    bh[mt] = *(const s16x8*)(pBh + o);
    bl[mt] = *(const s16x8*)(pBl + o);
  }
}
static __device__ __forceinline__ void mfma48(
    const s16x8 ah[4], const s16x8 al[4], const s16x8 bh[4], const s16x8 bl[4],
    f32x4 acc[4][4])
{
#pragma unroll
  for (int mt = 0; mt < 4; mt++)
#pragma unroll
    for (int nt = 0; nt < 4; nt++) {
      acc[mt][nt] = __builtin_amdgcn_mfma_f32_16x16x32_bf16(ah[mt], bh[nt], acc[mt][nt], 0, 0, 0);
      acc[mt][nt] = __builtin_amdgcn_mfma_f32_16x16x32_bf16(ah[mt], bl[nt], acc[mt][nt], 0, 0, 0);
      acc[mt][nt] = __builtin_amdgcn_mfma_f32_16x16x32_bf16(al[mt], bh[nt], acc[mt][nt], 0, 0, 0);
    }
}

// ---------------- QKV GEMM, barrier-free direct-fragment: -> q fp32 + K (hi/lo) +
// V (single RNE bf16) images
__global__ __launch_bounds__(256, 2) void qkv_mfma_k(
    const u16* __restrict__ xhi, const u16* __restrict__ xlo,
    const u16* __restrict__ bthi, const u16* __restrict__ btlo,
    const float* __restrict__ bias,
    float* __restrict__ qbuf, u16* __restrict__ khi, u16* __restrict__ klo,
    u16* __restrict__ vhi)
{
  __shared__ __align__(16) u16 img[4][4096];   // epilogue only (wave-private)
  const int tid = threadIdx.x;
  const int lane = tid & 63, wid = tid >> 6;
  const int g = lane >> 4, ql = lane & 15;
  const int wr = wid >> 1, wc = wid & 1;
  const int c0 = blockIdx.x * 128, r0 = blockIdx.y * 128;

  const u16* pAh = xhi  + (size_t)(r0 + wr * 64 + ql) * 768 + g * 8;
  const u16* pAl = xlo  + (size_t)(r0 + wr * 64 + ql) * 768 + g * 8;
  const u16* pBh = bthi + (size_t)(c0 + wc * 64 + ql) * 768 + g * 8;
  const u16* pBl = btlo + (size_t)(c0 + wc * 64 + ql) * 768 + g * 8;

  s16x8 Xah[4], Xal[4], Xbh[4], Xbl[4];
  s16x8 Yah[4], Yal[4], Ybh[4], Ybl[4];
  f32x4 acc[4][4] = {};

  load16(pAh, pAl, pBh, pBl, 0, Xah, Xal, Xbh, Xbl);
  for (int ks = 0; ks < 24; ks += 2) {
    load16(pAh, pAl, pBh, pBl, ks + 1, Yah, Yal, Ybh, Ybl);
    mfma48(Xah, Xal, Xbh, Xbl, acc);
    if (ks + 2 < 24)
      load16(pAh, pAl, pBh, pBl, ks + 2, Xah, Xal, Xbh, Xbl);
    mfma48(Yah, Yal, Ybh, Ybl, acc);
  }

  // ---- epilogue: q fp32 scatter / K,V permuted tile-images via LDS (wave-private)
  const int col0 = c0 + wc * 64;
  const int row0 = r0 + wr * 64;
  const int hb36 = col0 >> 6;
  const int which = hb36 / 12, head = hb36 - (hb36 / 12) * 12;
  const int b = row0 / 2304;
  const int sb = row0 - b * 2304;
  const int bh = b * 12 + head;
  float bb[4];
#pragma unroll
  for (int nt = 0; nt < 4; nt++) bb[nt] = bias[col0 + nt * 16 + ql];
#pragma unroll
  for (int mt = 0; mt < 4; mt++)
#pragma unroll
    for (int nt = 0; nt < 4; nt++)
#pragma unroll
      for (int r = 0; r < 4; r++)
        acc[mt][nt][r] += bb[nt];

  if (which == 0) {
#pragma unroll
    for (int mt = 0; mt < 4; mt++)
#pragma unroll
      for (int nt = 0; nt < 4; nt++)
#pragma unroll
        for (int r = 0; r < 4; r++) {
          int s = sb + mt * 16 + g * 4 + r;
          qbuf[((size_t)bh * SEQ + s) * 64 + nt * 16 + ql] = acc[mt][nt][r];
        }
  } else if (which == 1) {
    const int kt = sb >> 6;
    const size_t tile = ((size_t)bh * 36 + kt) * 4096;
    u16* const reg = img[wid];
    // pass 1: HI
#pragma unroll
    for (int mt = 0; mt < 4; mt++)
#pragma unroll
      for (int nt = 0; nt < 4; nt++) {
        int pcK = (nt >> 1) * 32 + (ql >> 2) * 8 + (nt & 1) * 4 + (ql & 3);
#pragma unroll
        for (int r = 0; r < 4; r++) {
          u16 h, l;
          split2(acc[mt][nt][r], h, l);
          reg[(mt * 16 + g * 4 + r) * 64 + pcK] = h;
        }
      }
    {
      const u16* src = reg + lane * 64;
      u16* dst = khi + tile + lane * 64;
#pragma unroll
      for (int j = 0; j < 8; j++)
        *(uint4*)(dst + j * 8) = *(const uint4*)(src + j * 8);
    }
    // pass 2: LO
#pragma unroll
    for (int mt = 0; mt < 4; mt++)
#pragma unroll
      for (int nt = 0; nt < 4; nt++) {
        int pcK = (nt >> 1) * 32 + (ql >> 2) * 8 + (nt & 1) * 4 + (ql & 3);
#pragma unroll
        for (int r = 0; r < 4; r++) {
          u16 h, l;
          split2(acc[mt][nt][r], h, l);
          reg[(mt * 16 + g * 4 + r) * 64 + pcK] = l;
        }
      }
    {
      const u16* src = reg + lane * 64;
      u16* dst = klo + tile + lane * 64;
#pragma unroll
      for (int j = 0; j < 8; j++)
        *(uint4*)(dst + j * 8) = *(const uint4*)(src + j * 8);
    }
  } else {
    // V image: single pass, RNE bf16 (consumed hi-only; RNE kills truncation bias)
    const int kt = sb >> 6;
    const size_t tile = ((size_t)bh * 36 + kt) * 4096;
    u16* const reg = img[wid];
#pragma unroll
    for (int mt = 0; mt < 4; mt++)
#pragma unroll
      for (int nt = 0; nt < 4; nt++)
#pragma unroll
        for (int r = 0; r < 4; r++) {
          int off = (nt * 16 + ql) * 64 + (mt >> 1) * 32 + g * 8 + (mt & 1) * 4 + r;
          reg[off] = rne_bf16(acc[mt][nt][r]);
        }
    {
      const u16* src = reg + lane * 64;
      u16* dst = vhi + tile + lane * 64;
#pragma unroll
      for (int j = 0; j < 8; j++)
        *(uint4*)(dst + j * 8) = *(const uint4*)(src + j * 8);
    }
  }
}

// ---------------- Fused attention (r13 structure, NO s_setprio): 64 q-rows/block,
// 864 blocks, LDS-staged K (hi/lo) + V (single bf16), split QK^T (3 MFMA),
// single-MFMA PV. A/B vs r13's 309us isolates setprio in 8-wave barrier-synced
// blocks (m190: setprio hurts lockstep structures; m191's win was 1-wave blocks).
// grid(bh=24, qt=36): 24%8==0 -> XCD = bh%8 for all qt (K/V image L2-pinned).
#define BH_OFF 27648                      // Bh: 49 x 65 u16 (row 48 = wrap slack)
#define BW_OFFA 34020                     // 27648 + 49*65*2=6370, +2 align
#define MS_OFF (BW_OFFA + 48*65*2)        // 40260
#define LS_OFF (MS_OFF + 256)             // 40516
__global__ __launch_bounds__(512) void attn_k(
    const float* __restrict__ qb,
    const u16* __restrict__ khi, const u16* __restrict__ klo,
    const u16* __restrict__ vhi,
    const float* __restrict__ rph, const float* __restrict__ rpw,
    u32* __restrict__ aop)
{
  __shared__ __align__(16) char pool[LS_OFF + 256];   // 40772 B
  u16* KhiL = (u16*)pool;              // [64 key][72]
  u16* KloL = (u16*)(pool + 9216);
  u16* VhL  = (u16*)(pool + 18432);    // [64 d][72]
  __half* Bh = (__half*)(pool + BH_OFF);   // [49 kh][65 pad]
  __half* Bw = (__half*)(pool + BW_OFFA);  // [48 kw][65 pad]
  float* m_s = (float*)(pool + MS_OFF);    // [64]
  float* l_s = (float*)(pool + LS_OFF);    // [64]
  float* qlds = (float*)pool;              // prologue alias [64][68] f32 (17408B)
  float* o_s  = (float*)pool;              // epilogue alias [64][68] f32

  const int tid  = threadIdx.x;
  const int lane = tid & 63;
  const int wid  = tid >> 6;
  const int g    = lane >> 4;
  const int ql   = lane & 15;
  const int wq   = wid & 3;     // q-group: rows [16*wq, 16*wq+16)
  const int hh   = wid >> 2;    // key-half stream
  const int bh   = blockIdx.x;  // 24
  const int qt   = blockIdx.y;  // 36
  const int s0   = qt * 64;

  // ---- stage Q tile fp32 -> LDS
  {
    int row = tid >> 3, c0 = (tid & 7) * 8;
    const float* src = qb + ((size_t)bh * SEQ + s0 + row) * HD + c0;
    f32x4 v0 = *(const f32x4*)src;
    f32x4 v1 = *(const f32x4*)(src + 4);
    *(f32x4*)&qlds[row * 68 + c0]     = v0;
    *(f32x4*)&qlds[row * 68 + c0 + 4] = v1;
  }
  __syncthreads();

  // ---- Q fragments hi/lo (lane's q = 16*wq + ql)
  s16x8 qfh[2], qfl[2];
  {
    int qrow = wq * 16 + ql;
#pragma unroll
    for (int ds = 0; ds < 2; ds++) {
#pragma unroll
      for (int h2 = 0; h2 < 2; h2++) {
        f32x4 qv = *(const f32x4*)&qlds[qrow * 68 + g * 4 + h2 * 16 + ds * 32];
#pragma unroll
        for (int j = 0; j < 4; j++) {
          u16 hi, lo;
          split2(qv[j], hi, lo);
          qfh[ds][h2 * 4 + j] = (short)hi;
          qfl[ds][h2 * 4 + j] = (short)lo;
        }
      }
    }
  }

  // ---- prefetch tile 0
  const size_t tbK = (size_t)bh * 36 * 4096;
  const int srow = tid >> 3;
  const int sch  = ((tid & 7) - (srow & 7)) & 7;
  const size_t soff = (size_t)srow * 64 + sch * 8;
  uint4 rkh = *(const uint4*)(khi + tbK + soff);
  uint4 rkl = *(const uint4*)(klo + tbK + soff);
  uint4 rvh = *(const uint4*)(vhi + tbK + soff);

  // ---- decomposed rel-pos bias tables (fp16, stride 65)
  for (int i = tid; i < 64 * 96; i += 512) {
    int q = i / 96, j = i - (i / 96) * 96;
    int s = s0 + q;
    int qhg = s / 48, qw = s - qhg * 48;
    const float* tab;
    int ridx, col;
    if (j < 48) { col = j;      ridx = qhg - j + 47;        tab = rph; }
    else        { col = j - 48; ridx = qw - (j - 48) + 47;  tab = rpw; }
    const float* rp = tab + (size_t)ridx * HD;
    const float* qp = &qlds[q * 68];
    float s1 = 0.f;
#pragma unroll 4
    for (int d = 0; d < 64; d += 4) {
      f32x4 a = *(const f32x4*)(qp + d);
      f32x4 bv = *(const f32x4*)(rp + d);
      s1 += a[0]*bv[0] + a[1]*bv[1] + a[2]*bv[2] + a[3]*bv[3];
    }
    if (j < 48) Bh[col * 65 + q] = __float2half_rn(s1);
    else        Bw[col * 65 + q] = __float2half_rn(s1);
  }

  float m_r = -3.0e38f, l_r = 0.f;
  f32x4 oacc[4] = {};   // O[q = 4g+r][d = ql + 16*dt]
  const int q64b = wq * 16 + ql;

  for (int kt = 0; kt < 36; kt++) {
    __syncthreads();
    *(uint4*)(KhiL + srow * 72 + sch * 8) = rkh;
    *(uint4*)(KloL + srow * 72 + sch * 8) = rkl;
    *(uint4*)(VhL  + srow * 72 + sch * 8) = rvh;
    __syncthreads();
    if (kt < 35) {     // T14: issue next-tile loads; land under MFMA phase
      size_t tb = tbK + (size_t)(kt + 1) * 4096;
      rkh = *(const uint4*)(khi + tb + soff);
      rkl = *(const uint4*)(klo + tb + soff);
      rvh = *(const uint4*)(vhi + tb + soff);
    }

    // ---- QK^T (swapped): S^T[key][q]
    f32x4 sacc[2] = {};
#pragma unroll
    for (int ds = 0; ds < 2; ds++) {
#pragma unroll
      for (int t2 = 0; t2 < 2; t2++) {
        int row = (hh * 2 + t2) * 16 + ql;
        s16x8 af = *(const s16x8*)(KhiL + row * 72 + ds * 32 + g * 8);
        s16x8 al = *(const s16x8*)(KloL + row * 72 + ds * 32 + g * 8);
        sacc[t2] = __builtin_amdgcn_mfma_f32_16x16x32_bf16(af, qfh[ds], sacc[t2], 0, 0, 0);
        sacc[t2] = __builtin_amdgcn_mfma_f32_16x16x32_bf16(af, qfl[ds], sacc[t2], 0, 0, 0);
        sacc[t2] = __builtin_amdgcn_mfma_f32_16x16x32_bf16(al, qfh[ds], sacc[t2], 0, 0, 0);
      }
    }

    // ---- bias gather: kh in {kh0,kh0+1} within a half-tile
    u32 kg0 = (u32)(kt * 64 + hh * 32);
    u32 kh0 = kg0 / 48u;
    int kw0 = (int)(kg0 - kh0 * 48u);
    float bh0 = __half2float(Bh[kh0 * 65 + q64b]);
    float bh1 = __half2float(Bh[(kh0 + 1) * 65 + q64b]);
    float lg[8];
    float tmax = -3.0e38f;
#pragma unroll
    for (int t2 = 0; t2 < 2; t2++)
#pragma unroll
      for (int r = 0; r < 4; r++) {
        int j = t2 * 4 + r;
        int w = kw0 + t2 * 16 + g * 4 + r;
        bool wrap = w >= 48;
        float bw = __half2float(Bw[(wrap ? w - 48 : w) * 65 + q64b]);
        float x = sacc[t2][r] * 0.125f + (wrap ? bh1 : bh0) + bw;
        lg[j] = x;
        tmax = fmaxf(tmax, x);
      }
    tmax = fmaxf(tmax, __shfl_xor(tmax, 16));
    tmax = fmaxf(tmax, __shfl_xor(tmax, 32));
    if (__any(tmax > m_r + 6.0f)) {   // T13 defer-max
      float mnew = fmaxf(m_r, tmax);
      float corr = __expf(m_r - mnew);
      l_r *= corr;
      m_r = mnew;
      float cq[4];
#pragma unroll
      for (int r = 0; r < 4; r++) cq[r] = __shfl(corr, g * 4 + r);
#pragma unroll
      for (int dt = 0; dt < 4; dt++)
#pragma unroll
        for (int r = 0; r < 4; r++) oacc[dt][r] *= cq[r];
    }
    float psum = 0.f;
    s16x8 pfh;
#pragma unroll
    for (int j = 0; j < 8; j++) {
      float p = __expf(lg[j] - m_r);
      psum += p;
      // truncation-to-bf16 of P: bias cancels in O/l (both scale together)
      pfh[j] = (short)(u16)(__float_as_uint(p) >> 16);
    }
    psum += __shfl_xor(psum, 16);
    psum += __shfl_xor(psum, 32);
    l_r += psum;

    // ---- PV: single MFMA per dt (P,V hi-only; random-signed rounding ~1e-4 in O/l)
#pragma unroll
    for (int dt = 0; dt < 4; dt++) {
      int row = ql + 16 * dt;
      s16x8 bhf = *(const s16x8*)(VhL + row * 72 + hh * 32 + g * 8);
      oacc[dt] = __builtin_amdgcn_mfma_f32_16x16x32_bf16(pfh, bhf, oacc[dt], 0, 0, 0);
    }
  }

  // ---- merge the two key-streams per q-group, write out (packed u32 hi|lo)
  __syncthreads();
  if (hh == 1) {
    if (g == 0) { m_s[q64b] = m_r; l_s[q64b] = l_r; }
#pragma unroll
    for (int dt = 0; dt < 4; dt++)
#pragma unroll
      for (int r = 0; r < 4; r++)
        o_s[(wq * 16 + g * 4 + r) * 68 + ql + 16 * dt] = oacc[dt][r];
  }
  __syncthreads();
  if (hh == 0) {
    float m2 = m_s[q64b];
    float l2 = l_s[q64b];
    float mf = fmaxf(m_r, m2);
    float c1 = __expf(m_r - mf);
    float c2 = __expf(m2 - mf);
    float lf = l_r * c1 + l2 * c2;
    float c1q[4], c2q[4], lfq[4];
#pragma unroll
    for (int r = 0; r < 4; r++) {
      c1q[r] = __shfl(c1, g * 4 + r);
      c2q[r] = __shfl(c2, g * 4 + r);
      lfq[r] = __shfl(lf, g * 4 + r);
    }
    const int b = bh / 12, head = bh - (bh / 12) * 12;
#pragma unroll
    for (int dt = 0; dt < 4; dt++)
#pragma unroll
      for (int r = 0; r < 4; r++) {
        float oo = oacc[dt][r] * c1q[r]
                 + o_s[(wq * 16 + g * 4 + r) * 68 + ql + 16 * dt] * c2q[r];
        float on = oo / lfq[r];
        int s = s0 + wq * 16 + g * 4 + r;
        size_t idx = ((size_t)b * SEQ + s) * 768 + head * 64 + ql + 16 * dt;
        u16 h, l;
        split2(on, h, l);
        aop[idx] = (u32)h | ((u32)l << 16);
      }
  }
}

// ---------------- proj GEMM via split-bf16 MFMA (A = packed u32 hi|lo): -> out
__global__ __launch_bounds__(256) void proj_mfma_k(
    const u32* __restrict__ aop,
    const u16* __restrict__ bthi, const u16* __restrict__ btlo,
    const float* __restrict__ bias, float* __restrict__ out)
{
  __shared__ __align__(16) u16 Ah[128*40], Al[128*40], Bh2[128*40], Bl2[128*40];
  const int tid = threadIdx.x;
  const int lane = tid & 63, wid = tid >> 6;
  const int g = lane >> 4, ql = lane & 15;
  const int wr = wid >> 1, wc = wid & 1;
  const int c0 = blockIdx.x * 128, r0 = blockIdx.y * 128;
  const int srow = tid >> 1, half = tid & 1;

  const u32* ag = aop + (size_t)(r0 + srow) * 768 + half * 16;
  const u16* bgh = bthi + (size_t)(c0 + srow) * 768 + half * 16;
  const u16* bgl = btlo + (size_t)(c0 + srow) * 768 + half * 16;

  uint4 paw[4]; uint4 pbh[2], pbl[2];
#pragma unroll
  for (int j = 0; j < 4; j++) paw[j] = *(const uint4*)(ag + j * 4);
  pbh[0] = *(const uint4*)bgh; pbh[1] = *(const uint4*)(bgh + 8);
  pbl[0] = *(const uint4*)bgl; pbl[1] = *(const uint4*)(bgl + 8);

  f32x4 acc[4][4] = {};

  for (int ks = 0; ks < 24; ks++) {
    __syncthreads();
    {
      u16 hb[16], lb[16];
      const u32* pw = (const u32*)&paw[0];
#pragma unroll
      for (int j = 0; j < 16; j++) {
        hb[j] = (u16)(pw[j] & 0xffffu);
        lb[j] = (u16)(pw[j] >> 16);
      }
      u16* d1 = Ah + srow * 40 + half * 16;
      u16* d2 = Al + srow * 40 + half * 16;
      u16* d3 = Bh2 + srow * 40 + half * 16;
      u16* d4 = Bl2 + srow * 40 + half * 16;
      *(uint4*)d1 = *(uint4*)&hb[0]; *(uint4*)(d1 + 8) = *(uint4*)&hb[8];
      *(uint4*)d2 = *(uint4*)&lb[0]; *(uint4*)(d2 + 8) = *(uint4*)&lb[8];
      *(uint4*)d3 = pbh[0]; *(uint4*)(d3 + 8) = pbh[1];
      *(uint4*)d4 = pbl[0]; *(uint4*)(d4 + 8) = pbl[1];
    }
    __syncthreads();
    if (ks < 23) {
      const int o = (ks + 1) * 32;
#pragma unroll
      for (int j = 0; j < 4; j++) paw[j] = *(const uint4*)(ag + o + j * 4);
      pbh[0] = *(const uint4*)(bgh + o); pbh[1] = *(const uint4*)(bgh + o + 8);
      pbl[0] = *(const uint4*)(bgl + o); pbl[1] = *(const uint4*)(bgl + o + 8);
    }
    s16x8 bfh[4], bfl[4];
#pragma unroll
    for (int nt = 0; nt < 4; nt++) {
      bfh[nt] = *(const s16x8*)(Bh2 + (wc * 64 + nt * 16 + ql) * 40 + g * 8);
      bfl[nt] = *(const s16x8*)(Bl2 + (wc * 64 + nt * 16 + ql) * 40 + g * 8);
    }
#pragma unroll
    for (int mt = 0; mt < 4; mt++) {
      s16x8 ah = *(const s16x8*)(Ah + (wr * 64 + mt * 16 + ql) * 40 + g * 8);
      s16x8 al = *(const s16x8*)(Al + (wr * 64 + mt * 16 + ql) * 40 + g * 8);
#pragma unroll
      for (int nt = 0; nt < 4; nt++) {
        acc[mt][nt] = __builtin_amdgcn_mfma_f32_16x16x32_bf16(ah, bfh[nt], acc[mt][nt], 0, 0, 0);
        acc[mt][nt] = __builtin_amdgcn_mfma_f32_16x16x32_bf16(ah, bfl[nt], acc[mt][nt], 0, 0, 0);
        acc[mt][nt] = __builtin_amdgcn_mfma_f32_16x16x32_bf16(al, bfh[nt], acc[mt][nt], 0, 0, 0);
      }
    }
  }
  const int col0 = c0 + wc * 64;
  const int row0 = r0 + wr * 64;
  float bb[4];
#pragma unroll
  for (int nt = 0; nt < 4; nt++) bb[nt] = bias[col0 + nt * 16 + ql];
#pragma unroll
  for (int mt = 0; mt < 4; mt++)
#pragma unroll
    for (int nt = 0; nt < 4; nt++)
#pragma unroll
      for (int r = 0; r < 4; r++)
        out[(size_t)(row0 + mt * 16 + g * 4 + r) * 768 + col0 + nt * 16 + ql] =
            acc[mt][nt][r] + bb[nt];
}

extern "C" void kernel_launch(void* const* d_in, const int* in_sizes, int n_in,
                              void* d_out, int out_size, void* d_ws, size_t ws_size,
                              hipStream_t stream) {
  const float* x      = (const float*)d_in[0];
  const float* qkv_w  = (const float*)d_in[1];
  const float* qkv_b  = (const float*)d_in[2];
  const float* proj_w = (const float*)d_in[3];
  const float* proj_b = (const float*)d_in[4];
  const float* rph    = (const float*)d_in[5];
  const float* rpw    = (const float*)d_in[6];
  float* out = (float*)d_out;
  float* ws  = (float*)d_ws;

  const size_t SZ = (size_t)24 * SEQ * HD;   // 3,538,944 elems (== 4608*768)
  float* qbuf = ws;                          // SZ f32
  u16* khi = (u16*)(ws + SZ);                // khi, klo, vhi (+dead slot)
  u16* klo = khi + SZ;
  u16* vhi = klo + SZ;
  u16* xhi = (u16*)(ws + 3 * SZ);            // 2 x SZ u16
  u16* xlo = xhi + SZ;
  u32* aop = (u32*)(ws + 4 * SZ);            // SZ u32 (packed hi|lo)
  u16* wqThi = (u16*)(ws + 5 * SZ);          // 768*2304 x2
  u16* wqTlo = wqThi + 768 * 2304;
  u16* wpThi = wqTlo + 768 * 2304;           // 768*768 x2
  u16* wpTlo = wpThi + 768 * 768;

  conv_split_k<<<1728, 256, 0, stream>>>(x, xhi, xlo);
  conv_wT_k <<<dim3(36, 12), 256, 0, stream>>>(qkv_w, wqThi, wqTlo, 768, 2304);
  conv_wT_k <<<dim3(12, 12), 256, 0, stream>>>(proj_w, wpThi, wpTlo, 768, 768);
  qkv_mfma_k<<<dim3(18, 36), 256, 0, stream>>>(xhi, xlo, wqThi, wqTlo, qkv_b,
                                               qbuf, khi, klo, vhi);
  attn_k    <<<dim3(24, 36), 512, 0, stream>>>(qbuf, khi, klo, vhi, rph, rpw, aop);
  proj_mfma_k<<<dim3(6, 36), 256, 0, stream>>>(aop, wpThi, wpTlo, proj_b, out);
}

// Round 18
// 456.571 us; speedup vs baseline: 1.7273x; 1.0281x over previous
//
#include <hip/hip_runtime.h>
#include <hip/hip_fp16.h>

#define HD 64
#define SEQ 2304

typedef unsigned short u16;
typedef unsigned int u32;
using f32x4 = __attribute__((ext_vector_type(4))) float;
using s16x8 = __attribute__((ext_vector_type(8))) short;

static __device__ __forceinline__ float bf2f(u16 h) {
  union { float f; u32 u; } a; a.u = ((u32)h) << 16; return a.f;
}
// truncation split: x ~= hi + lo, |err| ~ 2^-16 |x|
static __device__ __forceinline__ void split2(float x, u16& h, u16& l) {
  u32 u = __float_as_uint(x);
  h = (u16)(u >> 16);
  float r = x - __uint_as_float(u & 0xffff0000u);
  l = (u16)(__float_as_uint(r) >> 16);
}
// round-to-nearest-even bf16 (unbiased: used for V which is consumed hi-only)
static __device__ __forceinline__ u16 rne_bf16(float x) {
  u32 u = __float_as_uint(x);
  return (u16)((u + 0x7fffu + ((u >> 16) & 1u)) >> 16);
}

// ---------------- split fp32 -> bf16 hi/lo, 8 elems/thread
__global__ __launch_bounds__(256) void conv_split_k(
    const float* __restrict__ src, u16* __restrict__ dhi, u16* __restrict__ dlo)
{
  const size_t i = ((size_t)blockIdx.x * 256 + threadIdx.x) * 8;
  f32x4 a = *(const f32x4*)(src + i);
  f32x4 b = *(const f32x4*)(src + i + 4);
  u16 h[8], l[8];
#pragma unroll
  for (int j = 0; j < 8; j++) {
    float x = j < 4 ? a[j] : b[j - 4];
    split2(x, h[j], l[j]);
  }
  *(uint4*)(dhi + i) = *(uint4*)&h[0];
  *(uint4*)(dlo + i) = *(uint4*)&l[0];
}

// ---------------- convert + transpose weights: w[K][N] f32 -> wT[N][K] bf16 hi/lo
__global__ __launch_bounds__(256) void conv_wT_k(
    const float* __restrict__ src, u16* __restrict__ dhi, u16* __restrict__ dlo,
    int K, int N)
{
  __shared__ u32 t[64][65];
  const int tid = threadIdx.x;
  const int n0 = blockIdx.x * 64, k0 = blockIdx.y * 64;
  const int r = tid >> 2, c0 = (tid & 3) * 16;
  const float* sp = src + (size_t)(k0 + r) * N + n0 + c0;
#pragma unroll
  for (int j = 0; j < 16; j += 4) {
    f32x4 v = *(const f32x4*)(sp + j);
#pragma unroll
    for (int e = 0; e < 4; e++) {
      u16 h, l;
      split2(v[e], h, l);
      t[r][c0 + j + e] = (u32)h | ((u32)l << 16);
    }
  }
  __syncthreads();
  u16 hb[16], lb[16];
#pragma unroll
  for (int j = 0; j < 16; j++) {
    u32 p = t[c0 + j][r];
    hb[j] = (u16)(p & 0xffffu);
    lb[j] = (u16)(p >> 16);
  }
  size_t off = (size_t)(n0 + r) * K + k0 + c0;
  *(uint4*)(dhi + off)     = *(uint4*)&hb[0];
  *(uint4*)(dhi + off + 8) = *(uint4*)&hb[8];
  *(uint4*)(dlo + off)     = *(uint4*)&lb[0];
  *(uint4*)(dlo + off + 8) = *(uint4*)&lb[8];
}

// ---- direct-fragment helpers (qkv): 16 global b128 loads / 48 MFMAs per K-step
static __device__ __forceinline__ void load16(
    const u16* pAh, const u16* pAl, const u16* pBh, const u16* pBl, int kk,
    s16x8 ah[4], s16x8 al[4], s16x8 bh[4], s16x8 bl[4])
{
#pragma unroll
  for (int mt = 0; mt < 4; mt++) {
    size_t o = (size_t)mt * 12288 + (size_t)kk * 32;   // mt*16 rows, kk*32 cols
    ah[mt] = *(const s16x8*)(pAh + o);
    al[mt] = *(const s16x8*)(pAl + o);
    bh[mt] = *(const s16x8*)(pBh + o);
    bl[mt] = *(const s16x8*)(pBl + o);
  }
}
static __device__ __forceinline__ void mfma48(
    const s16x8 ah[4], const s16x8 al[4], const s16x8 bh[4], const s16x8 bl[4],
    f32x4 acc[4][4])
{
#pragma unroll
  for (int mt = 0; mt < 4; mt++)
#pragma unroll
    for (int nt = 0; nt < 4; nt++) {
      acc[mt][nt] = __builtin_amdgcn_mfma_f32_16x16x32_bf16(ah[mt], bh[nt], acc[mt][nt], 0, 0, 0);
      acc[mt][nt] = __builtin_amdgcn_mfma_f32_16x16x32_bf16(ah[mt], bl[nt], acc[mt][nt], 0, 0, 0);
      acc[mt][nt] = __builtin_amdgcn_mfma_f32_16x16x32_bf16(al[mt], bh[nt], acc[mt][nt], 0, 0, 0);
    }
}

// ---------------- QKV GEMM, barrier-free direct-fragment: -> q fp32 + K (hi/lo) +
// V (single RNE bf16) images
__global__ __launch_bounds__(256, 2) void qkv_mfma_k(
    const u16* __restrict__ xhi, const u16* __restrict__ xlo,
    const u16* __restrict__ bthi, const u16* __restrict__ btlo,
    const float* __restrict__ bias,
    float* __restrict__ qbuf, u16* __restrict__ khi, u16* __restrict__ klo,
    u16* __restrict__ vhi)
{
  __shared__ __align__(16) u16 img[4][4096];   // epilogue only (wave-private)
  const int tid = threadIdx.x;
  const int lane = tid & 63, wid = tid >> 6;
  const int g = lane >> 4, ql = lane & 15;
  const int wr = wid >> 1, wc = wid & 1;
  const int c0 = blockIdx.x * 128, r0 = blockIdx.y * 128;

  const u16* pAh = xhi  + (size_t)(r0 + wr * 64 + ql) * 768 + g * 8;
  const u16* pAl = xlo  + (size_t)(r0 + wr * 64 + ql) * 768 + g * 8;
  const u16* pBh = bthi + (size_t)(c0 + wc * 64 + ql) * 768 + g * 8;
  const u16* pBl = btlo + (size_t)(c0 + wc * 64 + ql) * 768 + g * 8;

  s16x8 Xah[4], Xal[4], Xbh[4], Xbl[4];
  s16x8 Yah[4], Yal[4], Ybh[4], Ybl[4];
  f32x4 acc[4][4] = {};

  load16(pAh, pAl, pBh, pBl, 0, Xah, Xal, Xbh, Xbl);
  for (int ks = 0; ks < 24; ks += 2) {
    load16(pAh, pAl, pBh, pBl, ks + 1, Yah, Yal, Ybh, Ybl);
    mfma48(Xah, Xal, Xbh, Xbl, acc);
    if (ks + 2 < 24)
      load16(pAh, pAl, pBh, pBl, ks + 2, Xah, Xal, Xbh, Xbl);
    mfma48(Yah, Yal, Ybh, Ybl, acc);
  }

  // ---- epilogue: q fp32 scatter / K,V permuted tile-images via LDS (wave-private)
  const int col0 = c0 + wc * 64;
  const int row0 = r0 + wr * 64;
  const int hb36 = col0 >> 6;
  const int which = hb36 / 12, head = hb36 - (hb36 / 12) * 12;
  const int b = row0 / 2304;
  const int sb = row0 - b * 2304;
  const int bh = b * 12 + head;
  float bb[4];
#pragma unroll
  for (int nt = 0; nt < 4; nt++) bb[nt] = bias[col0 + nt * 16 + ql];
#pragma unroll
  for (int mt = 0; mt < 4; mt++)
#pragma unroll
    for (int nt = 0; nt < 4; nt++)
#pragma unroll
      for (int r = 0; r < 4; r++)
        acc[mt][nt][r] += bb[nt];

  if (which == 0) {
#pragma unroll
    for (int mt = 0; mt < 4; mt++)
#pragma unroll
      for (int nt = 0; nt < 4; nt++)
#pragma unroll
        for (int r = 0; r < 4; r++) {
          int s = sb + mt * 16 + g * 4 + r;
          qbuf[((size_t)bh * SEQ + s) * 64 + nt * 16 + ql] = acc[mt][nt][r];
        }
  } else if (which == 1) {
    const int kt = sb >> 6;
    const size_t tile = ((size_t)bh * 36 + kt) * 4096;
    u16* const reg = img[wid];
    // pass 1: HI
#pragma unroll
    for (int mt = 0; mt < 4; mt++)
#pragma unroll
      for (int nt = 0; nt < 4; nt++) {
        int pcK = (nt >> 1) * 32 + (ql >> 2) * 8 + (nt & 1) * 4 + (ql & 3);
#pragma unroll
        for (int r = 0; r < 4; r++) {
          u16 h, l;
          split2(acc[mt][nt][r], h, l);
          reg[(mt * 16 + g * 4 + r) * 64 + pcK] = h;
        }
      }
    {
      const u16* src = reg + lane * 64;
      u16* dst = khi + tile + lane * 64;
#pragma unroll
      for (int j = 0; j < 8; j++)
        *(uint4*)(dst + j * 8) = *(const uint4*)(src + j * 8);
    }
    // pass 2: LO
#pragma unroll
    for (int mt = 0; mt < 4; mt++)
#pragma unroll
      for (int nt = 0; nt < 4; nt++) {
        int pcK = (nt >> 1) * 32 + (ql >> 2) * 8 + (nt & 1) * 4 + (ql & 3);
#pragma unroll
        for (int r = 0; r < 4; r++) {
          u16 h, l;
          split2(acc[mt][nt][r], h, l);
          reg[(mt * 16 + g * 4 + r) * 64 + pcK] = l;
        }
      }
    {
      const u16* src = reg + lane * 64;
      u16* dst = klo + tile + lane * 64;
#pragma unroll
      for (int j = 0; j < 8; j++)
        *(uint4*)(dst + j * 8) = *(const uint4*)(src + j * 8);
    }
  } else {
    // V image: single pass, RNE bf16 (consumed hi-only; RNE kills truncation bias)
    const int kt = sb >> 6;
    const size_t tile = ((size_t)bh * 36 + kt) * 4096;
    u16* const reg = img[wid];
#pragma unroll
    for (int mt = 0; mt < 4; mt++)
#pragma unroll
      for (int nt = 0; nt < 4; nt++)
#pragma unroll
        for (int r = 0; r < 4; r++) {
          int off = (nt * 16 + ql) * 64 + (mt >> 1) * 32 + g * 8 + (mt & 1) * 4 + r;
          reg[off] = rne_bf16(acc[mt][nt][r]);
        }
    {
      const u16* src = reg + lane * 64;
      u16* dst = vhi + tile + lane * 64;
#pragma unroll
      for (int j = 0; j < 8; j++)
        *(uint4*)(dst + j * 8) = *(const uint4*)(src + j * 8);
    }
  }
}

// ---------------- Fused attention (r17 base + register-hoisted Bw bias):
// per lane, Bw reads across ALL tiles touch only 12 values (kw0 in {0,16,32},
// period 3 in kt) -> build Bw in SCRATCH LDS (aliases V buffer, dead before main
// loop), hoist to 12 regs, select via kt%3 unroll rotation (static names).
// Kills 8 LDS reads + ~35 VALU per tile AND drops persistent Bw table:
// LDS 40.9 -> 34.5KB -> 4 blocks/CU (if VGPR<=64). No sync-structure change.
#define BWS_OFF 18432                     // scratch: aliases VhL (dead pre-loop)
#define BH_OFF  27648                     // Bh: 49 x 65 u16 (row 48 = wrap slack)
#define MS_OFF  (BH_OFF + 6372)           // 34020
#define LS_OFF  (MS_OFF + 256)            // 34276
__global__ __launch_bounds__(512) void attn_k(
    const float* __restrict__ qb,
    const u16* __restrict__ khi, const u16* __restrict__ klo,
    const u16* __restrict__ vhi,
    const float* __restrict__ rph, const float* __restrict__ rpw,
    u32* __restrict__ aop)
{
  __shared__ __align__(16) char pool[LS_OFF + 256];   // 34532 B
  u16* KhiL = (u16*)pool;              // [64 key][72]
  u16* KloL = (u16*)(pool + 9216);
  u16* VhL  = (u16*)(pool + 18432);    // [64 d][72]
  __half* BwS = (__half*)(pool + BWS_OFF); // scratch [48 kw][65 pad]
  __half* Bh  = (__half*)(pool + BH_OFF);  // [49 kh][65 pad]
  float* m_s = (float*)(pool + MS_OFF);    // [64]
  float* l_s = (float*)(pool + LS_OFF);    // [64]
  float* qlds = (float*)pool;              // prologue alias [64][68] f32 (17408B)
  float* o_s  = (float*)pool;              // epilogue alias [64][68] f32

  const int tid  = threadIdx.x;
  const int lane = tid & 63;
  const int wid  = tid >> 6;
  const int g    = lane >> 4;
  const int ql   = lane & 15;
  const int wq   = wid & 3;     // q-group: rows [16*wq, 16*wq+16)
  const int hh   = wid >> 2;    // key-half stream
  const int bh   = blockIdx.x;  // 24
  const int qt   = blockIdx.y;  // 36
  const int s0   = qt * 64;

  // ---- stage Q tile fp32 -> LDS
  {
    int row = tid >> 3, c0 = (tid & 7) * 8;
    const float* src = qb + ((size_t)bh * SEQ + s0 + row) * HD + c0;
    f32x4 v0 = *(const f32x4*)src;
    f32x4 v1 = *(const f32x4*)(src + 4);
    *(f32x4*)&qlds[row * 68 + c0]     = v0;
    *(f32x4*)&qlds[row * 68 + c0 + 4] = v1;
  }
  __syncthreads();

  // ---- Q fragments hi/lo (lane's q = 16*wq + ql)
  s16x8 qfh[2], qfl[2];
  {
    int qrow = wq * 16 + ql;
#pragma unroll
    for (int ds = 0; ds < 2; ds++) {
#pragma unroll
      for (int h2 = 0; h2 < 2; h2++) {
        f32x4 qv = *(const f32x4*)&qlds[qrow * 68 + g * 4 + h2 * 16 + ds * 32];
#pragma unroll
        for (int j = 0; j < 4; j++) {
          u16 hi, lo;
          split2(qv[j], hi, lo);
          qfh[ds][h2 * 4 + j] = (short)hi;
          qfl[ds][h2 * 4 + j] = (short)lo;
        }
      }
    }
  }

  // ---- prefetch tile 0
  const size_t tbK = (size_t)bh * 36 * 4096;
  const int srow = tid >> 3;
  const int sch  = ((tid & 7) - (srow & 7)) & 7;
  const size_t soff = (size_t)srow * 64 + sch * 8;
  uint4 rkh = *(const uint4*)(khi + tbK + soff);
  uint4 rkl = *(const uint4*)(klo + tbK + soff);
  uint4 rvh = *(const uint4*)(vhi + tbK + soff);

  // ---- decomposed rel-pos bias build: Bh persistent, Bw into scratch
  for (int i = tid; i < 64 * 96; i += 512) {
    int q = i / 96, j = i - (i / 96) * 96;
    int s = s0 + q;
    int qhg = s / 48, qw = s - qhg * 48;
    const float* tab;
    int ridx, col;
    if (j < 48) { col = j;      ridx = qhg - j + 47;        tab = rph; }
    else        { col = j - 48; ridx = qw - (j - 48) + 47;  tab = rpw; }
    const float* rp = tab + (size_t)ridx * HD;
    const float* qp = &qlds[q * 68];
    float s1 = 0.f;
#pragma unroll 4
    for (int d = 0; d < 64; d += 4) {
      f32x4 a = *(const f32x4*)(qp + d);
      f32x4 bv = *(const f32x4*)(rp + d);
      s1 += a[0]*bv[0] + a[1]*bv[1] + a[2]*bv[2] + a[3]*bv[3];
    }
    if (j < 48) Bh[col * 65 + q] = __float2half_rn(s1);
    else        BwS[col * 65 + q] = __float2half_rn(s1);
  }
  __syncthreads();

  const int q64b = wq * 16 + ql;

  // ---- hoist per-lane Bw values (12 of them), reorder by hh for kt%3 rotation
  float wA[4], wB[4], wC[4];
  {
    float b0[4], b1[4], b2[4];
#pragma unroll
    for (int r = 0; r < 4; r++) {
      b0[r] = __half2float(BwS[(      g * 4 + r) * 65 + q64b]);
      b1[r] = __half2float(BwS[(16 +  g * 4 + r) * 65 + q64b]);
      b2[r] = __half2float(BwS[(32 +  g * 4 + r) * 65 + q64b]);
    }
#pragma unroll
    for (int r = 0; r < 4; r++) {
      wA[r] = hh ? b2[r] : b0[r];   // w[j] = bw[(j + 2*hh) % 3]
      wB[r] = hh ? b0[r] : b1[r];
      wC[r] = hh ? b1[r] : b2[r];
    }
  }

  float m_r = -3.0e38f, l_r = 0.f;
  f32x4 oacc[4] = {};   // O[q = 4g+r][d = ql + 16*dt]

  // tile body: WA_ = bw for t2=0, WB_ = bw for t2=1; WRAP1 = (u==2), u=(kt+2hh)%3
#define ATTN_TILE(KT, WA_, WB_, WRAP1) {                                        \
    const int kt = (KT);                                                        \
    __syncthreads();                                                            \
    *(uint4*)(KhiL + srow * 72 + sch * 8) = rkh;                                \
    *(uint4*)(KloL + srow * 72 + sch * 8) = rkl;                                \
    *(uint4*)(VhL  + srow * 72 + sch * 8) = rvh;                                \
    __syncthreads();                                                            \
    if (kt < 35) {                                                              \
      size_t tb = tbK + (size_t)(kt + 1) * 4096;                                \
      rkh = *(const uint4*)(khi + tb + soff);                                   \
      rkl = *(const uint4*)(klo + tb + soff);                                   \
      rvh = *(const uint4*)(vhi + tb + soff);                                   \
    }                                                                           \
    f32x4 sacc[2] = {};                                                         \
    _Pragma("unroll")                                                           \
    for (int ds = 0; ds < 2; ds++) {                                            \
      _Pragma("unroll")                                                         \
      for (int t2 = 0; t2 < 2; t2++) {                                          \
        int row = (hh * 2 + t2) * 16 + ql;                                      \
        s16x8 af = *(const s16x8*)(KhiL + row * 72 + ds * 32 + g * 8);          \
        s16x8 al = *(const s16x8*)(KloL + row * 72 + ds * 32 + g * 8);          \
        sacc[t2] = __builtin_amdgcn_mfma_f32_16x16x32_bf16(af, qfh[ds], sacc[t2], 0, 0, 0); \
        sacc[t2] = __builtin_amdgcn_mfma_f32_16x16x32_bf16(af, qfl[ds], sacc[t2], 0, 0, 0); \
        sacc[t2] = __builtin_amdgcn_mfma_f32_16x16x32_bf16(al, qfh[ds], sacc[t2], 0, 0, 0); \
      }                                                                         \
    }                                                                           \
    u32 kg0 = (u32)(kt * 64 + hh * 32);                                         \
    u32 kh0 = kg0 / 48u;                                                        \
    float bh0v = __half2float(Bh[kh0 * 65 + q64b]);                             \
    float bh1v = __half2float(Bh[(kh0 + 1) * 65 + q64b]);                       \
    float bhB = (WRAP1) ? bh1v : bh0v;                                          \
    float lg[8];                                                                \
    float tmax = -3.0e38f;                                                      \
    _Pragma("unroll")                                                           \
    for (int r = 0; r < 4; r++) {                                               \
      float x0 = sacc[0][r] * 0.125f + (bh0v + WA_[r]);                         \
      float x1 = sacc[1][r] * 0.125f + (bhB  + WB_[r]);                         \
      lg[r]     = x0;                                                           \
      lg[4 + r] = x1;                                                           \
      tmax = fmaxf(tmax, fmaxf(x0, x1));                                        \
    }                                                                           \
    tmax = fmaxf(tmax, __shfl_xor(tmax, 16));                                   \
    tmax = fmaxf(tmax, __shfl_xor(tmax, 32));                                   \
    if (__any(tmax > m_r + 6.0f)) {                                             \
      float mnew = fmaxf(m_r, tmax);                                            \
      float corr = __expf(m_r - mnew);                                          \
      l_r *= corr;                                                              \
      m_r = mnew;                                                               \
      float cq[4];                                                              \
      _Pragma("unroll")                                                         \
      for (int r = 0; r < 4; r++) cq[r] = __shfl(corr, g * 4 + r);              \
      _Pragma("unroll")                                                         \
      for (int dt = 0; dt < 4; dt++)                                            \
        _Pragma("unroll")                                                       \
        for (int r = 0; r < 4; r++) oacc[dt][r] *= cq[r];                       \
    }                                                                           \
    float psum = 0.f;                                                           \
    s16x8 pfh;                                                                  \
    _Pragma("unroll")                                                           \
    for (int j = 0; j < 8; j++) {                                               \
      float p = __expf(lg[j] - m_r);                                            \
      psum += p;                                                                \
      pfh[j] = (short)(u16)(__float_as_uint(p) >> 16);                          \
    }                                                                           \
    psum += __shfl_xor(psum, 16);                                               \
    psum += __shfl_xor(psum, 32);                                               \
    l_r += psum;                                                                \
    _Pragma("unroll")                                                           \
    for (int dt = 0; dt < 4; dt++) {                                            \
      int row = ql + 16 * dt;                                                   \
      s16x8 bhf = *(const s16x8*)(VhL + row * 72 + hh * 32 + g * 8);            \
      oacc[dt] = __builtin_amdgcn_mfma_f32_16x16x32_bf16(pfh, bhf, oacc[dt], 0, 0, 0); \
    }                                                                           \
  }

  for (int kt0 = 0; kt0 < 36; kt0 += 3) {
    ATTN_TILE(kt0 + 0, wA, wB, hh != 0);   // d=0: wrap iff hh==1
    ATTN_TILE(kt0 + 1, wB, wC, false);     // d=1: never wraps
    ATTN_TILE(kt0 + 2, wC, wA, hh == 0);   // d=2: wrap iff hh==0
  }
#undef ATTN_TILE

  // ---- merge the two key-streams per q-group, write out (packed u32 hi|lo)
  __syncthreads();
  if (hh == 1) {
    if (g == 0) { m_s[q64b] = m_r; l_s[q64b] = l_r; }
#pragma unroll
    for (int dt = 0; dt < 4; dt++)
#pragma unroll
      for (int r = 0; r < 4; r++)
        o_s[(wq * 16 + g * 4 + r) * 68 + ql + 16 * dt] = oacc[dt][r];
  }
  __syncthreads();
  if (hh == 0) {
    float m2 = m_s[q64b];
    float l2 = l_s[q64b];
    float mf = fmaxf(m_r, m2);
    float c1 = __expf(m_r - mf);
    float c2 = __expf(m2 - mf);
    float lf = l_r * c1 + l2 * c2;
    float c1q[4], c2q[4], lfq[4];
#pragma unroll
    for (int r = 0; r < 4; r++) {
      c1q[r] = __shfl(c1, g * 4 + r);
      c2q[r] = __shfl(c2, g * 4 + r);
      lfq[r] = __shfl(lf, g * 4 + r);
    }
    const int b = bh / 12, head = bh - (bh / 12) * 12;
#pragma unroll
    for (int dt = 0; dt < 4; dt++)
#pragma unroll
      for (int r = 0; r < 4; r++) {
        float oo = oacc[dt][r] * c1q[r]
                 + o_s[(wq * 16 + g * 4 + r) * 68 + ql + 16 * dt] * c2q[r];
        float on = oo / lfq[r];
        int s = s0 + wq * 16 + g * 4 + r;
        size_t idx = ((size_t)b * SEQ + s) * 768 + head * 64 + ql + 16 * dt;
        u16 h, l;
        split2(on, h, l);
        aop[idx] = (u32)h | ((u32)l << 16);
      }
  }
}

// ---------------- proj GEMM via split-bf16 MFMA (A = packed u32 hi|lo): -> out
__global__ __launch_bounds__(256) void proj_mfma_k(
    const u32* __restrict__ aop,
    const u16* __restrict__ bthi, const u16* __restrict__ btlo,
    const float* __restrict__ bias, float* __restrict__ out)
{
  __shared__ __align__(16) u16 Ah[128*40], Al[128*40], Bh2[128*40], Bl2[128*40];
  const int tid = threadIdx.x;
  const int lane = tid & 63, wid = tid >> 6;
  const int g = lane >> 4, ql = lane & 15;
  const int wr = wid >> 1, wc = wid & 1;
  const int c0 = blockIdx.x * 128, r0 = blockIdx.y * 128;
  const int srow = tid >> 1, half = tid & 1;

  const u32* ag = aop + (size_t)(r0 + srow) * 768 + half * 16;
  const u16* bgh = bthi + (size_t)(c0 + srow) * 768 + half * 16;
  const u16* bgl = btlo + (size_t)(c0 + srow) * 768 + half * 16;

  uint4 paw[4]; uint4 pbh[2], pbl[2];
#pragma unroll
  for (int j = 0; j < 4; j++) paw[j] = *(const uint4*)(ag + j * 4);
  pbh[0] = *(const uint4*)bgh; pbh[1] = *(const uint4*)(bgh + 8);
  pbl[0] = *(const uint4*)bgl; pbl[1] = *(const uint4*)(bgl + 8);

  f32x4 acc[4][4] = {};

  for (int ks = 0; ks < 24; ks++) {
    __syncthreads();
    {
      u16 hb[16], lb[16];
      const u32* pw = (const u32*)&paw[0];
#pragma unroll
      for (int j = 0; j < 16; j++) {
        hb[j] = (u16)(pw[j] & 0xffffu);
        lb[j] = (u16)(pw[j] >> 16);
      }
      u16* d1 = Ah + srow * 40 + half * 16;
      u16* d2 = Al + srow * 40 + half * 16;
      u16* d3 = Bh2 + srow * 40 + half * 16;
      u16* d4 = Bl2 + srow * 40 + half * 16;
      *(uint4*)d1 = *(uint4*)&hb[0]; *(uint4*)(d1 + 8) = *(uint4*)&hb[8];
      *(uint4*)d2 = *(uint4*)&lb[0]; *(uint4*)(d2 + 8) = *(uint4*)&lb[8];
      *(uint4*)d3 = pbh[0]; *(uint4*)(d3 + 8) = pbh[1];
      *(uint4*)d4 = pbl[0]; *(uint4*)(d4 + 8) = pbl[1];
    }
    __syncthreads();
    if (ks < 23) {
      const int o = (ks + 1) * 32;
#pragma unroll
      for (int j = 0; j < 4; j++) paw[j] = *(const uint4*)(ag + o + j * 4);
      pbh[0] = *(const uint4*)(bgh + o); pbh[1] = *(const uint4*)(bgh + o + 8);
      pbl[0] = *(const uint4*)(bgl + o); pbl[1] = *(const uint4*)(bgl + o + 8);
    }
    s16x8 bfh[4], bfl[4];
#pragma unroll
    for (int nt = 0; nt < 4; nt++) {
      bfh[nt] = *(const s16x8*)(Bh2 + (wc * 64 + nt * 16 + ql) * 40 + g * 8);
      bfl[nt] = *(const s16x8*)(Bl2 + (wc * 64 + nt * 16 + ql) * 40 + g * 8);
    }
#pragma unroll
    for (int mt = 0; mt < 4; mt++) {
      s16x8 ah = *(const s16x8*)(Ah + (wr * 64 + mt * 16 + ql) * 40 + g * 8);
      s16x8 al = *(const s16x8*)(Al + (wr * 64 + mt * 16 + ql) * 40 + g * 8);
#pragma unroll
      for (int nt = 0; nt < 4; nt++) {
        acc[mt][nt] = __builtin_amdgcn_mfma_f32_16x16x32_bf16(ah, bfh[nt], acc[mt][nt], 0, 0, 0);
        acc[mt][nt] = __builtin_amdgcn_mfma_f32_16x16x32_bf16(ah, bfl[nt], acc[mt][nt], 0, 0, 0);
        acc[mt][nt] = __builtin_amdgcn_mfma_f32_16x16x32_bf16(al, bfh[nt], acc[mt][nt], 0, 0, 0);
      }
    }
  }
  const int col0 = c0 + wc * 64;
  const int row0 = r0 + wr * 64;
  float bb[4];
#pragma unroll
  for (int nt = 0; nt < 4; nt++) bb[nt] = bias[col0 + nt * 16 + ql];
#pragma unroll
  for (int mt = 0; mt < 4; mt++)
#pragma unroll
    for (int nt = 0; nt < 4; nt++)
#pragma unroll
      for (int r = 0; r < 4; r++)
        out[(size_t)(row0 + mt * 16 + g * 4 + r) * 768 + col0 + nt * 16 + ql] =
            acc[mt][nt][r] + bb[nt];
}

extern "C" void kernel_launch(void* const* d_in, const int* in_sizes, int n_in,
                              void* d_out, int out_size, void* d_ws, size_t ws_size,
                              hipStream_t stream) {
  const float* x      = (const float*)d_in[0];
  const float* qkv_w  = (const float*)d_in[1];
  const float* qkv_b  = (const float*)d_in[2];
  const float* proj_w = (const float*)d_in[3];
  const float* proj_b = (const float*)d_in[4];
  const float* rph    = (const float*)d_in[5];
  const float* rpw    = (const float*)d_in[6];
  float* out = (float*)d_out;
  float* ws  = (float*)d_ws;

  const size_t SZ = (size_t)24 * SEQ * HD;   // 3,538,944 elems (== 4608*768)
  float* qbuf = ws;                          // SZ f32
  u16* khi = (u16*)(ws + SZ);                // khi, klo, vhi (+dead slot)
  u16* klo = khi + SZ;
  u16* vhi = klo + SZ;
  u16* xhi = (u16*)(ws + 3 * SZ);            // 2 x SZ u16
  u16* xlo = xhi + SZ;
  u32* aop = (u32*)(ws + 4 * SZ);            // SZ u32 (packed hi|lo)
  u16* wqThi = (u16*)(ws + 5 * SZ);          // 768*2304 x2
  u16* wqTlo = wqThi + 768 * 2304;
  u16* wpThi = wqTlo + 768 * 2304;           // 768*768 x2
  u16* wpTlo = wpThi + 768 * 768;

  conv_split_k<<<1728, 256, 0, stream>>>(x, xhi, xlo);
  conv_wT_k <<<dim3(36, 12), 256, 0, stream>>>(qkv_w, wqThi, wqTlo, 768, 2304);
  conv_wT_k <<<dim3(12, 12), 256, 0, stream>>>(proj_w, wpThi, wpTlo, 768, 768);
  qkv_mfma_k<<<dim3(18, 36), 256, 0, stream>>>(xhi, xlo, wqThi, wqTlo, qkv_b,
                                               qbuf, khi, klo, vhi);
  attn_k    <<<dim3(24, 36), 512, 0, stream>>>(qbuf, khi, klo, vhi, rph, rpw, aop);
  proj_mfma_k<<<dim3(6, 36), 256, 0, stream>>>(aop, wpThi, wpTlo, proj_b, out);
}

// Round 19
// 454.188 us; speedup vs baseline: 1.7364x; 1.0052x over previous
//
#include <hip/hip_runtime.h>
#include <hip/hip_fp16.h>

#define HD 64
#define SEQ 2304

typedef unsigned short u16;
typedef unsigned int u32;
using f32x4 = __attribute__((ext_vector_type(4))) float;
using s16x8 = __attribute__((ext_vector_type(8))) short;

static __device__ __forceinline__ float bf2f(u16 h) {
  union { float f; u32 u; } a; a.u = ((u32)h) << 16; return a.f;
}
// truncation split: x ~= hi + lo, |err| ~ 2^-16 |x|
static __device__ __forceinline__ void split2(float x, u16& h, u16& l) {
  u32 u = __float_as_uint(x);
  h = (u16)(u >> 16);
  float r = x - __uint_as_float(u & 0xffff0000u);
  l = (u16)(__float_as_uint(r) >> 16);
}
// round-to-nearest-even bf16 (unbiased: used for V which is consumed hi-only)
static __device__ __forceinline__ u16 rne_bf16(float x) {
  u32 u = __float_as_uint(x);
  return (u16)((u + 0x7fffu + ((u >> 16) & 1u)) >> 16);
}

// ---------------- split fp32 -> bf16 hi/lo, 8 elems/thread
__global__ __launch_bounds__(256) void conv_split_k(
    const float* __restrict__ src, u16* __restrict__ dhi, u16* __restrict__ dlo)
{
  const size_t i = ((size_t)blockIdx.x * 256 + threadIdx.x) * 8;
  f32x4 a = *(const f32x4*)(src + i);
  f32x4 b = *(const f32x4*)(src + i + 4);
  u16 h[8], l[8];
#pragma unroll
  for (int j = 0; j < 8; j++) {
    float x = j < 4 ? a[j] : b[j - 4];
    split2(x, h[j], l[j]);
  }
  *(uint4*)(dhi + i) = *(uint4*)&h[0];
  *(uint4*)(dlo + i) = *(uint4*)&l[0];
}

// ---------------- convert + transpose weights: w[K][N] f32 -> wT[N][K] bf16 hi/lo
__global__ __launch_bounds__(256) void conv_wT_k(
    const float* __restrict__ src, u16* __restrict__ dhi, u16* __restrict__ dlo,
    int K, int N)
{
  __shared__ u32 t[64][65];
  const int tid = threadIdx.x;
  const int n0 = blockIdx.x * 64, k0 = blockIdx.y * 64;
  const int r = tid >> 2, c0 = (tid & 3) * 16;
  const float* sp = src + (size_t)(k0 + r) * N + n0 + c0;
#pragma unroll
  for (int j = 0; j < 16; j += 4) {
    f32x4 v = *(const f32x4*)(sp + j);
#pragma unroll
    for (int e = 0; e < 4; e++) {
      u16 h, l;
      split2(v[e], h, l);
      t[r][c0 + j + e] = (u32)h | ((u32)l << 16);
    }
  }
  __syncthreads();
  u16 hb[16], lb[16];
#pragma unroll
  for (int j = 0; j < 16; j++) {
    u32 p = t[c0 + j][r];
    hb[j] = (u16)(p & 0xffffu);
    lb[j] = (u16)(p >> 16);
  }
  size_t off = (size_t)(n0 + r) * K + k0 + c0;
  *(uint4*)(dhi + off)     = *(uint4*)&hb[0];
  *(uint4*)(dhi + off + 8) = *(uint4*)&hb[8];
  *(uint4*)(dlo + off)     = *(uint4*)&lb[0];
  *(uint4*)(dlo + off + 8) = *(uint4*)&lb[8];
}

// ---- direct-fragment helpers (qkv): 16 global b128 loads / 48 MFMAs per K-step
static __device__ __forceinline__ void load16(
    const u16* pAh, const u16* pAl, const u16* pBh, const u16* pBl, int kk,
    s16x8 ah[4], s16x8 al[4], s16x8 bh[4], s16x8 bl[4])
{
#pragma unroll
  for (int mt = 0; mt < 4; mt++) {
    size_t o = (size_t)mt * 12288 + (size_t)kk * 32;   // mt*16 rows, kk*32 cols
    ah[mt] = *(const s16x8*)(pAh + o);
    al[mt] = *(const s16x8*)(pAl + o);
    bh[mt] = *(const s16x8*)(pBh + o);
    bl[mt] = *(const s16x8*)(pBl + o);
  }
}
static __device__ __forceinline__ void mfma48(
    const s16x8 ah[4], const s16x8 al[4], const s16x8 bh[4], const s16x8 bl[4],
    f32x4 acc[4][4])
{
#pragma unroll
  for (int mt = 0; mt < 4; mt++)
#pragma unroll
    for (int nt = 0; nt < 4; nt++) {
      acc[mt][nt] = __builtin_amdgcn_mfma_f32_16x16x32_bf16(ah[mt], bh[nt], acc[mt][nt], 0, 0, 0);
      acc[mt][nt] = __builtin_amdgcn_mfma_f32_16x16x32_bf16(ah[mt], bl[nt], acc[mt][nt], 0, 0, 0);
      acc[mt][nt] = __builtin_amdgcn_mfma_f32_16x16x32_bf16(al[mt], bh[nt], acc[mt][nt], 0, 0, 0);
    }
}

// ---------------- QKV GEMM, barrier-free direct-fragment: -> q fp32 + K (hi/lo) +
// V (single RNE bf16) images
__global__ __launch_bounds__(256, 2) void qkv_mfma_k(
    const u16* __restrict__ xhi, const u16* __restrict__ xlo,
    const u16* __restrict__ bthi, const u16* __restrict__ btlo,
    const float* __restrict__ bias,
    float* __restrict__ qbuf, u16* __restrict__ khi, u16* __restrict__ klo,
    u16* __restrict__ vhi)
{
  __shared__ __align__(16) u16 img[4][4096];   // epilogue only (wave-private)
  const int tid = threadIdx.x;
  const int lane = tid & 63, wid = tid >> 6;
  const int g = lane >> 4, ql = lane & 15;
  const int wr = wid >> 1, wc = wid & 1;
  const int c0 = blockIdx.x * 128, r0 = blockIdx.y * 128;

  const u16* pAh = xhi  + (size_t)(r0 + wr * 64 + ql) * 768 + g * 8;
  const u16* pAl = xlo  + (size_t)(r0 + wr * 64 + ql) * 768 + g * 8;
  const u16* pBh = bthi + (size_t)(c0 + wc * 64 + ql) * 768 + g * 8;
  const u16* pBl = btlo + (size_t)(c0 + wc * 64 + ql) * 768 + g * 8;

  s16x8 Xah[4], Xal[4], Xbh[4], Xbl[4];
  s16x8 Yah[4], Yal[4], Ybh[4], Ybl[4];
  f32x4 acc[4][4] = {};

  load16(pAh, pAl, pBh, pBl, 0, Xah, Xal, Xbh, Xbl);
  for (int ks = 0; ks < 24; ks += 2) {
    load16(pAh, pAl, pBh, pBl, ks + 1, Yah, Yal, Ybh, Ybl);
    mfma48(Xah, Xal, Xbh, Xbl, acc);
    if (ks + 2 < 24)
      load16(pAh, pAl, pBh, pBl, ks + 2, Xah, Xal, Xbh, Xbl);
    mfma48(Yah, Yal, Ybh, Ybl, acc);
  }

  // ---- epilogue: q fp32 scatter / K,V permuted tile-images via LDS (wave-private)
  const int col0 = c0 + wc * 64;
  const int row0 = r0 + wr * 64;
  const int hb36 = col0 >> 6;
  const int which = hb36 / 12, head = hb36 - (hb36 / 12) * 12;
  const int b = row0 / 2304;
  const int sb = row0 - b * 2304;
  const int bh = b * 12 + head;
  float bb[4];
#pragma unroll
  for (int nt = 0; nt < 4; nt++) bb[nt] = bias[col0 + nt * 16 + ql];
#pragma unroll
  for (int mt = 0; mt < 4; mt++)
#pragma unroll
    for (int nt = 0; nt < 4; nt++)
#pragma unroll
      for (int r = 0; r < 4; r++)
        acc[mt][nt][r] += bb[nt];

  if (which == 0) {
#pragma unroll
    for (int mt = 0; mt < 4; mt++)
#pragma unroll
      for (int nt = 0; nt < 4; nt++)
#pragma unroll
        for (int r = 0; r < 4; r++) {
          int s = sb + mt * 16 + g * 4 + r;
          qbuf[((size_t)bh * SEQ + s) * 64 + nt * 16 + ql] = acc[mt][nt][r];
        }
  } else if (which == 1) {
    const int kt = sb >> 6;
    const size_t tile = ((size_t)bh * 36 + kt) * 4096;
    u16* const reg = img[wid];
    // pass 1: HI
#pragma unroll
    for (int mt = 0; mt < 4; mt++)
#pragma unroll
      for (int nt = 0; nt < 4; nt++) {
        int pcK = (nt >> 1) * 32 + (ql >> 2) * 8 + (nt & 1) * 4 + (ql & 3);
#pragma unroll
        for (int r = 0; r < 4; r++) {
          u16 h, l;
          split2(acc[mt][nt][r], h, l);
          reg[(mt * 16 + g * 4 + r) * 64 + pcK] = h;
        }
      }
    {
      const u16* src = reg + lane * 64;
      u16* dst = khi + tile + lane * 64;
#pragma unroll
      for (int j = 0; j < 8; j++)
        *(uint4*)(dst + j * 8) = *(const uint4*)(src + j * 8);
    }
    // pass 2: LO
#pragma unroll
    for (int mt = 0; mt < 4; mt++)
#pragma unroll
      for (int nt = 0; nt < 4; nt++) {
        int pcK = (nt >> 1) * 32 + (ql >> 2) * 8 + (nt & 1) * 4 + (ql & 3);
#pragma unroll
        for (int r = 0; r < 4; r++) {
          u16 h, l;
          split2(acc[mt][nt][r], h, l);
          reg[(mt * 16 + g * 4 + r) * 64 + pcK] = l;
        }
      }
    {
      const u16* src = reg + lane * 64;
      u16* dst = klo + tile + lane * 64;
#pragma unroll
      for (int j = 0; j < 8; j++)
        *(uint4*)(dst + j * 8) = *(const uint4*)(src + j * 8);
    }
  } else {
    // V image: single pass, RNE bf16 (consumed hi-only; RNE kills truncation bias)
    const int kt = sb >> 6;
    const size_t tile = ((size_t)bh * 36 + kt) * 4096;
    u16* const reg = img[wid];
#pragma unroll
    for (int mt = 0; mt < 4; mt++)
#pragma unroll
      for (int nt = 0; nt < 4; nt++)
#pragma unroll
        for (int r = 0; r < 4; r++) {
          int off = (nt * 16 + ql) * 64 + (mt >> 1) * 32 + g * 8 + (mt & 1) * 4 + r;
          reg[off] = rne_bf16(acc[mt][nt][r]);
        }
    {
      const u16* src = reg + lane * 64;
      u16* dst = vhi + tile + lane * 64;
#pragma unroll
      for (int j = 0; j < 8; j++)
        *(uint4*)(dst + j * 8) = *(const uint4*)(src + j * 8);
    }
  }
}

// ---------------- Fused attention (r18 base + deferred psum reduction):
// per-lane partial l (corr is g-uniform after tmax reduce -> exact); the 2
// cross-lane psum shuffles move out of the 36-tile loop into the epilogue.
#define BWS_OFF 18432                     // scratch: aliases VhL (dead pre-loop)
#define BH_OFF  27648                     // Bh: 49 x 65 u16 (row 48 = wrap slack)
#define MS_OFF  (BH_OFF + 6372)           // 34020
#define LS_OFF  (MS_OFF + 256)            // 34276
__global__ __launch_bounds__(512) void attn_k(
    const float* __restrict__ qb,
    const u16* __restrict__ khi, const u16* __restrict__ klo,
    const u16* __restrict__ vhi,
    const float* __restrict__ rph, const float* __restrict__ rpw,
    u32* __restrict__ aop)
{
  __shared__ __align__(16) char pool[LS_OFF + 256];   // 34532 B
  u16* KhiL = (u16*)pool;              // [64 key][72]
  u16* KloL = (u16*)(pool + 9216);
  u16* VhL  = (u16*)(pool + 18432);    // [64 d][72]
  __half* BwS = (__half*)(pool + BWS_OFF); // scratch [48 kw][65 pad]
  __half* Bh  = (__half*)(pool + BH_OFF);  // [49 kh][65 pad]
  float* m_s = (float*)(pool + MS_OFF);    // [64]
  float* l_s = (float*)(pool + LS_OFF);    // [64]
  float* qlds = (float*)pool;              // prologue alias [64][68] f32 (17408B)
  float* o_s  = (float*)pool;              // epilogue alias [64][68] f32

  const int tid  = threadIdx.x;
  const int lane = tid & 63;
  const int wid  = tid >> 6;
  const int g    = lane >> 4;
  const int ql   = lane & 15;
  const int wq   = wid & 3;     // q-group: rows [16*wq, 16*wq+16)
  const int hh   = wid >> 2;    // key-half stream
  const int bh   = blockIdx.x;  // 24
  const int qt   = blockIdx.y;  // 36
  const int s0   = qt * 64;

  // ---- stage Q tile fp32 -> LDS
  {
    int row = tid >> 3, c0 = (tid & 7) * 8;
    const float* src = qb + ((size_t)bh * SEQ + s0 + row) * HD + c0;
    f32x4 v0 = *(const f32x4*)src;
    f32x4 v1 = *(const f32x4*)(src + 4);
    *(f32x4*)&qlds[row * 68 + c0]     = v0;
    *(f32x4*)&qlds[row * 68 + c0 + 4] = v1;
  }
  __syncthreads();

  // ---- Q fragments hi/lo (lane's q = 16*wq + ql)
  s16x8 qfh[2], qfl[2];
  {
    int qrow = wq * 16 + ql;
#pragma unroll
    for (int ds = 0; ds < 2; ds++) {
#pragma unroll
      for (int h2 = 0; h2 < 2; h2++) {
        f32x4 qv = *(const f32x4*)&qlds[qrow * 68 + g * 4 + h2 * 16 + ds * 32];
#pragma unroll
        for (int j = 0; j < 4; j++) {
          u16 hi, lo;
          split2(qv[j], hi, lo);
          qfh[ds][h2 * 4 + j] = (short)hi;
          qfl[ds][h2 * 4 + j] = (short)lo;
        }
      }
    }
  }

  // ---- prefetch tile 0
  const size_t tbK = (size_t)bh * 36 * 4096;
  const int srow = tid >> 3;
  const int sch  = ((tid & 7) - (srow & 7)) & 7;
  const size_t soff = (size_t)srow * 64 + sch * 8;
  uint4 rkh = *(const uint4*)(khi + tbK + soff);
  uint4 rkl = *(const uint4*)(klo + tbK + soff);
  uint4 rvh = *(const uint4*)(vhi + tbK + soff);

  // ---- decomposed rel-pos bias build: Bh persistent, Bw into scratch
  for (int i = tid; i < 64 * 96; i += 512) {
    int q = i / 96, j = i - (i / 96) * 96;
    int s = s0 + q;
    int qhg = s / 48, qw = s - qhg * 48;
    const float* tab;
    int ridx, col;
    if (j < 48) { col = j;      ridx = qhg - j + 47;        tab = rph; }
    else        { col = j - 48; ridx = qw - (j - 48) + 47;  tab = rpw; }
    const float* rp = tab + (size_t)ridx * HD;
    const float* qp = &qlds[q * 68];
    float s1 = 0.f;
#pragma unroll 4
    for (int d = 0; d < 64; d += 4) {
      f32x4 a = *(const f32x4*)(qp + d);
      f32x4 bv = *(const f32x4*)(rp + d);
      s1 += a[0]*bv[0] + a[1]*bv[1] + a[2]*bv[2] + a[3]*bv[3];
    }
    if (j < 48) Bh[col * 65 + q] = __float2half_rn(s1);
    else        BwS[col * 65 + q] = __float2half_rn(s1);
  }
  __syncthreads();

  const int q64b = wq * 16 + ql;

  // ---- hoist per-lane Bw values (12 of them), reorder by hh for kt%3 rotation
  float wA[4], wB[4], wC[4];
  {
    float b0[4], b1[4], b2[4];
#pragma unroll
    for (int r = 0; r < 4; r++) {
      b0[r] = __half2float(BwS[(      g * 4 + r) * 65 + q64b]);
      b1[r] = __half2float(BwS[(16 +  g * 4 + r) * 65 + q64b]);
      b2[r] = __half2float(BwS[(32 +  g * 4 + r) * 65 + q64b]);
    }
#pragma unroll
    for (int r = 0; r < 4; r++) {
      wA[r] = hh ? b2[r] : b0[r];   // w[j] = bw[(j + 2*hh) % 3]
      wB[r] = hh ? b0[r] : b1[r];
      wC[r] = hh ? b1[r] : b2[r];
    }
  }

  float m_r = -3.0e38f, l_r = 0.f;   // l_r = per-lane partial (reduced in epilogue)
  f32x4 oacc[4] = {};   // O[q = 4g+r][d = ql + 16*dt]

  // tile body: WA_ = bw for t2=0, WB_ = bw for t2=1; WRAP1 = (u==2), u=(kt+2hh)%3
#define ATTN_TILE(KT, WA_, WB_, WRAP1) {                                        \
    const int kt = (KT);                                                        \
    __syncthreads();                                                            \
    *(uint4*)(KhiL + srow * 72 + sch * 8) = rkh;                                \
    *(uint4*)(KloL + srow * 72 + sch * 8) = rkl;                                \
    *(uint4*)(VhL  + srow * 72 + sch * 8) = rvh;                                \
    __syncthreads();                                                            \
    if (kt < 35) {                                                              \
      size_t tb = tbK + (size_t)(kt + 1) * 4096;                                \
      rkh = *(const uint4*)(khi + tb + soff);                                   \
      rkl = *(const uint4*)(klo + tb + soff);                                   \
      rvh = *(const uint4*)(vhi + tb + soff);                                   \
    }                                                                           \
    f32x4 sacc[2] = {};                                                         \
    _Pragma("unroll")                                                           \
    for (int ds = 0; ds < 2; ds++) {                                            \
      _Pragma("unroll")                                                         \
      for (int t2 = 0; t2 < 2; t2++) {                                          \
        int row = (hh * 2 + t2) * 16 + ql;                                      \
        s16x8 af = *(const s16x8*)(KhiL + row * 72 + ds * 32 + g * 8);          \
        s16x8 al = *(const s16x8*)(KloL + row * 72 + ds * 32 + g * 8);          \
        sacc[t2] = __builtin_amdgcn_mfma_f32_16x16x32_bf16(af, qfh[ds], sacc[t2], 0, 0, 0); \
        sacc[t2] = __builtin_amdgcn_mfma_f32_16x16x32_bf16(af, qfl[ds], sacc[t2], 0, 0, 0); \
        sacc[t2] = __builtin_amdgcn_mfma_f32_16x16x32_bf16(al, qfh[ds], sacc[t2], 0, 0, 0); \
      }                                                                         \
    }                                                                           \
    u32 kg0 = (u32)(kt * 64 + hh * 32);                                         \
    u32 kh0 = kg0 / 48u;                                                        \
    float bh0v = __half2float(Bh[kh0 * 65 + q64b]);                             \
    float bh1v = __half2float(Bh[(kh0 + 1) * 65 + q64b]);                       \
    float bhB = (WRAP1) ? bh1v : bh0v;                                          \
    float lg[8];                                                                \
    float tmax = -3.0e38f;                                                      \
    _Pragma("unroll")                                                           \
    for (int r = 0; r < 4; r++) {                                               \
      float x0 = sacc[0][r] * 0.125f + (bh0v + WA_[r]);                         \
      float x1 = sacc[1][r] * 0.125f + (bhB  + WB_[r]);                         \
      lg[r]     = x0;                                                           \
      lg[4 + r] = x1;                                                           \
      tmax = fmaxf(tmax, fmaxf(x0, x1));                                        \
    }                                                                           \
    tmax = fmaxf(tmax, __shfl_xor(tmax, 16));                                   \
    tmax = fmaxf(tmax, __shfl_xor(tmax, 32));                                   \
    if (__any(tmax > m_r + 6.0f)) {                                             \
      float mnew = fmaxf(m_r, tmax);                                            \
      float corr = __expf(m_r - mnew);                                          \
      l_r *= corr;                                                              \
      m_r = mnew;                                                               \
      float cq[4];                                                              \
      _Pragma("unroll")                                                         \
      for (int r = 0; r < 4; r++) cq[r] = __shfl(corr, g * 4 + r);              \
      _Pragma("unroll")                                                         \
      for (int dt = 0; dt < 4; dt++)                                            \
        _Pragma("unroll")                                                       \
        for (int r = 0; r < 4; r++) oacc[dt][r] *= cq[r];                       \
    }                                                                           \
    float psum = 0.f;                                                           \
    s16x8 pfh;                                                                  \
    _Pragma("unroll")                                                           \
    for (int j = 0; j < 8; j++) {                                               \
      float p = __expf(lg[j] - m_r);                                            \
      psum += p;                                                                \
      pfh[j] = (short)(u16)(__float_as_uint(p) >> 16);                          \
    }                                                                           \
    l_r += psum;                                                                \
    _Pragma("unroll")                                                           \
    for (int dt = 0; dt < 4; dt++) {                                            \
      int row = ql + 16 * dt;                                                   \
      s16x8 bhf = *(const s16x8*)(VhL + row * 72 + hh * 32 + g * 8);            \
      oacc[dt] = __builtin_amdgcn_mfma_f32_16x16x32_bf16(pfh, bhf, oacc[dt], 0, 0, 0); \
    }                                                                           \
  }

  for (int kt0 = 0; kt0 < 36; kt0 += 3) {
    ATTN_TILE(kt0 + 0, wA, wB, hh != 0);   // d=0: wrap iff hh==1
    ATTN_TILE(kt0 + 1, wB, wC, false);     // d=1: never wraps
    ATTN_TILE(kt0 + 2, wC, wA, hh == 0);   // d=2: wrap iff hh==0
  }
#undef ATTN_TILE

  // ---- deferred cross-g reduction of per-lane partial l
  l_r += __shfl_xor(l_r, 16);
  l_r += __shfl_xor(l_r, 32);

  // ---- merge the two key-streams per q-group, write out (packed u32 hi|lo)
  __syncthreads();
  if (hh == 1) {
    if (g == 0) { m_s[q64b] = m_r; l_s[q64b] = l_r; }
#pragma unroll
    for (int dt = 0; dt < 4; dt++)
#pragma unroll
      for (int r = 0; r < 4; r++)
        o_s[(wq * 16 + g * 4 + r) * 68 + ql + 16 * dt] = oacc[dt][r];
  }
  __syncthreads();
  if (hh == 0) {
    float m2 = m_s[q64b];
    float l2 = l_s[q64b];
    float mf = fmaxf(m_r, m2);
    float c1 = __expf(m_r - mf);
    float c2 = __expf(m2 - mf);
    float lf = l_r * c1 + l2 * c2;
    float c1q[4], c2q[4], lfq[4];
#pragma unroll
    for (int r = 0; r < 4; r++) {
      c1q[r] = __shfl(c1, g * 4 + r);
      c2q[r] = __shfl(c2, g * 4 + r);
      lfq[r] = __shfl(lf, g * 4 + r);
    }
    const int b = bh / 12, head = bh - (bh / 12) * 12;
#pragma unroll
    for (int dt = 0; dt < 4; dt++)
#pragma unroll
      for (int r = 0; r < 4; r++) {
        float oo = oacc[dt][r] * c1q[r]
                 + o_s[(wq * 16 + g * 4 + r) * 68 + ql + 16 * dt] * c2q[r];
        float on = oo / lfq[r];
        int s = s0 + wq * 16 + g * 4 + r;
        size_t idx = ((size_t)b * SEQ + s) * 768 + head * 64 + ql + 16 * dt;
        u16 h, l;
        split2(on, h, l);
        aop[idx] = (u32)h | ((u32)l << 16);
      }
  }
}

// ---- proj direct-fragment helpers: A = packed u32 (unpack in-register)
static __device__ __forceinline__ void unpack8(
    const uint4 w0, const uint4 w1, s16x8& h, s16x8& l)
{
  u32 w[8];
  *(uint4*)&w[0] = w0; *(uint4*)&w[4] = w1;
  u32 hw[4], lw[4];
#pragma unroll
  for (int i = 0; i < 4; i++) {
    hw[i] = (w[2*i] & 0xffffu) | (w[2*i+1] << 16);
    lw[i] = (w[2*i] >> 16) | (w[2*i+1] & 0xffff0000u);
  }
  h = *(s16x8*)&hw[0];
  l = *(s16x8*)&lw[0];
}
static __device__ __forceinline__ void loadP(
    const u32* pA, const u16* pBh, const u16* pBl, int kk,
    uint4 aw[4][2], s16x8 bh[4], s16x8 bl[4])
{
#pragma unroll
  for (int mt = 0; mt < 4; mt++) {
    size_t oa = (size_t)mt * 12288 + (size_t)kk * 32;  // u32 units (1 u32 per k)
    aw[mt][0] = *(const uint4*)(pA + oa);
    aw[mt][1] = *(const uint4*)(pA + oa + 4);
    size_t ob = (size_t)mt * 12288 + (size_t)kk * 32;  // u16 units
    bh[mt] = *(const s16x8*)(pBh + ob);
    bl[mt] = *(const s16x8*)(pBl + ob);
  }
}
static __device__ __forceinline__ void mfmaP(
    uint4 aw[4][2], const s16x8 bh[4], const s16x8 bl[4], f32x4 acc[4][4])
{
#pragma unroll
  for (int mt = 0; mt < 4; mt++) {
    s16x8 ah, al;
    unpack8(aw[mt][0], aw[mt][1], ah, al);
#pragma unroll
    for (int nt = 0; nt < 4; nt++) {
      acc[mt][nt] = __builtin_amdgcn_mfma_f32_16x16x32_bf16(ah, bh[nt], acc[mt][nt], 0, 0, 0);
      acc[mt][nt] = __builtin_amdgcn_mfma_f32_16x16x32_bf16(ah, bl[nt], acc[mt][nt], 0, 0, 0);
      acc[mt][nt] = __builtin_amdgcn_mfma_f32_16x16x32_bf16(al, bh[nt], acc[mt][nt], 0, 0, 0);
    }
  }
}

// ---------------- proj GEMM, barrier-free direct-fragment (qkv-style): -> out
__global__ __launch_bounds__(256, 2) void proj_mfma_k(
    const u32* __restrict__ aop,
    const u16* __restrict__ bthi, const u16* __restrict__ btlo,
    const float* __restrict__ bias, float* __restrict__ out)
{
  const int tid = threadIdx.x;
  const int lane = tid & 63, wid = tid >> 6;
  const int g = lane >> 4, ql = lane & 15;
  const int wr = wid >> 1, wc = wid & 1;
  const int c0 = blockIdx.x * 128, r0 = blockIdx.y * 128;

  const u32* pA  = aop  + (size_t)(r0 + wr * 64 + ql) * 768 + g * 8;
  const u16* pBh = bthi + (size_t)(c0 + wc * 64 + ql) * 768 + g * 8;
  const u16* pBl = btlo + (size_t)(c0 + wc * 64 + ql) * 768 + g * 8;

  uint4 Xa[4][2]; s16x8 Xbh[4], Xbl[4];
  uint4 Ya[4][2]; s16x8 Ybh[4], Ybl[4];
  f32x4 acc[4][4] = {};

  loadP(pA, pBh, pBl, 0, Xa, Xbh, Xbl);
  for (int ks = 0; ks < 24; ks += 2) {
    loadP(pA, pBh, pBl, ks + 1, Ya, Ybh, Ybl);
    mfmaP(Xa, Xbh, Xbl, acc);
    if (ks + 2 < 24)
      loadP(pA, pBh, pBl, ks + 2, Xa, Xbh, Xbl);
    mfmaP(Ya, Ybh, Ybl, acc);
  }

  const int col0 = c0 + wc * 64;
  const int row0 = r0 + wr * 64;
  float bb[4];
#pragma unroll
  for (int nt = 0; nt < 4; nt++) bb[nt] = bias[col0 + nt * 16 + ql];
#pragma unroll
  for (int mt = 0; mt < 4; mt++)
#pragma unroll
    for (int nt = 0; nt < 4; nt++)
#pragma unroll
      for (int r = 0; r < 4; r++)
        out[(size_t)(row0 + mt * 16 + g * 4 + r) * 768 + col0 + nt * 16 + ql] =
            acc[mt][nt][r] + bb[nt];
}

extern "C" void kernel_launch(void* const* d_in, const int* in_sizes, int n_in,
                              void* d_out, int out_size, void* d_ws, size_t ws_size,
                              hipStream_t stream) {
  const float* x      = (const float*)d_in[0];
  const float* qkv_w  = (const float*)d_in[1];
  const float* qkv_b  = (const float*)d_in[2];
  const float* proj_w = (const float*)d_in[3];
  const float* proj_b = (const float*)d_in[4];
  const float* rph    = (const float*)d_in[5];
  const float* rpw    = (const float*)d_in[6];
  float* out = (float*)d_out;
  float* ws  = (float*)d_ws;

  const size_t SZ = (size_t)24 * SEQ * HD;   // 3,538,944 elems (== 4608*768)
  float* qbuf = ws;                          // SZ f32
  u16* khi = (u16*)(ws + SZ);                // khi, klo, vhi (+dead slot)
  u16* klo = khi + SZ;
  u16* vhi = klo + SZ;
  u16* xhi = (u16*)(ws + 3 * SZ);            // 2 x SZ u16
  u16* xlo = xhi + SZ;
  u32* aop = (u32*)(ws + 4 * SZ);            // SZ u32 (packed hi|lo)
  u16* wqThi = (u16*)(ws + 5 * SZ);          // 768*2304 x2
  u16* wqTlo = wqThi + 768 * 2304;
  u16* wpThi = wqTlo + 768 * 2304;           // 768*768 x2
  u16* wpTlo = wpThi + 768 * 768;

  conv_split_k<<<1728, 256, 0, stream>>>(x, xhi, xlo);
  conv_wT_k <<<dim3(36, 12), 256, 0, stream>>>(qkv_w, wqThi, wqTlo, 768, 2304);
  conv_wT_k <<<dim3(12, 12), 256, 0, stream>>>(proj_w, wpThi, wpTlo, 768, 768);
  qkv_mfma_k<<<dim3(18, 36), 256, 0, stream>>>(xhi, xlo, wqThi, wqTlo, qkv_b,
                                               qbuf, khi, klo, vhi);
  attn_k    <<<dim3(24, 36), 512, 0, stream>>>(qbuf, khi, klo, vhi, rph, rpw, aop);
  proj_mfma_k<<<dim3(6, 36), 256, 0, stream>>>(aop, wpThi, wpTlo, proj_b, out);
}

// Round 20
// 446.182 us; speedup vs baseline: 1.7676x; 1.0179x over previous
//
#include <hip/hip_runtime.h>
#include <hip/hip_fp16.h>

#define HD 64
#define SEQ 2304

typedef unsigned short u16;
typedef unsigned int u32;
using f32x4 = __attribute__((ext_vector_type(4))) float;
using s16x8 = __attribute__((ext_vector_type(8))) short;

static __device__ __forceinline__ float bf2f(u16 h) {
  union { float f; u32 u; } a; a.u = ((u32)h) << 16; return a.f;
}
// truncation split: x ~= hi + lo, |err| ~ 2^-16 |x|
static __device__ __forceinline__ void split2(float x, u16& h, u16& l) {
  u32 u = __float_as_uint(x);
  h = (u16)(u >> 16);
  float r = x - __uint_as_float(u & 0xffff0000u);
  l = (u16)(__float_as_uint(r) >> 16);
}
// round-to-nearest-even bf16 (unbiased: used for V which is consumed hi-only)
static __device__ __forceinline__ u16 rne_bf16(float x) {
  u32 u = __float_as_uint(x);
  return (u16)((u + 0x7fffu + ((u >> 16) & 1u)) >> 16);
}

// ---------------- convert + transpose BOTH weights: w[768][N] f32 -> wT[N][768]
// bf16 hi/lo. Grid x: [0,36) -> qkv_w (N=2304), [36,48) -> proj_w (N=768).
__global__ __launch_bounds__(256) void conv_wT2_k(
    const float* __restrict__ wq, const float* __restrict__ wp,
    u16* __restrict__ qhiT, u16* __restrict__ qloT,
    u16* __restrict__ phiT, u16* __restrict__ ploT)
{
  __shared__ u32 t[64][65];
  const int tid = threadIdx.x;
  const bool isq = blockIdx.x < 36;
  const int bx = isq ? blockIdx.x : blockIdx.x - 36;
  const float* src = isq ? wq : wp;
  u16* dhi = isq ? qhiT : phiT;
  u16* dlo = isq ? qloT : ploT;
  const int N = isq ? 2304 : 768;
  const int n0 = bx * 64, k0 = blockIdx.y * 64;
  const int r = tid >> 2, c0 = (tid & 3) * 16;
  const float* sp = src + (size_t)(k0 + r) * N + n0 + c0;
#pragma unroll
  for (int j = 0; j < 16; j += 4) {
    f32x4 v = *(const f32x4*)(sp + j);
#pragma unroll
    for (int e = 0; e < 4; e++) {
      u16 h, l;
      split2(v[e], h, l);
      t[r][c0 + j + e] = (u32)h | ((u32)l << 16);
    }
  }
  __syncthreads();
  u16 hb[16], lb[16];
#pragma unroll
  for (int j = 0; j < 16; j++) {
    u32 p = t[c0 + j][r];
    hb[j] = (u16)(p & 0xffffu);
    lb[j] = (u16)(p >> 16);
  }
  size_t off = (size_t)(n0 + r) * 768 + k0 + c0;
  *(uint4*)(dhi + off)     = *(uint4*)&hb[0];
  *(uint4*)(dhi + off + 8) = *(uint4*)&hb[8];
  *(uint4*)(dlo + off)     = *(uint4*)&lb[0];
  *(uint4*)(dlo + off + 8) = *(uint4*)&lb[8];
}

// ---- qkv direct-fragment helpers: A = raw fp32 (split in-register at use)
static __device__ __forceinline__ void loadF(
    const float* pA, const u16* pBh, const u16* pBl, int kk,
    uint4 aw[4][2], s16x8 bh[4], s16x8 bl[4])
{
#pragma unroll
  for (int mt = 0; mt < 4; mt++) {
    size_t o = (size_t)mt * 12288 + (size_t)kk * 32;   // row-stride 768 elems
    aw[mt][0] = *(const uint4*)(pA + o);       // 4 f32 (bits)
    aw[mt][1] = *(const uint4*)(pA + o + 4);
    bh[mt] = *(const s16x8*)(pBh + o);
    bl[mt] = *(const s16x8*)(pBl + o);
  }
}
static __device__ __forceinline__ void mfmaF(
    uint4 aw[4][2], const s16x8 bh[4], const s16x8 bl[4], f32x4 acc[4][4])
{
#pragma unroll
  for (int mt = 0; mt < 4; mt++) {
    u32 w[8];
    *(uint4*)&w[0] = aw[mt][0]; *(uint4*)&w[4] = aw[mt][1];
    u16 hh[8], ll[8];
#pragma unroll
    for (int j = 0; j < 8; j++)
      split2(__uint_as_float(w[j]), hh[j], ll[j]);
    s16x8 ah = *(s16x8*)&hh[0];
    s16x8 al = *(s16x8*)&ll[0];
#pragma unroll
    for (int nt = 0; nt < 4; nt++) {
      acc[mt][nt] = __builtin_amdgcn_mfma_f32_16x16x32_bf16(ah, bh[nt], acc[mt][nt], 0, 0, 0);
      acc[mt][nt] = __builtin_amdgcn_mfma_f32_16x16x32_bf16(ah, bl[nt], acc[mt][nt], 0, 0, 0);
      acc[mt][nt] = __builtin_amdgcn_mfma_f32_16x16x32_bf16(al, bh[nt], acc[mt][nt], 0, 0, 0);
    }
  }
}

// ---------------- QKV GEMM, barrier-free direct-fragment, fp32-A in-register split:
// -> q fp32 + K (hi/lo) + V (single RNE bf16) images. conv_split kernel eliminated.
__global__ __launch_bounds__(256, 2) void qkv_mfma_k(
    const float* __restrict__ x,
    const u16* __restrict__ bthi, const u16* __restrict__ btlo,
    const float* __restrict__ bias,
    float* __restrict__ qbuf, u16* __restrict__ khi, u16* __restrict__ klo,
    u16* __restrict__ vhi)
{
  __shared__ __align__(16) u16 img[4][4096];   // epilogue only (wave-private)
  const int tid = threadIdx.x;
  const int lane = tid & 63, wid = tid >> 6;
  const int g = lane >> 4, ql = lane & 15;
  const int wr = wid >> 1, wc = wid & 1;
  const int c0 = blockIdx.x * 128, r0 = blockIdx.y * 128;

  const float* pA = x    + (size_t)(r0 + wr * 64 + ql) * 768 + g * 8;
  const u16* pBh = bthi + (size_t)(c0 + wc * 64 + ql) * 768 + g * 8;
  const u16* pBl = btlo + (size_t)(c0 + wc * 64 + ql) * 768 + g * 8;

  uint4 Xa[4][2]; s16x8 Xbh[4], Xbl[4];
  uint4 Ya[4][2]; s16x8 Ybh[4], Ybl[4];
  f32x4 acc[4][4] = {};

  loadF(pA, pBh, pBl, 0, Xa, Xbh, Xbl);
  for (int ks = 0; ks < 24; ks += 2) {
    loadF(pA, pBh, pBl, ks + 1, Ya, Ybh, Ybl);
    mfmaF(Xa, Xbh, Xbl, acc);
    if (ks + 2 < 24)
      loadF(pA, pBh, pBl, ks + 2, Xa, Xbh, Xbl);
    mfmaF(Ya, Ybh, Ybl, acc);
  }

  // ---- epilogue: q fp32 scatter / K,V permuted tile-images via LDS (wave-private)
  const int col0 = c0 + wc * 64;
  const int row0 = r0 + wr * 64;
  const int hb36 = col0 >> 6;
  const int which = hb36 / 12, head = hb36 - (hb36 / 12) * 12;
  const int b = row0 / 2304;
  const int sb = row0 - b * 2304;
  const int bh = b * 12 + head;
  float bb[4];
#pragma unroll
  for (int nt = 0; nt < 4; nt++) bb[nt] = bias[col0 + nt * 16 + ql];
#pragma unroll
  for (int mt = 0; mt < 4; mt++)
#pragma unroll
    for (int nt = 0; nt < 4; nt++)
#pragma unroll
      for (int r = 0; r < 4; r++)
        acc[mt][nt][r] += bb[nt];

  if (which == 0) {
#pragma unroll
    for (int mt = 0; mt < 4; mt++)
#pragma unroll
      for (int nt = 0; nt < 4; nt++)
#pragma unroll
        for (int r = 0; r < 4; r++) {
          int s = sb + mt * 16 + g * 4 + r;
          qbuf[((size_t)bh * SEQ + s) * 64 + nt * 16 + ql] = acc[mt][nt][r];
        }
  } else if (which == 1) {
    const int kt = sb >> 6;
    const size_t tile = ((size_t)bh * 36 + kt) * 4096;
    u16* const reg = img[wid];
    // pass 1: HI
#pragma unroll
    for (int mt = 0; mt < 4; mt++)
#pragma unroll
      for (int nt = 0; nt < 4; nt++) {
        int pcK = (nt >> 1) * 32 + (ql >> 2) * 8 + (nt & 1) * 4 + (ql & 3);
#pragma unroll
        for (int r = 0; r < 4; r++) {
          u16 h, l;
          split2(acc[mt][nt][r], h, l);
          reg[(mt * 16 + g * 4 + r) * 64 + pcK] = h;
        }
      }
    {
      const u16* src = reg + lane * 64;
      u16* dst = khi + tile + lane * 64;
#pragma unroll
      for (int j = 0; j < 8; j++)
        *(uint4*)(dst + j * 8) = *(const uint4*)(src + j * 8);
    }
    // pass 2: LO
#pragma unroll
    for (int mt = 0; mt < 4; mt++)
#pragma unroll
      for (int nt = 0; nt < 4; nt++) {
        int pcK = (nt >> 1) * 32 + (ql >> 2) * 8 + (nt & 1) * 4 + (ql & 3);
#pragma unroll
        for (int r = 0; r < 4; r++) {
          u16 h, l;
          split2(acc[mt][nt][r], h, l);
          reg[(mt * 16 + g * 4 + r) * 64 + pcK] = l;
        }
      }
    {
      const u16* src = reg + lane * 64;
      u16* dst = klo + tile + lane * 64;
#pragma unroll
      for (int j = 0; j < 8; j++)
        *(uint4*)(dst + j * 8) = *(const uint4*)(src + j * 8);
    }
  } else {
    // V image: single pass, RNE bf16 (consumed hi-only; RNE kills truncation bias)
    const int kt = sb >> 6;
    const size_t tile = ((size_t)bh * 36 + kt) * 4096;
    u16* const reg = img[wid];
#pragma unroll
    for (int mt = 0; mt < 4; mt++)
#pragma unroll
      for (int nt = 0; nt < 4; nt++)
#pragma unroll
        for (int r = 0; r < 4; r++) {
          int off = (nt * 16 + ql) * 64 + (mt >> 1) * 32 + g * 8 + (mt & 1) * 4 + r;
          reg[off] = rne_bf16(acc[mt][nt][r]);
        }
    {
      const u16* src = reg + lane * 64;
      u16* dst = vhi + tile + lane * 64;
#pragma unroll
      for (int j = 0; j < 8; j++)
        *(uint4*)(dst + j * 8) = *(const uint4*)(src + j * 8);
    }
  }
}

// ---------------- Fused attention (r19, unchanged): deferred psum, hoisted Bw,
// no setprio, single-MFMA PV, LDS-staged K hi/lo + V.
#define BWS_OFF 18432                     // scratch: aliases VhL (dead pre-loop)
#define BH_OFF  27648                     // Bh: 49 x 65 u16 (row 48 = wrap slack)
#define MS_OFF  (BH_OFF + 6372)           // 34020
#define LS_OFF  (MS_OFF + 256)            // 34276
__global__ __launch_bounds__(512) void attn_k(
    const float* __restrict__ qb,
    const u16* __restrict__ khi, const u16* __restrict__ klo,
    const u16* __restrict__ vhi,
    const float* __restrict__ rph, const float* __restrict__ rpw,
    u32* __restrict__ aop)
{
  __shared__ __align__(16) char pool[LS_OFF + 256];   // 34532 B
  u16* KhiL = (u16*)pool;              // [64 key][72]
  u16* KloL = (u16*)(pool + 9216);
  u16* VhL  = (u16*)(pool + 18432);    // [64 d][72]
  __half* BwS = (__half*)(pool + BWS_OFF); // scratch [48 kw][65 pad]
  __half* Bh  = (__half*)(pool + BH_OFF);  // [49 kh][65 pad]
  float* m_s = (float*)(pool + MS_OFF);    // [64]
  float* l_s = (float*)(pool + LS_OFF);    // [64]
  float* qlds = (float*)pool;              // prologue alias [64][68] f32 (17408B)
  float* o_s  = (float*)pool;              // epilogue alias [64][68] f32

  const int tid  = threadIdx.x;
  const int lane = tid & 63;
  const int wid  = tid >> 6;
  const int g    = lane >> 4;
  const int ql   = lane & 15;
  const int wq   = wid & 3;     // q-group: rows [16*wq, 16*wq+16)
  const int hh   = wid >> 2;    // key-half stream
  const int bh   = blockIdx.x;  // 24
  const int qt   = blockIdx.y;  // 36
  const int s0   = qt * 64;

  // ---- stage Q tile fp32 -> LDS
  {
    int row = tid >> 3, c0 = (tid & 7) * 8;
    const float* src = qb + ((size_t)bh * SEQ + s0 + row) * HD + c0;
    f32x4 v0 = *(const f32x4*)src;
    f32x4 v1 = *(const f32x4*)(src + 4);
    *(f32x4*)&qlds[row * 68 + c0]     = v0;
    *(f32x4*)&qlds[row * 68 + c0 + 4] = v1;
  }
  __syncthreads();

  // ---- Q fragments hi/lo (lane's q = 16*wq + ql)
  s16x8 qfh[2], qfl[2];
  {
    int qrow = wq * 16 + ql;
#pragma unroll
    for (int ds = 0; ds < 2; ds++) {
#pragma unroll
      for (int h2 = 0; h2 < 2; h2++) {
        f32x4 qv = *(const f32x4*)&qlds[qrow * 68 + g * 4 + h2 * 16 + ds * 32];
#pragma unroll
        for (int j = 0; j < 4; j++) {
          u16 hi, lo;
          split2(qv[j], hi, lo);
          qfh[ds][h2 * 4 + j] = (short)hi;
          qfl[ds][h2 * 4 + j] = (short)lo;
        }
      }
    }
  }

  // ---- prefetch tile 0
  const size_t tbK = (size_t)bh * 36 * 4096;
  const int srow = tid >> 3;
  const int sch  = ((tid & 7) - (srow & 7)) & 7;
  const size_t soff = (size_t)srow * 64 + sch * 8;
  uint4 rkh = *(const uint4*)(khi + tbK + soff);
  uint4 rkl = *(const uint4*)(klo + tbK + soff);
  uint4 rvh = *(const uint4*)(vhi + tbK + soff);

  // ---- decomposed rel-pos bias build: Bh persistent, Bw into scratch
  for (int i = tid; i < 64 * 96; i += 512) {
    int q = i / 96, j = i - (i / 96) * 96;
    int s = s0 + q;
    int qhg = s / 48, qw = s - qhg * 48;
    const float* tab;
    int ridx, col;
    if (j < 48) { col = j;      ridx = qhg - j + 47;        tab = rph; }
    else        { col = j - 48; ridx = qw - (j - 48) + 47;  tab = rpw; }
    const float* rp = tab + (size_t)ridx * HD;
    const float* qp = &qlds[q * 68];
    float s1 = 0.f;
#pragma unroll 4
    for (int d = 0; d < 64; d += 4) {
      f32x4 a = *(const f32x4*)(qp + d);
      f32x4 bv = *(const f32x4*)(rp + d);
      s1 += a[0]*bv[0] + a[1]*bv[1] + a[2]*bv[2] + a[3]*bv[3];
    }
    if (j < 48) Bh[col * 65 + q] = __float2half_rn(s1);
    else        BwS[col * 65 + q] = __float2half_rn(s1);
  }
  __syncthreads();

  const int q64b = wq * 16 + ql;

  // ---- hoist per-lane Bw values (12 of them), reorder by hh for kt%3 rotation
  float wA[4], wB[4], wC[4];
  {
    float b0[4], b1[4], b2[4];
#pragma unroll
    for (int r = 0; r < 4; r++) {
      b0[r] = __half2float(BwS[(      g * 4 + r) * 65 + q64b]);
      b1[r] = __half2float(BwS[(16 +  g * 4 + r) * 65 + q64b]);
      b2[r] = __half2float(BwS[(32 +  g * 4 + r) * 65 + q64b]);
    }
#pragma unroll
    for (int r = 0; r < 4; r++) {
      wA[r] = hh ? b2[r] : b0[r];   // w[j] = bw[(j + 2*hh) % 3]
      wB[r] = hh ? b0[r] : b1[r];
      wC[r] = hh ? b1[r] : b2[r];
    }
  }

  float m_r = -3.0e38f, l_r = 0.f;   // l_r = per-lane partial (reduced in epilogue)
  f32x4 oacc[4] = {};   // O[q = 4g+r][d = ql + 16*dt]

  // tile body: WA_ = bw for t2=0, WB_ = bw for t2=1; WRAP1 = (u==2), u=(kt+2hh)%3
#define ATTN_TILE(KT, WA_, WB_, WRAP1) {                                        \
    const int kt = (KT);                                                        \
    __syncthreads();                                                            \
    *(uint4*)(KhiL + srow * 72 + sch * 8) = rkh;                                \
    *(uint4*)(KloL + srow * 72 + sch * 8) = rkl;                                \
    *(uint4*)(VhL  + srow * 72 + sch * 8) = rvh;                                \
    __syncthreads();                                                            \
    if (kt < 35) {                                                              \
      size_t tb = tbK + (size_t)(kt + 1) * 4096;                                \
      rkh = *(const uint4*)(khi + tb + soff);                                   \
      rkl = *(const uint4*)(klo + tb + soff);                                   \
      rvh = *(const uint4*)(vhi + tb + soff);                                   \
    }                                                                           \
    f32x4 sacc[2] = {};                                                         \
    _Pragma("unroll")                                                           \
    for (int ds = 0; ds < 2; ds++) {                                            \
      _Pragma("unroll")                                                         \
      for (int t2 = 0; t2 < 2; t2++) {                                          \
        int row = (hh * 2 + t2) * 16 + ql;                                      \
        s16x8 af = *(const s16x8*)(KhiL + row * 72 + ds * 32 + g * 8);          \
        s16x8 al = *(const s16x8*)(KloL + row * 72 + ds * 32 + g * 8);          \
        sacc[t2] = __builtin_amdgcn_mfma_f32_16x16x32_bf16(af, qfh[ds], sacc[t2], 0, 0, 0); \
        sacc[t2] = __builtin_amdgcn_mfma_f32_16x16x32_bf16(af, qfl[ds], sacc[t2], 0, 0, 0); \
        sacc[t2] = __builtin_amdgcn_mfma_f32_16x16x32_bf16(al, qfh[ds], sacc[t2], 0, 0, 0); \
      }                                                                         \
    }                                                                           \
    u32 kg0 = (u32)(kt * 64 + hh * 32);                                         \
    u32 kh0 = kg0 / 48u;                                                        \
    float bh0v = __half2float(Bh[kh0 * 65 + q64b]);                             \
    float bh1v = __half2float(Bh[(kh0 + 1) * 65 + q64b]);                       \
    float bhB = (WRAP1) ? bh1v : bh0v;                                          \
    float lg[8];                                                                \
    float tmax = -3.0e38f;                                                      \
    _Pragma("unroll")                                                           \
    for (int r = 0; r < 4; r++) {                                               \
      float x0 = sacc[0][r] * 0.125f + (bh0v + WA_[r]);                         \
      float x1 = sacc[1][r] * 0.125f + (bhB  + WB_[r]);                         \
      lg[r]     = x0;                                                           \
      lg[4 + r] = x1;                                                           \
      tmax = fmaxf(tmax, fmaxf(x0, x1));                                        \
    }                                                                           \
    tmax = fmaxf(tmax, __shfl_xor(tmax, 16));                                   \
    tmax = fmaxf(tmax, __shfl_xor(tmax, 32));                                   \
    if (__any(tmax > m_r + 6.0f)) {                                             \
      float mnew = fmaxf(m_r, tmax);                                            \
      float corr = __expf(m_r - mnew);                                          \
      l_r *= corr;                                                              \
      m_r = mnew;                                                               \
      float cq[4];                                                              \
      _Pragma("unroll")                                                         \
      for (int r = 0; r < 4; r++) cq[r] = __shfl(corr, g * 4 + r);              \
      _Pragma("unroll")                                                         \
      for (int dt = 0; dt < 4; dt++)                                            \
        _Pragma("unroll")                                                       \
        for (int r = 0; r < 4; r++) oacc[dt][r] *= cq[r];                       \
    }                                                                           \
    float psum = 0.f;                                                           \
    s16x8 pfh;                                                                  \
    _Pragma("unroll")                                                           \
    for (int j = 0; j < 8; j++) {                                               \
      float p = __expf(lg[j] - m_r);                                            \
      psum += p;                                                                \
      pfh[j] = (short)(u16)(__float_as_uint(p) >> 16);                          \
    }                                                                           \
    l_r += psum;                                                                \
    _Pragma("unroll")                                                           \
    for (int dt = 0; dt < 4; dt++) {                                            \
      int row = ql + 16 * dt;                                                   \
      s16x8 bhf = *(const s16x8*)(VhL + row * 72 + hh * 32 + g * 8);            \
      oacc[dt] = __builtin_amdgcn_mfma_f32_16x16x32_bf16(pfh, bhf, oacc[dt], 0, 0, 0); \
    }                                                                           \
  }

  for (int kt0 = 0; kt0 < 36; kt0 += 3) {
    ATTN_TILE(kt0 + 0, wA, wB, hh != 0);   // d=0: wrap iff hh==1
    ATTN_TILE(kt0 + 1, wB, wC, false);     // d=1: never wraps
    ATTN_TILE(kt0 + 2, wC, wA, hh == 0);   // d=2: wrap iff hh==0
  }
#undef ATTN_TILE

  // ---- deferred cross-g reduction of per-lane partial l
  l_r += __shfl_xor(l_r, 16);
  l_r += __shfl_xor(l_r, 32);

  // ---- merge the two key-streams per q-group, write out (packed u32 hi|lo)
  __syncthreads();
  if (hh == 1) {
    if (g == 0) { m_s[q64b] = m_r; l_s[q64b] = l_r; }
#pragma unroll
    for (int dt = 0; dt < 4; dt++)
#pragma unroll
      for (int r = 0; r < 4; r++)
        o_s[(wq * 16 + g * 4 + r) * 68 + ql + 16 * dt] = oacc[dt][r];
  }
  __syncthreads();
  if (hh == 0) {
    float m2 = m_s[q64b];
    float l2 = l_s[q64b];
    float mf = fmaxf(m_r, m2);
    float c1 = __expf(m_r - mf);
    float c2 = __expf(m2 - mf);
    float lf = l_r * c1 + l2 * c2;
    float c1q[4], c2q[4], lfq[4];
#pragma unroll
    for (int r = 0; r < 4; r++) {
      c1q[r] = __shfl(c1, g * 4 + r);
      c2q[r] = __shfl(c2, g * 4 + r);
      lfq[r] = __shfl(lf, g * 4 + r);
    }
    const int b = bh / 12, head = bh - (bh / 12) * 12;
#pragma unroll
    for (int dt = 0; dt < 4; dt++)
#pragma unroll
      for (int r = 0; r < 4; r++) {
        float oo = oacc[dt][r] * c1q[r]
                 + o_s[(wq * 16 + g * 4 + r) * 68 + ql + 16 * dt] * c2q[r];
        float on = oo / lfq[r];
        int s = s0 + wq * 16 + g * 4 + r;
        size_t idx = ((size_t)b * SEQ + s) * 768 + head * 64 + ql + 16 * dt;
        u16 h, l;
        split2(on, h, l);
        aop[idx] = (u32)h | ((u32)l << 16);
      }
  }
}

// ---- proj direct-fragment helpers: A = packed u32 (unpack in-register)
static __device__ __forceinline__ void unpack8(
    const uint4 w0, const uint4 w1, s16x8& h, s16x8& l)
{
  u32 w[8];
  *(uint4*)&w[0] = w0; *(uint4*)&w[4] = w1;
  u32 hw[4], lw[4];
#pragma unroll
  for (int i = 0; i < 4; i++) {
    hw[i] = (w[2*i] & 0xffffu) | (w[2*i+1] << 16);
    lw[i] = (w[2*i] >> 16) | (w[2*i+1] & 0xffff0000u);
  }
  h = *(s16x8*)&hw[0];
  l = *(s16x8*)&lw[0];
}
static __device__ __forceinline__ void loadP(
    const u32* pA, const u16* pBh, const u16* pBl, int kk,
    uint4 aw[4][2], s16x8 bh[4], s16x8 bl[4])
{
#pragma unroll
  for (int mt = 0; mt < 4; mt++) {
    size_t oa = (size_t)mt * 12288 + (size_t)kk * 32;  // u32 units (1 u32 per k)
    aw[mt][0] = *(const uint4*)(pA + oa);
    aw[mt][1] = *(const uint4*)(pA + oa + 4);
    size_t ob = (size_t)mt * 12288 + (size_t)kk * 32;  // u16 units
    bh[mt] = *(const s16x8*)(pBh + ob);
    bl[mt] = *(const s16x8*)(pBl + ob);
  }
}
static __device__ __forceinline__ void mfmaP(
    uint4 aw[4][2], const s16x8 bh[4], const s16x8 bl[4], f32x4 acc[4][4])
{
#pragma unroll
  for (int mt = 0; mt < 4; mt++) {
    s16x8 ah, al;
    unpack8(aw[mt][0], aw[mt][1], ah, al);
#pragma unroll
    for (int nt = 0; nt < 4; nt++) {
      acc[mt][nt] = __builtin_amdgcn_mfma_f32_16x16x32_bf16(ah, bh[nt], acc[mt][nt], 0, 0, 0);
      acc[mt][nt] = __builtin_amdgcn_mfma_f32_16x16x32_bf16(ah, bl[nt], acc[mt][nt], 0, 0, 0);
      acc[mt][nt] = __builtin_amdgcn_mfma_f32_16x16x32_bf16(al, bh[nt], acc[mt][nt], 0, 0, 0);
    }
  }
}

// ---------------- proj GEMM, barrier-free direct-fragment (qkv-style): -> out
__global__ __launch_bounds__(256, 2) void proj_mfma_k(
    const u32* __restrict__ aop,
    const u16* __restrict__ bthi, const u16* __restrict__ btlo,
    const float* __restrict__ bias, float* __restrict__ out)
{
  const int tid = threadIdx.x;
  const int lane = tid & 63, wid = tid >> 6;
  const int g = lane >> 4, ql = lane & 15;
  const int wr = wid >> 1, wc = wid & 1;
  const int c0 = blockIdx.x * 128, r0 = blockIdx.y * 128;

  const u32* pA  = aop  + (size_t)(r0 + wr * 64 + ql) * 768 + g * 8;
  const u16* pBh = bthi + (size_t)(c0 + wc * 64 + ql) * 768 + g * 8;
  const u16* pBl = btlo + (size_t)(c0 + wc * 64 + ql) * 768 + g * 8;

  uint4 Xa[4][2]; s16x8 Xbh[4], Xbl[4];
  uint4 Ya[4][2]; s16x8 Ybh[4], Ybl[4];
  f32x4 acc[4][4] = {};

  loadP(pA, pBh, pBl, 0, Xa, Xbh, Xbl);
  for (int ks = 0; ks < 24; ks += 2) {
    loadP(pA, pBh, pBl, ks + 1, Ya, Ybh, Ybl);
    mfmaP(Xa, Xbh, Xbl, acc);
    if (ks + 2 < 24)
      loadP(pA, pBh, pBl, ks + 2, Xa, Xbh, Xbl);
    mfmaP(Ya, Ybh, Ybl, acc);
  }

  const int col0 = c0 + wc * 64;
  const int row0 = r0 + wr * 64;
  float bb[4];
#pragma unroll
  for (int nt = 0; nt < 4; nt++) bb[nt] = bias[col0 + nt * 16 + ql];
#pragma unroll
  for (int mt = 0; mt < 4; mt++)
#pragma unroll
    for (int nt = 0; nt < 4; nt++)
#pragma unroll
      for (int r = 0; r < 4; r++)
        out[(size_t)(row0 + mt * 16 + g * 4 + r) * 768 + col0 + nt * 16 + ql] =
            acc[mt][nt][r] + bb[nt];
}

extern "C" void kernel_launch(void* const* d_in, const int* in_sizes, int n_in,
                              void* d_out, int out_size, void* d_ws, size_t ws_size,
                              hipStream_t stream) {
  const float* x      = (const float*)d_in[0];
  const float* qkv_w  = (const float*)d_in[1];
  const float* qkv_b  = (const float*)d_in[2];
  const float* proj_w = (const float*)d_in[3];
  const float* proj_b = (const float*)d_in[4];
  const float* rph    = (const float*)d_in[5];
  const float* rpw    = (const float*)d_in[6];
  float* out = (float*)d_out;
  float* ws  = (float*)d_ws;

  const size_t SZ = (size_t)24 * SEQ * HD;   // 3,538,944 elems (== 4608*768)
  float* qbuf = ws;                          // SZ f32
  u16* khi = (u16*)(ws + SZ);                // khi, klo, vhi (+dead slot)
  u16* klo = khi + SZ;
  u16* vhi = klo + SZ;
  u32* aop = (u32*)(ws + 4 * SZ);            // SZ u32 (packed hi|lo)
  u16* wqThi = (u16*)(ws + 5 * SZ);          // 768*2304 x2
  u16* wqTlo = wqThi + 768 * 2304;
  u16* wpThi = wqTlo + 768 * 2304;           // 768*768 x2
  u16* wpTlo = wpThi + 768 * 768;

  conv_wT2_k <<<dim3(48, 12), 256, 0, stream>>>(qkv_w, proj_w,
                                                wqThi, wqTlo, wpThi, wpTlo);
  qkv_mfma_k <<<dim3(18, 36), 256, 0, stream>>>(x, wqThi, wqTlo, qkv_b,
                                                qbuf, khi, klo, vhi);
  attn_k     <<<dim3(24, 36), 512, 0, stream>>>(qbuf, khi, klo, vhi, rph, rpw, aop);
  proj_mfma_k<<<dim3(6, 36), 256, 0, stream>>>(aop, wpThi, wpTlo, proj_b, out);
}